// Round 2
// baseline (19578.960 us; speedup 1.0000x reference)
//
#include <hip/hip_runtime.h>
#include <hip/hip_bf16.h>
#include <hip/hip_fp16.h>

// ---------------- problem constants ----------------
#define BB 32
#define NN 20
#define TT 100
#define DD 4
#define HH 128
#define EE 380          // N*(N-1)
#define BE 12160        // B*E
#define L1 96           // conv1 out length
#define LP 48           // after maxpool
#define L2 44           // conv2 out length
#define NOUT 16
#define EPS 1e-5f

// stats slot indices (floats)
#define S_BN1_SUM 0
#define S_BN1_SQ 128
#define S_BN1_SC 256
#define S_BN1_SH 384
#define S_BN2_SUM 512
#define S_BN2_SQ 640
#define S_BN2_SC 768
#define S_BN2_SH 896
#define S_M1_SUM 1024
#define S_M1_SQ 1152
#define S_M1_SC 1280
#define S_M1_SH 1408
#define S_M2_SUM 1536
#define S_M2_SQ 1664
#define S_M2_SC 1792
#define S_M2_SH 1920
#define S_M3_SUM 2048
#define S_M3_SQ 2176
#define S_M3_SC 2304
#define S_M3_SH 2432
#define S_COUNT 2560

// workspace offsets (bytes)
#define OFF_STATS 0ULL
#define OFF_SIDX 16384ULL
#define OFF_RIDX 18432ULL
#define OFF_INC 20480ULL
#define OFF_Y3 24576ULL                      // fp16 [BE][128][44]
#define OFF_X 136994816ULL                   // f32 [BE][128]
#define OFF_BUFA 143220736ULL                // f32 [BE][128]
#define OFF_BUFB 149446656ULL                // f32 [BE][128]
#define OFF_SKIP 155672576ULL                // f32 [BE][128]
#define OFF_XN 161898496ULL                  // f32 [640][128]
#define OFF_T640 162226176ULL                // f32 [640][128]
#define OFF_XN2 162553856ULL                 // f32 [640][128]

__device__ __forceinline__ float eluf(float v) { return v > 0.f ? v : expm1f(v); }

// ---------------- K0: zero stats + edge index tables ----------------
__global__ void k_init(const float* __restrict__ rel_rec, const float* __restrict__ rel_send,
                       float* stats, int* sidx, int* ridx, int* inc) {
    int tid = threadIdx.x;
    for (int i = tid; i < S_COUNT; i += 256) stats[i] = 0.f;
    for (int e = tid; e < EE; e += 256) {
        int s = 0, r = 0;
        for (int n = 0; n < NN; ++n) {
            if (rel_send[e * NN + n] > 0.5f) s = n;
            if (rel_rec[e * NN + n] > 0.5f) r = n;
        }
        sidx[e] = s; ridx[e] = r;
    }
    __syncthreads();
    if (tid < NN) {
        int k = 0;
        for (int e = 0; e < EE; ++e)
            if (ridx[e] == tid) inc[tid * (NN - 1) + (k++)] = e;
    }
}

// conv1 unit: one output channel o, pre-pool t-range [lc*24, lc*24+24) -> 24 relu'd values
__device__ __forceinline__ void conv1_unit(const float* s_edges /*[8][100]*/,
                                           const float* s_w1 /*[128][40]*/,
                                           int o, int lc, float bias, float v[24]) {
    float acc[24];
#pragma unroll
    for (int t = 0; t < 24; ++t) acc[t] = bias;
#pragma unroll
    for (int ci = 0; ci < 8; ++ci) {
        float win[28];
        const float4* p = reinterpret_cast<const float4*>(s_edges + ci * 100 + lc * 24);
#pragma unroll
        for (int q = 0; q < 7; ++q) {
            float4 f = p[q];
            win[4 * q + 0] = f.x; win[4 * q + 1] = f.y;
            win[4 * q + 2] = f.z; win[4 * q + 3] = f.w;
        }
        const float* wr = s_w1 + o * 40 + ci * 5;
#pragma unroll
        for (int k = 0; k < 5; ++k) {
            float w = wr[k];
#pragma unroll
            for (int t = 0; t < 24; ++t) acc[t] = fmaf(win[t + k], w, acc[t]);
        }
    }
#pragma unroll
    for (int t = 0; t < 24; ++t) v[t] = fmaxf(acc[t], 0.f);
}

__device__ __forceinline__ void load_edges_w1(float* s_edges, float* s_w1,
                                              const float* __restrict__ inputs,
                                              const float* __restrict__ conv1_w,
                                              int b, int sn, int rn) {
    for (int i = threadIdx.x; i < 800; i += 256) {
        int ci = i / 100, t = i - ci * 100;
        int n = (ci < 4) ? sn : rn;
        int d = ci & 3;
        s_edges[ci * 100 + t] = inputs[((b * NN + n) * TT + t) * DD + d];
    }
    for (int i = threadIdx.x; i < 5120; i += 256) s_w1[i] = conv1_w[i];
}

// ---------------- K1: conv1 + relu, accumulate BN1 stats (no store) ----------------
__global__ __launch_bounds__(256) void k_conv1_stats(const float* __restrict__ inputs,
                                                     const float* __restrict__ conv1_w,
                                                     const float* __restrict__ conv1_b,
                                                     const int* __restrict__ sidx,
                                                     const int* __restrict__ ridx,
                                                     float* stats) {
    __shared__ float s_edges[8 * 100];
    __shared__ float s_w1[128 * 40];
    int be = blockIdx.x;
    int b = be / EE, e = be - b * EE;
    load_edges_w1(s_edges, s_w1, inputs, conv1_w, b, sidx[e], ridx[e]);
    __syncthreads();
#pragma unroll
    for (int u = 0; u < 2; ++u) {
        int unit = threadIdx.x + u * 256;
        int o = unit >> 2, lc = unit & 3;
        float v[24];
        conv1_unit(s_edges, s_w1, o, lc, conv1_b[o], v);
        float s = 0.f, q = 0.f;
#pragma unroll
        for (int t = 0; t < 24; ++t) { s += v[t]; q += v[t] * v[t]; }
        s += __shfl_xor(s, 1); s += __shfl_xor(s, 2);
        q += __shfl_xor(q, 1); q += __shfl_xor(q, 2);
        if ((threadIdx.x & 3) == 0) {
            atomicAdd(&stats[S_BN1_SUM + o], s);
            atomicAdd(&stats[S_BN1_SQ + o], q);
        }
    }
}

// ---------------- finalize BN: scale/shift from sum/sumsq ----------------
__global__ void k_finalize(float* stats, int sumIdx, const float* __restrict__ g,
                           const float* __restrict__ bb, float inv_count) {
    int j = threadIdx.x;
    float m = stats[sumIdx + j] * inv_count;
    float v = fmaxf(stats[sumIdx + 128 + j] * inv_count - m * m, 0.f);
    float sc = g[j] * rsqrtf(v + EPS);
    stats[sumIdx + 256 + j] = sc;
    stats[sumIdx + 384 + j] = bb[j] - m * sc;
}

// ---------------- K3: conv1(recompute)+BN1+pool+conv2+relu -> y3 (fp16) + BN2 stats ----------------
__global__ __launch_bounds__(256) void k_conv2(const float* __restrict__ inputs,
                                               const float* __restrict__ conv1_w,
                                               const float* __restrict__ conv1_b,
                                               const float* __restrict__ conv2_w,
                                               const float* __restrict__ conv2_b,
                                               const int* __restrict__ sidx,
                                               const int* __restrict__ ridx,
                                               float* stats,
                                               __half* __restrict__ y3) {
    __shared__ float s_y2[128 * 48];
    __shared__ __align__(16) char s_un[41472];  // union: {edges 3200 + w1 20480} | w2chunk 128*81*4
    float* s_edges = (float*)s_un;
    float* s_w1 = (float*)(s_un + 3200);
    float* s_w2 = (float*)s_un;

    int be = blockIdx.x;
    int b = be / EE, e = be - b * EE;
    load_edges_w1(s_edges, s_w1, inputs, conv1_w, b, sidx[e], ridx[e]);
    __syncthreads();
    // phase 2: conv1 + BN1 + maxpool -> s_y2
#pragma unroll
    for (int u = 0; u < 2; ++u) {
        int unit = threadIdx.x + u * 256;
        int o = unit >> 2, lc = unit & 3;
        float v[24];
        conv1_unit(s_edges, s_w1, o, lc, conv1_b[o], v);
        float sc = stats[S_BN1_SC + o], sh = stats[S_BN1_SH + o];
#pragma unroll
        for (int l = 0; l < 12; ++l) {
            float a = fmaf(v[2 * l], sc, sh);
            float c = fmaf(v[2 * l + 1], sc, sh);
            s_y2[o * 48 + lc * 12 + l] = fmaxf(a, c);
        }
    }
    // phase 3: conv2 over s_y2, weights staged in LDS chunks of 16 input channels
    int co = threadIdx.x >> 1, half = threadIdx.x & 1;
    float acc[22];
    float bias2 = conv2_b[co];
#pragma unroll
    for (int t = 0; t < 22; ++t) acc[t] = bias2;

    for (int c0 = 0; c0 < 128; c0 += 16) {
        __syncthreads();  // protect previous chunk (and phase-1/2 LDS) before overwrite
        for (int i = threadIdx.x; i < 128 * 80; i += 256) {
            int cc = i / 80, r = i - cc * 80;
            s_w2[cc * 81 + r] = conv2_w[cc * 640 + c0 * 5 + r];
        }
        __syncthreads();
        for (int cl = 0; cl < 16; ++cl) {
            int ci = c0 + cl;
            float win[28];
            const float4* p = reinterpret_cast<const float4*>(s_y2 + ci * 48 + half * 20);
#pragma unroll
            for (int q = 0; q < 7; ++q) {
                float4 f = p[q];
                win[4 * q + 0] = f.x; win[4 * q + 1] = f.y;
                win[4 * q + 2] = f.z; win[4 * q + 3] = f.w;
            }
            const float* wr = s_w2 + co * 81 + cl * 5;
#pragma unroll
            for (int k = 0; k < 5; ++k) {
                float w = wr[k];
#pragma unroll
                for (int t = 0; t < 22; ++t) acc[t] = fmaf(win[2 * half + t + k], w, acc[t]);
            }
        }
    }
    // epilogue: relu, store fp16, BN2 stats
    float s = 0.f, q = 0.f;
    long long base = ((long long)be * 128 + co) * 44 + half * 22;
#pragma unroll
    for (int t = 0; t < 22; ++t) {
        float v = fmaxf(acc[t], 0.f);
        y3[base + t] = __float2half(v);
        s += v; q += v * v;
    }
    s += __shfl_xor(s, 1);
    q += __shfl_xor(q, 1);
    if (half == 0) {
        atomicAdd(&stats[S_BN2_SUM + co], s);
        atomicAdd(&stats[S_BN2_SQ + co], q);
    }
}

// ---------------- K5: BN2 apply + attention-pool (collapsed) -> x [BE][128] ----------------
__global__ __launch_bounds__(128) void k_predatt(const __half* __restrict__ y3,
                                                 const float* __restrict__ stats,
                                                 const float* __restrict__ att_w,
                                                 const float* __restrict__ att_b,
                                                 const float* __restrict__ pred_w,
                                                 const float* __restrict__ pred_b,
                                                 float* __restrict__ x) {
    __shared__ float h[128 * 45];
    __shared__ float att[44];
    __shared__ float hw[128];
    int be = blockIdx.x;
    int tid = threadIdx.x;
    for (int i = tid; i < 128 * 44; i += 128) {
        int c = i / 44, t = i - c * 44;
        float v = __half2float(y3[(long long)be * 5632 + i]);
        h[c * 45 + t] = fmaf(v, stats[S_BN2_SC + c], stats[S_BN2_SH + c]);
    }
    __syncthreads();
    if (tid < 44) {
        float a = att_b[0];
        for (int c = 0; c < 128; ++c) a = fmaf(h[c * 45 + tid], att_w[c], a);
        att[tid] = a;
    }
    __syncthreads();
    if (tid == 0) {
        float m = -1e30f;
        for (int t = 0; t < 44; ++t) m = fmaxf(m, att[t]);
        float s = 0.f;
        for (int t = 0; t < 44; ++t) { float ev = expf(att[t] - m); att[t] = ev; s += ev; }
        float inv = 1.f / s;
        for (int t = 0; t < 44; ++t) att[t] *= inv;
    }
    __syncthreads();
    {
        int c = tid;
        float a = 0.f;
        for (int t = 0; t < 44; ++t) a = fmaf(h[c * 45 + t], att[t], a);
        hw[c] = a;
    }
    __syncthreads();
    {
        int o = tid;
        float a = pred_b[o];
        for (int c = 0; c < 128; ++c) a = fmaf(pred_w[o * 128 + c], hw[c], a);
        x[(long long)be * 128 + o] = a * (1.0f / 44.0f);
    }
}

// ---------------- generic linear (IN -> 128) + ELU, 8 rows per block ----------------
template <int IN>
__global__ __launch_bounds__(128) void k_linear(const float* __restrict__ in,
                                                const float* __restrict__ W,
                                                const float* __restrict__ bias,
                                                float* __restrict__ out) {
    __shared__ float s_in[8 * IN];
    int r0 = blockIdx.x * 8;
    int j = threadIdx.x;
    for (int i = j; i < 8 * IN; i += 128) s_in[i] = in[(long long)r0 * IN + i];
    __syncthreads();
    float acc[8];
    float bj = bias[j];
#pragma unroll
    for (int e = 0; e < 8; ++e) acc[e] = bj;
    for (int i = 0; i < IN; ++i) {
        float w = W[j * IN + i];
#pragma unroll
        for (int e = 0; e < 8; ++e) acc[e] = fmaf(s_in[e * IN + i], w, acc[e]);
    }
#pragma unroll
    for (int e = 0; e < 8; ++e) out[(long long)(r0 + e) * 128 + j] = eluf(acc[e]);
}

// ---------------- mlp3 layer1: gather-concat [send|recv|skip] (384) -> 128, ELU ----------------
__global__ __launch_bounds__(128) void k_mlp3l1(const float* __restrict__ xn2,
                                                const float* __restrict__ x_skip,
                                                const int* __restrict__ sidx,
                                                const int* __restrict__ ridx,
                                                const float* __restrict__ W,
                                                const float* __restrict__ bias,
                                                float* __restrict__ out) {
    __shared__ float s_in[8 * 384];
    int r0 = blockIdx.x * 8;
    int j = threadIdx.x;
    for (int e = 0; e < 8; ++e) {
        int r = r0 + e;
        int b = r / EE, ed = r - b * EE;
        s_in[e * 384 + j] = xn2[(b * NN + sidx[ed]) * 128 + j];
        s_in[e * 384 + 128 + j] = xn2[(b * NN + ridx[ed]) * 128 + j];
        s_in[e * 384 + 256 + j] = x_skip[(long long)r * 128 + j];
    }
    __syncthreads();
    float acc[8];
    float bj = bias[j];
#pragma unroll
    for (int e = 0; e < 8; ++e) acc[e] = bj;
    for (int i = 0; i < 384; ++i) {
        float w = W[j * 384 + i];
#pragma unroll
        for (int e = 0; e < 8; ++e) acc[e] = fmaf(s_in[e * 384 + i], w, acc[e]);
    }
#pragma unroll
    for (int e = 0; e < 8; ++e) out[(long long)(r0 + e) * 128 + j] = eluf(acc[e]);
}

// ---------------- per-feature (column) stats over [R][128] ----------------
__global__ __launch_bounds__(128) void k_colstats(const float* __restrict__ in,
                                                  float* stats, int sumIdx, int R) {
    int r0 = blockIdx.x * 128;
    int j = threadIdx.x;
    float s = 0.f, q = 0.f;
    int rend = (r0 + 128 < R) ? r0 + 128 : R;
    for (int r = r0; r < rend; ++r) {
        float v = in[(long long)r * 128 + j];
        s += v; q += v * v;
    }
    atomicAdd(&stats[sumIdx + j], s);
    atomicAdd(&stats[sumIdx + 128 + j], q);
}

// ---------------- BN apply (elementwise, per-column scale/shift) ----------------
__global__ __launch_bounds__(256) void k_bnapply(const float* __restrict__ in,
                                                 float* __restrict__ out,
                                                 const float* __restrict__ stats,
                                                 int scIdx, int n) {
    int i = blockIdx.x * 256 + threadIdx.x;
    if (i < n) {
        int j = i & 127;
        out[i] = fmaf(in[i], stats[scIdx + j], stats[scIdx + 128 + j]);
    }
}

// ---------------- edge2node scatter-mean (via incoming-edge lists) ----------------
__global__ __launch_bounds__(128) void k_e2n(const float* __restrict__ x_skip,
                                             const int* __restrict__ inc,
                                             float* __restrict__ xn) {
    int bn = blockIdx.x;
    int b = bn / NN, n = bn - b * NN;
    int j = threadIdx.x;
    float s = 0.f;
    for (int k = 0; k < NN - 1; ++k) {
        int e = inc[n * (NN - 1) + k];
        s += x_skip[(long long)(b * EE + e) * 128 + j];
    }
    xn[bn * 128 + j] = s * (1.0f / (float)NN);
}

// ---------------- BN3 apply + fc_out (128 -> 16) ----------------
__global__ __launch_bounds__(256) void k_fcout(const float* __restrict__ h2,
                                               const float* __restrict__ stats,
                                               const float* __restrict__ fcw,
                                               const float* __restrict__ fcb,
                                               float* __restrict__ out) {
    __shared__ float s_x[16 * 129];
    __shared__ float s_w[16 * 129];
    int r0 = blockIdx.x * 16;
    int tid = threadIdx.x;
    for (int i = tid; i < 16 * 128; i += 256) {
        int rr = i >> 7, j = i & 127;
        s_x[rr * 129 + j] = fmaf(h2[(long long)(r0 + rr) * 128 + j],
                                 stats[S_M3_SC + j], stats[S_M3_SH + j]);
    }
    for (int i = tid; i < 16 * 128; i += 256) {
        int o = i >> 7, j = i & 127;
        s_w[o * 129 + j] = fcw[i];
    }
    __syncthreads();
    int rl = tid >> 4, o = tid & 15;
    float a = fcb[o];
    for (int j = 0; j < 128; ++j) a = fmaf(s_x[rl * 129 + j], s_w[o * 129 + j], a);
    out[(long long)(r0 + rl) * 16 + o] = a;
}

// ---------------- host launcher ----------------
extern "C" void kernel_launch(void* const* d_in, const int* in_sizes, int n_in,
                              void* d_out, int out_size, void* d_ws, size_t ws_size,
                              hipStream_t stream) {
    const float* inputs = (const float*)d_in[0];
    const float* rel_rec = (const float*)d_in[1];
    const float* rel_send = (const float*)d_in[2];
    const float* conv1_w = (const float*)d_in[3];
    const float* conv1_b = (const float*)d_in[4];
    const float* bn1_g = (const float*)d_in[5];
    const float* bn1_b = (const float*)d_in[6];
    const float* conv2_w = (const float*)d_in[7];
    const float* conv2_b = (const float*)d_in[8];
    const float* bn2_g = (const float*)d_in[9];
    const float* bn2_b = (const float*)d_in[10];
    const float* pred_w = (const float*)d_in[11];
    const float* pred_b = (const float*)d_in[12];
    const float* att_w = (const float*)d_in[13];
    const float* att_b = (const float*)d_in[14];
    const float* m1w1 = (const float*)d_in[15];
    const float* m1b1 = (const float*)d_in[16];
    const float* m1w2 = (const float*)d_in[17];
    const float* m1b2 = (const float*)d_in[18];
    const float* m1g = (const float*)d_in[19];
    const float* m1bb = (const float*)d_in[20];
    const float* m2w1 = (const float*)d_in[21];
    const float* m2b1 = (const float*)d_in[22];
    const float* m2w2 = (const float*)d_in[23];
    const float* m2b2 = (const float*)d_in[24];
    const float* m2g = (const float*)d_in[25];
    const float* m2bb = (const float*)d_in[26];
    const float* m3w1 = (const float*)d_in[27];
    const float* m3b1 = (const float*)d_in[28];
    const float* m3w2 = (const float*)d_in[29];
    const float* m3b2 = (const float*)d_in[30];
    const float* m3g = (const float*)d_in[31];
    const float* m3bb = (const float*)d_in[32];
    const float* fcw = (const float*)d_in[33];
    const float* fcb = (const float*)d_in[34];

    char* ws = (char*)d_ws;
    float* stats = (float*)(ws + OFF_STATS);
    int* sidx = (int*)(ws + OFF_SIDX);
    int* ridx = (int*)(ws + OFF_RIDX);
    int* inc = (int*)(ws + OFF_INC);
    __half* y3 = (__half*)(ws + OFF_Y3);
    float* x = (float*)(ws + OFF_X);
    float* bufA = (float*)(ws + OFF_BUFA);
    float* bufB = (float*)(ws + OFF_BUFB);
    float* x_skip = (float*)(ws + OFF_SKIP);
    float* xn = (float*)(ws + OFF_XN);
    float* t640 = (float*)(ws + OFF_T640);
    float* xn2 = (float*)(ws + OFF_XN2);
    float* outp = (float*)d_out;

    hipLaunchKernelGGL(k_init, dim3(1), dim3(256), 0, stream,
                       rel_rec, rel_send, stats, sidx, ridx, inc);
    hipLaunchKernelGGL(k_conv1_stats, dim3(BE), dim3(256), 0, stream,
                       inputs, conv1_w, conv1_b, sidx, ridx, stats);
    hipLaunchKernelGGL(k_finalize, dim3(1), dim3(128), 0, stream,
                       stats, S_BN1_SUM, bn1_g, bn1_b, 1.0f / (float)(BE * L1));
    hipLaunchKernelGGL(k_conv2, dim3(BE), dim3(256), 0, stream,
                       inputs, conv1_w, conv1_b, conv2_w, conv2_b, sidx, ridx, stats, y3);
    hipLaunchKernelGGL(k_finalize, dim3(1), dim3(128), 0, stream,
                       stats, S_BN2_SUM, bn2_g, bn2_b, 1.0f / (float)(BE * L2));
    hipLaunchKernelGGL(k_predatt, dim3(BE), dim3(128), 0, stream,
                       y3, stats, att_w, att_b, pred_w, pred_b, x);
    // mlp1
    hipLaunchKernelGGL(k_linear<128>, dim3(BE / 8), dim3(128), 0, stream, x, m1w1, m1b1, bufA);
    hipLaunchKernelGGL(k_linear<128>, dim3(BE / 8), dim3(128), 0, stream, bufA, m1w2, m1b2, bufB);
    hipLaunchKernelGGL(k_colstats, dim3(BE / 128), dim3(128), 0, stream, bufB, stats, S_M1_SUM, BE);
    hipLaunchKernelGGL(k_finalize, dim3(1), dim3(128), 0, stream,
                       stats, S_M1_SUM, m1g, m1bb, 1.0f / (float)BE);
    hipLaunchKernelGGL(k_bnapply, dim3(BE * 128 / 256), dim3(256), 0, stream,
                       bufB, x_skip, stats, S_M1_SC, BE * 128);
    // edge2node + mlp2
    hipLaunchKernelGGL(k_e2n, dim3(BB * NN), dim3(128), 0, stream, x_skip, inc, xn);
    hipLaunchKernelGGL(k_linear<128>, dim3(BB * NN / 8), dim3(128), 0, stream, xn, m2w1, m2b1, t640);
    hipLaunchKernelGGL(k_linear<128>, dim3(BB * NN / 8), dim3(128), 0, stream, t640, m2w2, m2b2, xn);
    hipLaunchKernelGGL(k_colstats, dim3(BB * NN / 128), dim3(128), 0, stream, xn, stats, S_M2_SUM, BB * NN);
    hipLaunchKernelGGL(k_finalize, dim3(1), dim3(128), 0, stream,
                       stats, S_M2_SUM, m2g, m2bb, 1.0f / (float)(BB * NN));
    hipLaunchKernelGGL(k_bnapply, dim3(BB * NN * 128 / 256), dim3(256), 0, stream,
                       xn, xn2, stats, S_M2_SC, BB * NN * 128);
    // node2edge + mlp3
    hipLaunchKernelGGL(k_mlp3l1, dim3(BE / 8), dim3(128), 0, stream,
                       xn2, x_skip, sidx, ridx, m3w1, m3b1, bufA);
    hipLaunchKernelGGL(k_linear<128>, dim3(BE / 8), dim3(128), 0, stream, bufA, m3w2, m3b2, bufB);
    hipLaunchKernelGGL(k_colstats, dim3(BE / 128), dim3(128), 0, stream, bufB, stats, S_M3_SUM, BE);
    hipLaunchKernelGGL(k_finalize, dim3(1), dim3(128), 0, stream,
                       stats, S_M3_SUM, m3g, m3bb, 1.0f / (float)BE);
    // fc_out
    hipLaunchKernelGGL(k_fcout, dim3(BE / 16), dim3(256), 0, stream, bufB, stats, fcw, fcb, outp);
    (void)in_sizes; (void)n_in; (void)out_size; (void)ws_size;
}

// Round 3
// 3489.955 us; speedup vs baseline: 5.6101x; 5.6101x over previous
//
#include <hip/hip_runtime.h>
#include <hip/hip_bf16.h>
#include <hip/hip_fp16.h>

// ---------------- problem constants ----------------
#define BB 32
#define NN 20
#define TT 100
#define DD 4
#define HH 128
#define EE 380          // N*(N-1)
#define BE 12160        // B*E
#define L1 96           // conv1 out length
#define LP 48           // after maxpool
#define L2 44           // conv2 out length
#define NOUT 16
#define EPS 1e-5f

// stats slot indices (floats)
#define S_BN1_SUM 0
#define S_BN1_SQ 128
#define S_BN1_SC 256
#define S_BN1_SH 384
#define S_BN2_SUM 512
#define S_BN2_SQ 640
#define S_BN2_SC 768
#define S_BN2_SH 896
#define S_M1_SUM 1024
#define S_M1_SQ 1152
#define S_M1_SC 1280
#define S_M1_SH 1408
#define S_M2_SUM 1536
#define S_M2_SQ 1664
#define S_M2_SC 1792
#define S_M2_SH 1920
#define S_M3_SUM 2048
#define S_M3_SQ 2176
#define S_M3_SC 2304
#define S_M3_SH 2432
#define S_COUNT 2560

// workspace offsets (bytes)
#define OFF_STATS 0ULL
#define OFF_SIDX 16384ULL
#define OFF_RIDX 18432ULL
#define OFF_INC 20480ULL
#define OFF_Y3 24576ULL                      // fp16 [BE][128][44]
#define OFF_X 136994816ULL                   // f32 [BE][128]
#define OFF_BUFA 143220736ULL                // f32 [BE][128]
#define OFF_BUFB 149446656ULL                // f32 [BE][128]
#define OFF_SKIP 155672576ULL                // f32 [BE][128]
#define OFF_XN 161898496ULL                  // f32 [640][128]
#define OFF_T640 162226176ULL                // f32 [640][128]
#define OFF_XN2 162553856ULL                 // f32 [640][128]

__device__ __forceinline__ float eluf(float v) { return v > 0.f ? v : expm1f(v); }

// ---------------- K0: zero stats + edge index tables ----------------
__global__ void k_init(const float* __restrict__ rel_rec, const float* __restrict__ rel_send,
                       float* stats, int* sidx, int* ridx, int* inc) {
    int tid = threadIdx.x;
    for (int i = tid; i < S_COUNT; i += 256) stats[i] = 0.f;
    for (int e = tid; e < EE; e += 256) {
        int s = 0, r = 0;
        for (int n = 0; n < NN; ++n) {
            if (rel_send[e * NN + n] > 0.5f) s = n;
            if (rel_rec[e * NN + n] > 0.5f) r = n;
        }
        sidx[e] = s; ridx[e] = r;
    }
    __syncthreads();
    if (tid < NN) {
        int k = 0;
        for (int e = 0; e < EE; ++e)
            if (ridx[e] == tid) inc[tid * (NN - 1) + (k++)] = e;
    }
}

// conv1 unit: one output channel o, pre-pool t-range [lc*24, lc*24+24) -> 24 relu'd values
__device__ __forceinline__ void conv1_unit(const float* s_edges /*[8][100]*/,
                                           const float* s_w1 /*[128][40]*/,
                                           int o, int lc, float bias, float v[24]) {
    float acc[24];
#pragma unroll
    for (int t = 0; t < 24; ++t) acc[t] = bias;
#pragma unroll
    for (int ci = 0; ci < 8; ++ci) {
        float win[28];
        const float4* p = reinterpret_cast<const float4*>(s_edges + ci * 100 + lc * 24);
#pragma unroll
        for (int q = 0; q < 7; ++q) {
            float4 f = p[q];
            win[4 * q + 0] = f.x; win[4 * q + 1] = f.y;
            win[4 * q + 2] = f.z; win[4 * q + 3] = f.w;
        }
        const float* wr = s_w1 + o * 40 + ci * 5;
#pragma unroll
        for (int k = 0; k < 5; ++k) {
            float w = wr[k];
#pragma unroll
            for (int t = 0; t < 24; ++t) acc[t] = fmaf(win[t + k], w, acc[t]);
        }
    }
#pragma unroll
    for (int t = 0; t < 24; ++t) v[t] = fmaxf(acc[t], 0.f);
}

__device__ __forceinline__ void load_edges_w1(float* s_edges, float* s_w1,
                                              const float* __restrict__ inputs,
                                              const float* __restrict__ conv1_w,
                                              int b, int sn, int rn) {
    for (int i = threadIdx.x; i < 800; i += 256) {
        int ci = i / 100, t = i - ci * 100;
        int n = (ci < 4) ? sn : rn;
        int d = ci & 3;
        s_edges[ci * 100 + t] = inputs[((b * NN + n) * TT + t) * DD + d];
    }
    for (int i = threadIdx.x; i < 5120; i += 256) s_w1[i] = conv1_w[i];
}

// ---------------- K1: conv1 + relu, accumulate BN1 stats (no store) ----------------
__global__ __launch_bounds__(256) void k_conv1_stats(const float* __restrict__ inputs,
                                                     const float* __restrict__ conv1_w,
                                                     const float* __restrict__ conv1_b,
                                                     const int* __restrict__ sidx,
                                                     const int* __restrict__ ridx,
                                                     float* stats) {
    __shared__ float s_edges[8 * 100];
    __shared__ float s_w1[128 * 40];
    int be = blockIdx.x;
    int b = be / EE, e = be - b * EE;
    load_edges_w1(s_edges, s_w1, inputs, conv1_w, b, sidx[e], ridx[e]);
    __syncthreads();
#pragma unroll
    for (int u = 0; u < 2; ++u) {
        int unit = threadIdx.x + u * 256;
        int o = unit >> 2, lc = unit & 3;
        float v[24];
        conv1_unit(s_edges, s_w1, o, lc, conv1_b[o], v);
        float s = 0.f, q = 0.f;
#pragma unroll
        for (int t = 0; t < 24; ++t) { s += v[t]; q += v[t] * v[t]; }
        s += __shfl_xor(s, 1); s += __shfl_xor(s, 2);
        q += __shfl_xor(q, 1); q += __shfl_xor(q, 2);
        if ((threadIdx.x & 3) == 0) {
            atomicAdd(&stats[S_BN1_SUM + o], s);
            atomicAdd(&stats[S_BN1_SQ + o], q);
        }
    }
}

// ---------------- finalize BN: scale/shift from sum/sumsq ----------------
__global__ void k_finalize(float* stats, int sumIdx, const float* __restrict__ g,
                           const float* __restrict__ bb, float inv_count) {
    int j = threadIdx.x;
    float m = stats[sumIdx + j] * inv_count;
    float v = fmaxf(stats[sumIdx + 128 + j] * inv_count - m * m, 0.f);
    float sc = g[j] * rsqrtf(v + EPS);
    stats[sumIdx + 256 + j] = sc;
    stats[sumIdx + 384 + j] = bb[j] - m * sc;
}

// ---------------- K3: conv1(recompute)+BN1+pool+conv2+relu -> y3 (fp16) + BN2 stats ----------------
__global__ __launch_bounds__(256) void k_conv2(const float* __restrict__ inputs,
                                               const float* __restrict__ conv1_w,
                                               const float* __restrict__ conv1_b,
                                               const float* __restrict__ conv2_w,
                                               const float* __restrict__ conv2_b,
                                               const int* __restrict__ sidx,
                                               const int* __restrict__ ridx,
                                               float* stats,
                                               __half* __restrict__ y3) {
    __shared__ float s_y2[128 * 48];
    __shared__ __align__(16) char s_un[41472];  // union: {edges 3200 + w1 20480} | w2chunk 128*81*4
    float* s_edges = (float*)s_un;
    float* s_w1 = (float*)(s_un + 3200);
    float* s_w2 = (float*)s_un;

    int be = blockIdx.x;
    int b = be / EE, e = be - b * EE;
    load_edges_w1(s_edges, s_w1, inputs, conv1_w, b, sidx[e], ridx[e]);
    __syncthreads();
    // phase 2: conv1 + BN1 + maxpool -> s_y2
#pragma unroll
    for (int u = 0; u < 2; ++u) {
        int unit = threadIdx.x + u * 256;
        int o = unit >> 2, lc = unit & 3;
        float v[24];
        conv1_unit(s_edges, s_w1, o, lc, conv1_b[o], v);
        float sc = stats[S_BN1_SC + o], sh = stats[S_BN1_SH + o];
#pragma unroll
        for (int l = 0; l < 12; ++l) {
            float a = fmaf(v[2 * l], sc, sh);
            float c = fmaf(v[2 * l + 1], sc, sh);
            s_y2[o * 48 + lc * 12 + l] = fmaxf(a, c);
        }
    }
    // phase 3: conv2 over s_y2, weights staged in LDS chunks of 16 input channels.
    // NOTE: window base folds in half*22 so ALL win[] indices are compile-time
    // (runtime-indexed register arrays demote to scratch -> 51 GB FETCH_SIZE in R2).
    // float2 loads because half*22 floats = 88 B is only 8-byte aligned.
    int co = threadIdx.x >> 1, half = threadIdx.x & 1;
    float acc[22];
    float bias2 = conv2_b[co];
#pragma unroll
    for (int t = 0; t < 22; ++t) acc[t] = bias2;

    for (int c0 = 0; c0 < 128; c0 += 16) {
        __syncthreads();  // protect previous chunk (and phase-1/2 LDS) before overwrite
        for (int i = threadIdx.x; i < 128 * 80; i += 256) {
            int cc = i / 80, r = i - cc * 80;
            s_w2[cc * 81 + r] = conv2_w[cc * 640 + c0 * 5 + r];
        }
        __syncthreads();
        for (int cl = 0; cl < 16; ++cl) {
            int ci = c0 + cl;
            float win[26];
            const float2* p = reinterpret_cast<const float2*>(s_y2 + ci * 48 + half * 22);
#pragma unroll
            for (int q = 0; q < 13; ++q) {
                float2 f = p[q];
                win[2 * q] = f.x; win[2 * q + 1] = f.y;
            }
            const float* wr = s_w2 + co * 81 + cl * 5;
#pragma unroll
            for (int k = 0; k < 5; ++k) {
                float w = wr[k];
#pragma unroll
                for (int t = 0; t < 22; ++t) acc[t] = fmaf(win[t + k], w, acc[t]);
            }
        }
    }
    // epilogue: relu, store fp16, BN2 stats
    float s = 0.f, q = 0.f;
    long long base = ((long long)be * 128 + co) * 44 + half * 22;
#pragma unroll
    for (int t = 0; t < 22; ++t) {
        float v = fmaxf(acc[t], 0.f);
        y3[base + t] = __float2half(v);
        s += v; q += v * v;
    }
    s += __shfl_xor(s, 1);
    q += __shfl_xor(q, 1);
    if (half == 0) {
        atomicAdd(&stats[S_BN2_SUM + co], s);
        atomicAdd(&stats[S_BN2_SQ + co], q);
    }
}

// ---------------- K5: BN2 apply + attention-pool (collapsed) -> x [BE][128] ----------------
__global__ __launch_bounds__(128) void k_predatt(const __half* __restrict__ y3,
                                                 const float* __restrict__ stats,
                                                 const float* __restrict__ att_w,
                                                 const float* __restrict__ att_b,
                                                 const float* __restrict__ pred_w,
                                                 const float* __restrict__ pred_b,
                                                 float* __restrict__ x) {
    __shared__ float h[128 * 45];
    __shared__ float att[44];
    __shared__ float hw[128];
    int be = blockIdx.x;
    int tid = threadIdx.x;
    for (int i = tid; i < 128 * 44; i += 128) {
        int c = i / 44, t = i - c * 44;
        float v = __half2float(y3[(long long)be * 5632 + i]);
        h[c * 45 + t] = fmaf(v, stats[S_BN2_SC + c], stats[S_BN2_SH + c]);
    }
    __syncthreads();
    if (tid < 44) {
        float a = att_b[0];
        for (int c = 0; c < 128; ++c) a = fmaf(h[c * 45 + tid], att_w[c], a);
        att[tid] = a;
    }
    __syncthreads();
    if (tid == 0) {
        float m = -1e30f;
        for (int t = 0; t < 44; ++t) m = fmaxf(m, att[t]);
        float s = 0.f;
        for (int t = 0; t < 44; ++t) { float ev = expf(att[t] - m); att[t] = ev; s += ev; }
        float inv = 1.f / s;
        for (int t = 0; t < 44; ++t) att[t] *= inv;
    }
    __syncthreads();
    {
        int c = tid;
        float a = 0.f;
        for (int t = 0; t < 44; ++t) a = fmaf(h[c * 45 + t], att[t], a);
        hw[c] = a;
    }
    __syncthreads();
    {
        int o = tid;
        float a = pred_b[o];
        for (int c = 0; c < 128; ++c) a = fmaf(pred_w[o * 128 + c], hw[c], a);
        x[(long long)be * 128 + o] = a * (1.0f / 44.0f);
    }
}

// ---------------- generic linear (IN -> 128) + ELU, 8 rows per block ----------------
template <int IN>
__global__ __launch_bounds__(128) void k_linear(const float* __restrict__ in,
                                                const float* __restrict__ W,
                                                const float* __restrict__ bias,
                                                float* __restrict__ out) {
    __shared__ float s_in[8 * IN];
    int r0 = blockIdx.x * 8;
    int j = threadIdx.x;
    for (int i = j; i < 8 * IN; i += 128) s_in[i] = in[(long long)r0 * IN + i];
    __syncthreads();
    float acc[8];
    float bj = bias[j];
#pragma unroll
    for (int e = 0; e < 8; ++e) acc[e] = bj;
    for (int i = 0; i < IN; ++i) {
        float w = W[j * IN + i];
#pragma unroll
        for (int e = 0; e < 8; ++e) acc[e] = fmaf(s_in[e * IN + i], w, acc[e]);
    }
#pragma unroll
    for (int e = 0; e < 8; ++e) out[(long long)(r0 + e) * 128 + j] = eluf(acc[e]);
}

// ---------------- mlp3 layer1: gather-concat [send|recv|skip] (384) -> 128, ELU ----------------
__global__ __launch_bounds__(128) void k_mlp3l1(const float* __restrict__ xn2,
                                                const float* __restrict__ x_skip,
                                                const int* __restrict__ sidx,
                                                const int* __restrict__ ridx,
                                                const float* __restrict__ W,
                                                const float* __restrict__ bias,
                                                float* __restrict__ out) {
    __shared__ float s_in[8 * 384];
    int r0 = blockIdx.x * 8;
    int j = threadIdx.x;
    for (int e = 0; e < 8; ++e) {
        int r = r0 + e;
        int b = r / EE, ed = r - b * EE;
        s_in[e * 384 + j] = xn2[(b * NN + sidx[ed]) * 128 + j];
        s_in[e * 384 + 128 + j] = xn2[(b * NN + ridx[ed]) * 128 + j];
        s_in[e * 384 + 256 + j] = x_skip[(long long)r * 128 + j];
    }
    __syncthreads();
    float acc[8];
    float bj = bias[j];
#pragma unroll
    for (int e = 0; e < 8; ++e) acc[e] = bj;
    for (int i = 0; i < 384; ++i) {
        float w = W[j * 384 + i];
#pragma unroll
        for (int e = 0; e < 8; ++e) acc[e] = fmaf(s_in[e * 384 + i], w, acc[e]);
    }
#pragma unroll
    for (int e = 0; e < 8; ++e) out[(long long)(r0 + e) * 128 + j] = eluf(acc[e]);
}

// ---------------- per-feature (column) stats over [R][128] ----------------
__global__ __launch_bounds__(128) void k_colstats(const float* __restrict__ in,
                                                  float* stats, int sumIdx, int R) {
    int r0 = blockIdx.x * 128;
    int j = threadIdx.x;
    float s = 0.f, q = 0.f;
    int rend = (r0 + 128 < R) ? r0 + 128 : R;
    for (int r = r0; r < rend; ++r) {
        float v = in[(long long)r * 128 + j];
        s += v; q += v * v;
    }
    atomicAdd(&stats[sumIdx + j], s);
    atomicAdd(&stats[sumIdx + 128 + j], q);
}

// ---------------- BN apply (elementwise, per-column scale/shift) ----------------
__global__ __launch_bounds__(256) void k_bnapply(const float* __restrict__ in,
                                                 float* __restrict__ out,
                                                 const float* __restrict__ stats,
                                                 int scIdx, int n) {
    int i = blockIdx.x * 256 + threadIdx.x;
    if (i < n) {
        int j = i & 127;
        out[i] = fmaf(in[i], stats[scIdx + j], stats[scIdx + 128 + j]);
    }
}

// ---------------- edge2node scatter-mean (via incoming-edge lists) ----------------
__global__ __launch_bounds__(128) void k_e2n(const float* __restrict__ x_skip,
                                             const int* __restrict__ inc,
                                             float* __restrict__ xn) {
    int bn = blockIdx.x;
    int b = bn / NN, n = bn - b * NN;
    int j = threadIdx.x;
    float s = 0.f;
    for (int k = 0; k < NN - 1; ++k) {
        int e = inc[n * (NN - 1) + k];
        s += x_skip[(long long)(b * EE + e) * 128 + j];
    }
    xn[bn * 128 + j] = s * (1.0f / (float)NN);
}

// ---------------- BN3 apply + fc_out (128 -> 16) ----------------
__global__ __launch_bounds__(256) void k_fcout(const float* __restrict__ h2,
                                               const float* __restrict__ stats,
                                               const float* __restrict__ fcw,
                                               const float* __restrict__ fcb,
                                               float* __restrict__ out) {
    __shared__ float s_x[16 * 129];
    __shared__ float s_w[16 * 129];
    int r0 = blockIdx.x * 16;
    int tid = threadIdx.x;
    for (int i = tid; i < 16 * 128; i += 256) {
        int rr = i >> 7, j = i & 127;
        s_x[rr * 129 + j] = fmaf(h2[(long long)(r0 + rr) * 128 + j],
                                 stats[S_M3_SC + j], stats[S_M3_SH + j]);
    }
    for (int i = tid; i < 16 * 128; i += 256) {
        int o = i >> 7, j = i & 127;
        s_w[o * 129 + j] = fcw[i];
    }
    __syncthreads();
    int rl = tid >> 4, o = tid & 15;
    float a = fcb[o];
    for (int j = 0; j < 128; ++j) a = fmaf(s_x[rl * 129 + j], s_w[o * 129 + j], a);
    out[(long long)(r0 + rl) * 16 + o] = a;
}

// ---------------- host launcher ----------------
extern "C" void kernel_launch(void* const* d_in, const int* in_sizes, int n_in,
                              void* d_out, int out_size, void* d_ws, size_t ws_size,
                              hipStream_t stream) {
    const float* inputs = (const float*)d_in[0];
    const float* rel_rec = (const float*)d_in[1];
    const float* rel_send = (const float*)d_in[2];
    const float* conv1_w = (const float*)d_in[3];
    const float* conv1_b = (const float*)d_in[4];
    const float* bn1_g = (const float*)d_in[5];
    const float* bn1_b = (const float*)d_in[6];
    const float* conv2_w = (const float*)d_in[7];
    const float* conv2_b = (const float*)d_in[8];
    const float* bn2_g = (const float*)d_in[9];
    const float* bn2_b = (const float*)d_in[10];
    const float* pred_w = (const float*)d_in[11];
    const float* pred_b = (const float*)d_in[12];
    const float* att_w = (const float*)d_in[13];
    const float* att_b = (const float*)d_in[14];
    const float* m1w1 = (const float*)d_in[15];
    const float* m1b1 = (const float*)d_in[16];
    const float* m1w2 = (const float*)d_in[17];
    const float* m1b2 = (const float*)d_in[18];
    const float* m1g = (const float*)d_in[19];
    const float* m1bb = (const float*)d_in[20];
    const float* m2w1 = (const float*)d_in[21];
    const float* m2b1 = (const float*)d_in[22];
    const float* m2w2 = (const float*)d_in[23];
    const float* m2b2 = (const float*)d_in[24];
    const float* m2g = (const float*)d_in[25];
    const float* m2bb = (const float*)d_in[26];
    const float* m3w1 = (const float*)d_in[27];
    const float* m3b1 = (const float*)d_in[28];
    const float* m3w2 = (const float*)d_in[29];
    const float* m3b2 = (const float*)d_in[30];
    const float* m3g = (const float*)d_in[31];
    const float* m3bb = (const float*)d_in[32];
    const float* fcw = (const float*)d_in[33];
    const float* fcb = (const float*)d_in[34];

    char* ws = (char*)d_ws;
    float* stats = (float*)(ws + OFF_STATS);
    int* sidx = (int*)(ws + OFF_SIDX);
    int* ridx = (int*)(ws + OFF_RIDX);
    int* inc = (int*)(ws + OFF_INC);
    __half* y3 = (__half*)(ws + OFF_Y3);
    float* x = (float*)(ws + OFF_X);
    float* bufA = (float*)(ws + OFF_BUFA);
    float* bufB = (float*)(ws + OFF_BUFB);
    float* x_skip = (float*)(ws + OFF_SKIP);
    float* xn = (float*)(ws + OFF_XN);
    float* t640 = (float*)(ws + OFF_T640);
    float* xn2 = (float*)(ws + OFF_XN2);
    float* outp = (float*)d_out;

    hipLaunchKernelGGL(k_init, dim3(1), dim3(256), 0, stream,
                       rel_rec, rel_send, stats, sidx, ridx, inc);
    hipLaunchKernelGGL(k_conv1_stats, dim3(BE), dim3(256), 0, stream,
                       inputs, conv1_w, conv1_b, sidx, ridx, stats);
    hipLaunchKernelGGL(k_finalize, dim3(1), dim3(128), 0, stream,
                       stats, S_BN1_SUM, bn1_g, bn1_b, 1.0f / (float)(BE * L1));
    hipLaunchKernelGGL(k_conv2, dim3(BE), dim3(256), 0, stream,
                       inputs, conv1_w, conv1_b, conv2_w, conv2_b, sidx, ridx, stats, y3);
    hipLaunchKernelGGL(k_finalize, dim3(1), dim3(128), 0, stream,
                       stats, S_BN2_SUM, bn2_g, bn2_b, 1.0f / (float)(BE * L2));
    hipLaunchKernelGGL(k_predatt, dim3(BE), dim3(128), 0, stream,
                       y3, stats, att_w, att_b, pred_w, pred_b, x);
    // mlp1
    hipLaunchKernelGGL(k_linear<128>, dim3(BE / 8), dim3(128), 0, stream, x, m1w1, m1b1, bufA);
    hipLaunchKernelGGL(k_linear<128>, dim3(BE / 8), dim3(128), 0, stream, bufA, m1w2, m1b2, bufB);
    hipLaunchKernelGGL(k_colstats, dim3(BE / 128), dim3(128), 0, stream, bufB, stats, S_M1_SUM, BE);
    hipLaunchKernelGGL(k_finalize, dim3(1), dim3(128), 0, stream,
                       stats, S_M1_SUM, m1g, m1bb, 1.0f / (float)BE);
    hipLaunchKernelGGL(k_bnapply, dim3(BE * 128 / 256), dim3(256), 0, stream,
                       bufB, x_skip, stats, S_M1_SC, BE * 128);
    // edge2node + mlp2
    hipLaunchKernelGGL(k_e2n, dim3(BB * NN), dim3(128), 0, stream, x_skip, inc, xn);
    hipLaunchKernelGGL(k_linear<128>, dim3(BB * NN / 8), dim3(128), 0, stream, xn, m2w1, m2b1, t640);
    hipLaunchKernelGGL(k_linear<128>, dim3(BB * NN / 8), dim3(128), 0, stream, t640, m2w2, m2b2, xn);
    hipLaunchKernelGGL(k_colstats, dim3(BB * NN / 128), dim3(128), 0, stream, xn, stats, S_M2_SUM, BB * NN);
    hipLaunchKernelGGL(k_finalize, dim3(1), dim3(128), 0, stream,
                       stats, S_M2_SUM, m2g, m2bb, 1.0f / (float)(BB * NN));
    hipLaunchKernelGGL(k_bnapply, dim3(BB * NN * 128 / 256), dim3(256), 0, stream,
                       xn, xn2, stats, S_M2_SC, BB * NN * 128);
    // node2edge + mlp3
    hipLaunchKernelGGL(k_mlp3l1, dim3(BE / 8), dim3(128), 0, stream,
                       xn2, x_skip, sidx, ridx, m3w1, m3b1, bufA);
    hipLaunchKernelGGL(k_linear<128>, dim3(BE / 8), dim3(128), 0, stream, bufA, m3w2, m3b2, bufB);
    hipLaunchKernelGGL(k_colstats, dim3(BE / 128), dim3(128), 0, stream, bufB, stats, S_M3_SUM, BE);
    hipLaunchKernelGGL(k_finalize, dim3(1), dim3(128), 0, stream,
                       stats, S_M3_SUM, m3g, m3bb, 1.0f / (float)BE);
    // fc_out
    hipLaunchKernelGGL(k_fcout, dim3(BE / 16), dim3(256), 0, stream, bufB, stats, fcw, fcb, outp);
    (void)in_sizes; (void)n_in; (void)out_size; (void)ws_size;
}

// Round 4
// 2070.452 us; speedup vs baseline: 9.4564x; 1.6856x over previous
//
#include <hip/hip_runtime.h>
#include <hip/hip_bf16.h>
#include <hip/hip_fp16.h>

// ---------------- problem constants ----------------
#define BB 32
#define NN 20
#define TT 100
#define DD 4
#define HH 128
#define EE 380          // N*(N-1)
#define BE 12160        // B*E
#define L1 96           // conv1 out length
#define LP 48           // after maxpool
#define L2 44           // conv2 out length
#define NOUT 16
#define EPS 1e-5f

typedef _Float16 f16x8 __attribute__((ext_vector_type(8)));
typedef float f32x4 __attribute__((ext_vector_type(4)));

// stats slot indices (floats)
#define S_BN1_SUM 0
#define S_BN1_SQ 128
#define S_BN1_SC 256
#define S_BN1_SH 384
#define S_BN2_SUM 512
#define S_BN2_SQ 640
#define S_BN2_SC 768
#define S_BN2_SH 896
#define S_M1_SUM 1024
#define S_M1_SQ 1152
#define S_M1_SC 1280
#define S_M1_SH 1408
#define S_M2_SUM 1536
#define S_M2_SQ 1664
#define S_M2_SC 1792
#define S_M2_SH 1920
#define S_M3_SUM 2048
#define S_M3_SQ 2176
#define S_M3_SC 2304
#define S_M3_SH 2432
#define S_COUNT 2560

// workspace offsets (bytes)
#define OFF_STATS 0ULL
#define OFF_SIDX 16384ULL
#define OFF_RIDX 18432ULL
#define OFF_INC 20480ULL
#define OFF_Y3 24576ULL                      // fp16 [BE][128][44]
#define OFF_X 136994816ULL                   // f32 [BE][128]
#define OFF_BUFA 143220736ULL                // f32 [BE][128]
#define OFF_BUFB 149446656ULL                // f32 [BE][128]
#define OFF_SKIP 155672576ULL                // f32 [BE][128]
#define OFF_XN 161898496ULL                  // f32 [640][128]
#define OFF_T640 162226176ULL                // f32 [640][128]; ALSO holds Apack (f16, 160KB) during conv2 phase — t640 only used later
#define OFF_XN2 162553856ULL                 // f32 [640][128]
#define OFF_APACK OFF_T640

__device__ __forceinline__ float eluf(float v) { return v > 0.f ? v : expm1f(v); }

// ---------------- K0: zero stats + edge index tables ----------------
__global__ void k_init(const float* __restrict__ rel_rec, const float* __restrict__ rel_send,
                       float* stats, int* sidx, int* ridx, int* inc) {
    int tid = threadIdx.x;
    for (int i = tid; i < S_COUNT; i += 256) stats[i] = 0.f;
    for (int e = tid; e < EE; e += 256) {
        int s = 0, r = 0;
        for (int n = 0; n < NN; ++n) {
            if (rel_send[e * NN + n] > 0.5f) s = n;
            if (rel_rec[e * NN + n] > 0.5f) r = n;
        }
        sidx[e] = s; ridx[e] = r;
    }
    __syncthreads();
    if (tid < NN) {
        int k = 0;
        for (int e = 0; e < EE; ++e)
            if (ridx[e] == tid) inc[tid * (NN - 1) + (k++)] = e;
    }
}

// ---------------- K pack: conv2_w -> f16 A-fragment-linear layout ----------------
// Frag f=(k*4+s)*8+m0: lane l holds A[m=m0*16+(l&15)][ci=32s+(l>>4)*8+j] of W_k
// Apack[(f*64+l)*8 + j]. 160 frags * 64 lanes * 8 = 81920 f16 = 160 KB.
__global__ void k_pack(const float* __restrict__ w2, _Float16* __restrict__ apack) {
    int f = blockIdx.x;       // 0..159
    int l = threadIdx.x;      // 0..63
    int m0 = f & 7, ks = f >> 3, s = ks & 3, k = ks >> 2;
    int m = m0 * 16 + (l & 15);
    int cbase = 32 * s + (l >> 4) * 8;
#pragma unroll
    for (int j = 0; j < 8; ++j)
        apack[(f * 64 + l) * 8 + j] = (_Float16)w2[m * 640 + (cbase + j) * 5 + k];
}

// conv1 unit: one output channel o, pre-pool t-range [lc*24, lc*24+24) -> 24 relu'd values
__device__ __forceinline__ void conv1_unit(const float* s_edges /*[8][100]*/,
                                           const float* s_w1 /*[128][40]*/,
                                           int o, int lc, float bias, float v[24]) {
    float acc[24];
#pragma unroll
    for (int t = 0; t < 24; ++t) acc[t] = bias;
#pragma unroll
    for (int ci = 0; ci < 8; ++ci) {
        float win[28];
        const float4* p = reinterpret_cast<const float4*>(s_edges + ci * 100 + lc * 24);
#pragma unroll
        for (int q = 0; q < 7; ++q) {
            float4 f = p[q];
            win[4 * q + 0] = f.x; win[4 * q + 1] = f.y;
            win[4 * q + 2] = f.z; win[4 * q + 3] = f.w;
        }
        const float* wr = s_w1 + o * 40 + ci * 5;
#pragma unroll
        for (int k = 0; k < 5; ++k) {
            float w = wr[k];
#pragma unroll
            for (int t = 0; t < 24; ++t) acc[t] = fmaf(win[t + k], w, acc[t]);
        }
    }
#pragma unroll
    for (int t = 0; t < 24; ++t) v[t] = fmaxf(acc[t], 0.f);
}

__device__ __forceinline__ void load_edges_w1(float* s_edges, float* s_w1,
                                              const float* __restrict__ inputs,
                                              const float* __restrict__ conv1_w,
                                              int b, int sn, int rn) {
    for (int i = threadIdx.x; i < 800; i += 256) {
        int ci = i / 100, t = i - ci * 100;
        int n = (ci < 4) ? sn : rn;
        int d = ci & 3;
        s_edges[ci * 100 + t] = inputs[((b * NN + n) * TT + t) * DD + d];
    }
    for (int i = threadIdx.x; i < 5120; i += 256) s_w1[i] = conv1_w[i];
}

// ---------------- K1: conv1 + relu, accumulate BN1 stats (no store) ----------------
__global__ __launch_bounds__(256) void k_conv1_stats(const float* __restrict__ inputs,
                                                     const float* __restrict__ conv1_w,
                                                     const float* __restrict__ conv1_b,
                                                     const int* __restrict__ sidx,
                                                     const int* __restrict__ ridx,
                                                     float* stats) {
    __shared__ float s_edges[8 * 100];
    __shared__ float s_w1[128 * 40];
    int be = blockIdx.x;
    int b = be / EE, e = be - b * EE;
    load_edges_w1(s_edges, s_w1, inputs, conv1_w, b, sidx[e], ridx[e]);
    __syncthreads();
#pragma unroll
    for (int u = 0; u < 2; ++u) {
        int unit = threadIdx.x + u * 256;
        int o = unit >> 2, lc = unit & 3;
        float v[24];
        conv1_unit(s_edges, s_w1, o, lc, conv1_b[o], v);
        float s = 0.f, q = 0.f;
#pragma unroll
        for (int t = 0; t < 24; ++t) { s += v[t]; q += v[t] * v[t]; }
        s += __shfl_xor(s, 1); s += __shfl_xor(s, 2);
        q += __shfl_xor(q, 1); q += __shfl_xor(q, 2);
        if ((threadIdx.x & 3) == 0) {
            atomicAdd(&stats[S_BN1_SUM + o], s);
            atomicAdd(&stats[S_BN1_SQ + o], q);
        }
    }
}

// ---------------- finalize BN: scale/shift from sum/sumsq ----------------
__global__ void k_finalize(float* stats, int sumIdx, const float* __restrict__ g,
                           const float* __restrict__ bb, float inv_count) {
    int j = threadIdx.x;
    float m = stats[sumIdx + j] * inv_count;
    float v = fmaxf(stats[sumIdx + 128 + j] * inv_count - m * m, 0.f);
    float sc = g[j] * rsqrtf(v + EPS);
    stats[sumIdx + 256 + j] = sc;
    stats[sumIdx + 384 + j] = bb[j] - m * sc;
}

// ---------------- K3: conv1(recompute)+BN1+pool -> LDS f16 (t-major), then conv2 via f16 MFMA ----------------
// conv2 as 5 shifted GEMMs (one per tap k): C[co][t] += W_k[co][:] . y2[:][t+k]
// y2t LDS layout: [52 rows t][136 f16] (rows 48..51 zero; +8 f16 pad spreads banks).
// B-frag (16x16x32): lane reads y2t[(nt*16+l15)+k][32s+quad*8 ..+7] = one ds_read_b128.
// A-frags from Apack (global, L2-hot). Each of 4 waves: mtiles {2w,2w+1} x ntiles {0,1,2}.
__global__ __launch_bounds__(256) void k_conv2(const float* __restrict__ inputs,
                                               const float* __restrict__ conv1_w,
                                               const float* __restrict__ conv1_b,
                                               const _Float16* __restrict__ apack,
                                               const float* __restrict__ conv2_b,
                                               const int* __restrict__ sidx,
                                               const int* __restrict__ ridx,
                                               float* stats,
                                               __half* __restrict__ y3h) {
    __shared__ float s_edges[8 * 100];
    __shared__ float s_w1[128 * 40];
    __shared__ __align__(16) _Float16 s_y2t[52 * 136];

    int be = blockIdx.x;
    int b = be / EE, e = be - b * EE;
    load_edges_w1(s_edges, s_w1, inputs, conv1_w, b, sidx[e], ridx[e]);
    // zero pad rows 48..51 (read by B-frags at n+k>=48; outputs there are discarded)
    {
        int* z = (int*)&s_y2t[48 * 136];
        for (int i = threadIdx.x; i < 272; i += 256) z[i] = 0;
    }
    __syncthreads();
    // phase 2: conv1 + BN1 + maxpool -> s_y2t (f16, t-major)
#pragma unroll
    for (int u = 0; u < 2; ++u) {
        int unit = threadIdx.x + u * 256;
        int o = unit >> 2, lc = unit & 3;
        float v[24];
        conv1_unit(s_edges, s_w1, o, lc, conv1_b[o], v);
        float sc = stats[S_BN1_SC + o], sh = stats[S_BN1_SH + o];
#pragma unroll
        for (int l = 0; l < 12; ++l) {
            float a = fmaf(v[2 * l], sc, sh);
            float c = fmaf(v[2 * l + 1], sc, sh);
            s_y2t[(lc * 12 + l) * 136 + o] = (_Float16)fmaxf(a, c);
        }
    }
    __syncthreads();
    // phase 3: MFMA GEMM
    int w = threadIdx.x >> 6;
    int lane = threadIdx.x & 63;
    int quad = lane >> 4, l15 = lane & 15;
    f32x4 acc[2][3];
#pragma unroll
    for (int m = 0; m < 2; ++m)
#pragma unroll
        for (int nt = 0; nt < 3; ++nt) acc[m][nt] = (f32x4){0.f, 0.f, 0.f, 0.f};

    const f16x8* Ap = (const f16x8*)apack;
#pragma unroll
    for (int k = 0; k < 5; ++k) {
#pragma unroll
        for (int s = 0; s < 4; ++s) {
            f16x8 a0 = Ap[((k * 4 + s) * 8 + 2 * w) * 64 + lane];
            f16x8 a1 = Ap[((k * 4 + s) * 8 + 2 * w + 1) * 64 + lane];
#pragma unroll
            for (int nt = 0; nt < 3; ++nt) {
                const f16x8* bp = (const f16x8*)((const char*)s_y2t +
                                                 (nt * 16 + l15 + k) * 272 + 64 * s + quad * 16);
                f16x8 bfr = *bp;
                acc[0][nt] = __builtin_amdgcn_mfma_f32_16x16x32_f16(a0, bfr, acc[0][nt], 0, 0, 0);
                acc[1][nt] = __builtin_amdgcn_mfma_f32_16x16x32_f16(a1, bfr, acc[1][nt], 0, 0, 0);
            }
        }
    }
    // epilogue: bias + relu, store f16 y3, BN2 stats via shuffle-reduce
    _Float16* y3 = (_Float16*)y3h;
#pragma unroll
    for (int m = 0; m < 2; ++m) {
        int co0 = (2 * w + m) * 16 + quad * 4;
        float ssum[4] = {0.f, 0.f, 0.f, 0.f}, qsum[4] = {0.f, 0.f, 0.f, 0.f};
#pragma unroll
        for (int nt = 0; nt < 3; ++nt) {
            int t = nt * 16 + l15;
            bool valid = t < 44;
#pragma unroll
            for (int r = 0; r < 4; ++r) {
                float v = fmaxf(acc[m][nt][r] + conv2_b[co0 + r], 0.f);
                if (valid) {
                    y3[((long long)be * 128 + co0 + r) * 44 + t] = (_Float16)v;
                    ssum[r] += v; qsum[r] += v * v;
                }
            }
        }
#pragma unroll
        for (int r = 0; r < 4; ++r) {
            float s = ssum[r], q = qsum[r];
            s += __shfl_xor(s, 1); s += __shfl_xor(s, 2); s += __shfl_xor(s, 4); s += __shfl_xor(s, 8);
            q += __shfl_xor(q, 1); q += __shfl_xor(q, 2); q += __shfl_xor(q, 4); q += __shfl_xor(q, 8);
            if (l15 == 0) {
                atomicAdd(&stats[S_BN2_SUM + co0 + r], s);
                atomicAdd(&stats[S_BN2_SQ + co0 + r], q);
            }
        }
    }
}

// ---------------- K5: BN2 apply + attention-pool (collapsed) -> x [BE][128] ----------------
__global__ __launch_bounds__(128) void k_predatt(const __half* __restrict__ y3,
                                                 const float* __restrict__ stats,
                                                 const float* __restrict__ att_w,
                                                 const float* __restrict__ att_b,
                                                 const float* __restrict__ pred_w,
                                                 const float* __restrict__ pred_b,
                                                 float* __restrict__ x) {
    __shared__ float h[128 * 45];
    __shared__ float att[44];
    __shared__ float hw[128];
    int be = blockIdx.x;
    int tid = threadIdx.x;
    for (int i = tid; i < 128 * 44; i += 128) {
        int c = i / 44, t = i - c * 44;
        float v = __half2float(y3[(long long)be * 5632 + i]);
        h[c * 45 + t] = fmaf(v, stats[S_BN2_SC + c], stats[S_BN2_SH + c]);
    }
    __syncthreads();
    if (tid < 44) {
        float a = att_b[0];
        for (int c = 0; c < 128; ++c) a = fmaf(h[c * 45 + tid], att_w[c], a);
        att[tid] = a;
    }
    __syncthreads();
    if (tid == 0) {
        float m = -1e30f;
        for (int t = 0; t < 44; ++t) m = fmaxf(m, att[t]);
        float s = 0.f;
        for (int t = 0; t < 44; ++t) { float ev = expf(att[t] - m); att[t] = ev; s += ev; }
        float inv = 1.f / s;
        for (int t = 0; t < 44; ++t) att[t] *= inv;
    }
    __syncthreads();
    {
        int c = tid;
        float a = 0.f;
        for (int t = 0; t < 44; ++t) a = fmaf(h[c * 45 + t], att[t], a);
        hw[c] = a;
    }
    __syncthreads();
    {
        int o = tid;
        float a = pred_b[o];
        for (int c = 0; c < 128; ++c) a = fmaf(pred_w[o * 128 + c], hw[c], a);
        x[(long long)be * 128 + o] = a * (1.0f / 44.0f);
    }
}

// ---------------- generic linear (IN -> 128) + ELU, 8 rows per block ----------------
template <int IN>
__global__ __launch_bounds__(128) void k_linear(const float* __restrict__ in,
                                                const float* __restrict__ W,
                                                const float* __restrict__ bias,
                                                float* __restrict__ out) {
    __shared__ float s_in[8 * IN];
    int r0 = blockIdx.x * 8;
    int j = threadIdx.x;
    for (int i = j; i < 8 * IN; i += 128) s_in[i] = in[(long long)r0 * IN + i];
    __syncthreads();
    float acc[8];
    float bj = bias[j];
#pragma unroll
    for (int e = 0; e < 8; ++e) acc[e] = bj;
    for (int i = 0; i < IN; ++i) {
        float w = W[j * IN + i];
#pragma unroll
        for (int e = 0; e < 8; ++e) acc[e] = fmaf(s_in[e * IN + i], w, acc[e]);
    }
#pragma unroll
    for (int e = 0; e < 8; ++e) out[(long long)(r0 + e) * 128 + j] = eluf(acc[e]);
}

// ---------------- mlp3 layer1: gather-concat [send|recv|skip] (384) -> 128, ELU ----------------
__global__ __launch_bounds__(128) void k_mlp3l1(const float* __restrict__ xn2,
                                                const float* __restrict__ x_skip,
                                                const int* __restrict__ sidx,
                                                const int* __restrict__ ridx,
                                                const float* __restrict__ W,
                                                const float* __restrict__ bias,
                                                float* __restrict__ out) {
    __shared__ float s_in[8 * 384];
    int r0 = blockIdx.x * 8;
    int j = threadIdx.x;
    for (int e = 0; e < 8; ++e) {
        int r = r0 + e;
        int b = r / EE, ed = r - b * EE;
        s_in[e * 384 + j] = xn2[(b * NN + sidx[ed]) * 128 + j];
        s_in[e * 384 + 128 + j] = xn2[(b * NN + ridx[ed]) * 128 + j];
        s_in[e * 384 + 256 + j] = x_skip[(long long)r * 128 + j];
    }
    __syncthreads();
    float acc[8];
    float bj = bias[j];
#pragma unroll
    for (int e = 0; e < 8; ++e) acc[e] = bj;
    for (int i = 0; i < 384; ++i) {
        float w = W[j * 384 + i];
#pragma unroll
        for (int e = 0; e < 8; ++e) acc[e] = fmaf(s_in[e * 384 + i], w, acc[e]);
    }
#pragma unroll
    for (int e = 0; e < 8; ++e) out[(long long)(r0 + e) * 128 + j] = eluf(acc[e]);
}

// ---------------- per-feature (column) stats over [R][128] ----------------
__global__ __launch_bounds__(128) void k_colstats(const float* __restrict__ in,
                                                  float* stats, int sumIdx, int R) {
    int r0 = blockIdx.x * 128;
    int j = threadIdx.x;
    float s = 0.f, q = 0.f;
    int rend = (r0 + 128 < R) ? r0 + 128 : R;
    for (int r = r0; r < rend; ++r) {
        float v = in[(long long)r * 128 + j];
        s += v; q += v * v;
    }
    atomicAdd(&stats[sumIdx + j], s);
    atomicAdd(&stats[sumIdx + 128 + j], q);
}

// ---------------- BN apply (elementwise, per-column scale/shift) ----------------
__global__ __launch_bounds__(256) void k_bnapply(const float* __restrict__ in,
                                                 float* __restrict__ out,
                                                 const float* __restrict__ stats,
                                                 int scIdx, int n) {
    int i = blockIdx.x * 256 + threadIdx.x;
    if (i < n) {
        int j = i & 127;
        out[i] = fmaf(in[i], stats[scIdx + j], stats[scIdx + 128 + j]);
    }
}

// ---------------- edge2node scatter-mean (via incoming-edge lists) ----------------
__global__ __launch_bounds__(128) void k_e2n(const float* __restrict__ x_skip,
                                             const int* __restrict__ inc,
                                             float* __restrict__ xn) {
    int bn = blockIdx.x;
    int b = bn / NN, n = bn - b * NN;
    int j = threadIdx.x;
    float s = 0.f;
    for (int k = 0; k < NN - 1; ++k) {
        int e = inc[n * (NN - 1) + k];
        s += x_skip[(long long)(b * EE + e) * 128 + j];
    }
    xn[bn * 128 + j] = s * (1.0f / (float)NN);
}

// ---------------- BN3 apply + fc_out (128 -> 16) ----------------
__global__ __launch_bounds__(256) void k_fcout(const float* __restrict__ h2,
                                               const float* __restrict__ stats,
                                               const float* __restrict__ fcw,
                                               const float* __restrict__ fcb,
                                               float* __restrict__ out) {
    __shared__ float s_x[16 * 129];
    __shared__ float s_w[16 * 129];
    int r0 = blockIdx.x * 16;
    int tid = threadIdx.x;
    for (int i = tid; i < 16 * 128; i += 256) {
        int rr = i >> 7, j = i & 127;
        s_x[rr * 129 + j] = fmaf(h2[(long long)(r0 + rr) * 128 + j],
                                 stats[S_M3_SC + j], stats[S_M3_SH + j]);
    }
    for (int i = tid; i < 16 * 128; i += 256) {
        int o = i >> 7, j = i & 127;
        s_w[o * 129 + j] = fcw[i];
    }
    __syncthreads();
    int rl = tid >> 4, o = tid & 15;
    float a = fcb[o];
    for (int j = 0; j < 128; ++j) a = fmaf(s_x[rl * 129 + j], s_w[o * 129 + j], a);
    out[(long long)(r0 + rl) * 16 + o] = a;
}

// ---------------- host launcher ----------------
extern "C" void kernel_launch(void* const* d_in, const int* in_sizes, int n_in,
                              void* d_out, int out_size, void* d_ws, size_t ws_size,
                              hipStream_t stream) {
    const float* inputs = (const float*)d_in[0];
    const float* rel_rec = (const float*)d_in[1];
    const float* rel_send = (const float*)d_in[2];
    const float* conv1_w = (const float*)d_in[3];
    const float* conv1_b = (const float*)d_in[4];
    const float* bn1_g = (const float*)d_in[5];
    const float* bn1_b = (const float*)d_in[6];
    const float* conv2_w = (const float*)d_in[7];
    const float* conv2_b = (const float*)d_in[8];
    const float* bn2_g = (const float*)d_in[9];
    const float* bn2_b = (const float*)d_in[10];
    const float* pred_w = (const float*)d_in[11];
    const float* pred_b = (const float*)d_in[12];
    const float* att_w = (const float*)d_in[13];
    const float* att_b = (const float*)d_in[14];
    const float* m1w1 = (const float*)d_in[15];
    const float* m1b1 = (const float*)d_in[16];
    const float* m1w2 = (const float*)d_in[17];
    const float* m1b2 = (const float*)d_in[18];
    const float* m1g = (const float*)d_in[19];
    const float* m1bb = (const float*)d_in[20];
    const float* m2w1 = (const float*)d_in[21];
    const float* m2b1 = (const float*)d_in[22];
    const float* m2w2 = (const float*)d_in[23];
    const float* m2b2 = (const float*)d_in[24];
    const float* m2g = (const float*)d_in[25];
    const float* m2bb = (const float*)d_in[26];
    const float* m3w1 = (const float*)d_in[27];
    const float* m3b1 = (const float*)d_in[28];
    const float* m3w2 = (const float*)d_in[29];
    const float* m3b2 = (const float*)d_in[30];
    const float* m3g = (const float*)d_in[31];
    const float* m3bb = (const float*)d_in[32];
    const float* fcw = (const float*)d_in[33];
    const float* fcb = (const float*)d_in[34];

    char* ws = (char*)d_ws;
    float* stats = (float*)(ws + OFF_STATS);
    int* sidx = (int*)(ws + OFF_SIDX);
    int* ridx = (int*)(ws + OFF_RIDX);
    int* inc = (int*)(ws + OFF_INC);
    __half* y3 = (__half*)(ws + OFF_Y3);
    float* x = (float*)(ws + OFF_X);
    float* bufA = (float*)(ws + OFF_BUFA);
    float* bufB = (float*)(ws + OFF_BUFB);
    float* x_skip = (float*)(ws + OFF_SKIP);
    float* xn = (float*)(ws + OFF_XN);
    float* t640 = (float*)(ws + OFF_T640);
    float* xn2 = (float*)(ws + OFF_XN2);
    _Float16* apack = (_Float16*)(ws + OFF_APACK);
    float* outp = (float*)d_out;

    hipLaunchKernelGGL(k_init, dim3(1), dim3(256), 0, stream,
                       rel_rec, rel_send, stats, sidx, ridx, inc);
    hipLaunchKernelGGL(k_pack, dim3(160), dim3(64), 0, stream, conv2_w, apack);
    hipLaunchKernelGGL(k_conv1_stats, dim3(BE), dim3(256), 0, stream,
                       inputs, conv1_w, conv1_b, sidx, ridx, stats);
    hipLaunchKernelGGL(k_finalize, dim3(1), dim3(128), 0, stream,
                       stats, S_BN1_SUM, bn1_g, bn1_b, 1.0f / (float)(BE * L1));
    hipLaunchKernelGGL(k_conv2, dim3(BE), dim3(256), 0, stream,
                       inputs, conv1_w, conv1_b, apack, conv2_b, sidx, ridx, stats, y3);
    hipLaunchKernelGGL(k_finalize, dim3(1), dim3(128), 0, stream,
                       stats, S_BN2_SUM, bn2_g, bn2_b, 1.0f / (float)(BE * L2));
    hipLaunchKernelGGL(k_predatt, dim3(BE), dim3(128), 0, stream,
                       y3, stats, att_w, att_b, pred_w, pred_b, x);
    // mlp1
    hipLaunchKernelGGL(k_linear<128>, dim3(BE / 8), dim3(128), 0, stream, x, m1w1, m1b1, bufA);
    hipLaunchKernelGGL(k_linear<128>, dim3(BE / 8), dim3(128), 0, stream, bufA, m1w2, m1b2, bufB);
    hipLaunchKernelGGL(k_colstats, dim3(BE / 128), dim3(128), 0, stream, bufB, stats, S_M1_SUM, BE);
    hipLaunchKernelGGL(k_finalize, dim3(1), dim3(128), 0, stream,
                       stats, S_M1_SUM, m1g, m1bb, 1.0f / (float)BE);
    hipLaunchKernelGGL(k_bnapply, dim3(BE * 128 / 256), dim3(256), 0, stream,
                       bufB, x_skip, stats, S_M1_SC, BE * 128);
    // edge2node + mlp2
    hipLaunchKernelGGL(k_e2n, dim3(BB * NN), dim3(128), 0, stream, x_skip, inc, xn);
    hipLaunchKernelGGL(k_linear<128>, dim3(BB * NN / 8), dim3(128), 0, stream, xn, m2w1, m2b1, t640);
    hipLaunchKernelGGL(k_linear<128>, dim3(BB * NN / 8), dim3(128), 0, stream, t640, m2w2, m2b2, xn);
    hipLaunchKernelGGL(k_colstats, dim3(BB * NN / 128), dim3(128), 0, stream, xn, stats, S_M2_SUM, BB * NN);
    hipLaunchKernelGGL(k_finalize, dim3(1), dim3(128), 0, stream,
                       stats, S_M2_SUM, m2g, m2bb, 1.0f / (float)(BB * NN));
    hipLaunchKernelGGL(k_bnapply, dim3(BB * NN * 128 / 256), dim3(256), 0, stream,
                       xn, xn2, stats, S_M2_SC, BB * NN * 128);
    // node2edge + mlp3
    hipLaunchKernelGGL(k_mlp3l1, dim3(BE / 8), dim3(128), 0, stream,
                       xn2, x_skip, sidx, ridx, m3w1, m3b1, bufA);
    hipLaunchKernelGGL(k_linear<128>, dim3(BE / 8), dim3(128), 0, stream, bufA, m3w2, m3b2, bufB);
    hipLaunchKernelGGL(k_colstats, dim3(BE / 128), dim3(128), 0, stream, bufB, stats, S_M3_SUM, BE);
    hipLaunchKernelGGL(k_finalize, dim3(1), dim3(128), 0, stream,
                       stats, S_M3_SUM, m3g, m3bb, 1.0f / (float)BE);
    // fc_out
    hipLaunchKernelGGL(k_fcout, dim3(BE / 16), dim3(256), 0, stream, bufB, stats, fcw, fcb, outp);
    (void)in_sizes; (void)n_in; (void)out_size; (void)ws_size;
}

// Round 5
// 1017.878 us; speedup vs baseline: 19.2351x; 2.0341x over previous
//
#include <hip/hip_runtime.h>
#include <hip/hip_bf16.h>
#include <hip/hip_fp16.h>

// ---------------- problem constants ----------------
#define BB 32
#define NN 20
#define TT 100
#define DD 4
#define HH 128
#define EE 380          // N*(N-1)
#define BE 12160        // B*E
#define L1 96           // conv1 out length
#define LP 48           // after maxpool
#define L2 44           // conv2 out length
#define NOUT 16
#define EPS 1e-5f
#define NREP 64         // stats replicas (atomic de-contention)

typedef _Float16 f16x8 __attribute__((ext_vector_type(8)));
typedef float f32x4 __attribute__((ext_vector_type(4)));

// stats slot indices (floats)
#define S_BN1_SUM 0
#define S_BN1_SQ 128
#define S_BN1_SC 256
#define S_BN1_SH 384
#define S_BN2_SUM 512
#define S_BN2_SQ 640
#define S_BN2_SC 768
#define S_BN2_SH 896
#define S_M1_SUM 1024
#define S_M1_SQ 1152
#define S_M1_SC 1280
#define S_M1_SH 1408
#define S_M2_SUM 1536
#define S_M2_SQ 1664
#define S_M2_SC 1792
#define S_M2_SH 1920
#define S_M3_SUM 2048
#define S_M3_SQ 2176
#define S_M3_SC 2304
#define S_M3_SH 2432
#define S_COUNT 2560

// workspace offsets (bytes)
#define OFF_STATS 0ULL
#define OFF_SIDX 16384ULL
#define OFF_RIDX 18432ULL
#define OFF_INC 20480ULL
#define OFF_Y3 24576ULL                      // fp16 [BE][128][44]
#define OFF_X 136994816ULL                   // f32 [BE][128]
#define OFF_BUFA 143220736ULL                // f32 [BE][128]; first 128KB doubles as BN1/BN2 replicas before mlp1
#define OFF_BUFB 149446656ULL                // f32 [BE][128]
#define OFF_SKIP 155672576ULL                // f32 [BE][128]
#define OFF_XN 161898496ULL                  // f32 [640][128]
#define OFF_T640 162226176ULL                // f32 [640][128]; ALSO holds Apack (f16, 160KB) during conv2 phase
#define OFF_XN2 162553856ULL                 // f32 [640][128]
#define OFF_APACK OFF_T640
#define OFF_REP1 OFF_BUFA                    // f32 [64][256] BN1 replica sums (dead until mlp1)
#define OFF_REP2 (OFF_BUFA + 65536ULL)       // f32 [64][256] BN2 replica sums

__device__ __forceinline__ float eluf(float v) { return v > 0.f ? v : expm1f(v); }

// ---------------- K0: zero stats+replicas, edge index tables ----------------
__global__ void k_init(const float* __restrict__ rel_rec, const float* __restrict__ rel_send,
                       float* stats, float* rep1, float* rep2,
                       int* sidx, int* ridx, int* inc) {
    int tid = threadIdx.x;
    for (int i = tid; i < S_COUNT; i += 256) stats[i] = 0.f;
    for (int i = tid; i < NREP * 256; i += 256) { rep1[i] = 0.f; rep2[i] = 0.f; }
    for (int e = tid; e < EE; e += 256) {
        int s = 0, r = 0;
        for (int n = 0; n < NN; ++n) {
            if (rel_send[e * NN + n] > 0.5f) s = n;
            if (rel_rec[e * NN + n] > 0.5f) r = n;
        }
        sidx[e] = s; ridx[e] = r;
    }
    __syncthreads();
    if (tid < NN) {
        int k = 0;
        for (int e = 0; e < EE; ++e)
            if (ridx[e] == tid) inc[tid * (NN - 1) + (k++)] = e;
    }
}

// ---------------- K pack: conv2_w -> f16 A-fragment-linear layout ----------------
__global__ void k_pack(const float* __restrict__ w2, _Float16* __restrict__ apack) {
    int f = blockIdx.x;       // 0..159
    int l = threadIdx.x;      // 0..63
    int m0 = f & 7, ks = f >> 3, s = ks & 3, k = ks >> 2;
    int m = m0 * 16 + (l & 15);
    int cbase = 32 * s + (l >> 4) * 8;
#pragma unroll
    for (int j = 0; j < 8; ++j)
        apack[(f * 64 + l) * 8 + j] = (_Float16)w2[m * 640 + (cbase + j) * 5 + k];
}

// conv1 unit: one output channel o, pre-pool t-range [lc*24, lc*24+24) -> 24 relu'd values
__device__ __forceinline__ void conv1_unit(const float* s_edges /*[8][100]*/,
                                           const float* s_w1 /*[128][40]*/,
                                           int o, int lc, float bias, float v[24]) {
    float acc[24];
#pragma unroll
    for (int t = 0; t < 24; ++t) acc[t] = bias;
#pragma unroll
    for (int ci = 0; ci < 8; ++ci) {
        float win[28];
        const float4* p = reinterpret_cast<const float4*>(s_edges + ci * 100 + lc * 24);
#pragma unroll
        for (int q = 0; q < 7; ++q) {
            float4 f = p[q];
            win[4 * q + 0] = f.x; win[4 * q + 1] = f.y;
            win[4 * q + 2] = f.z; win[4 * q + 3] = f.w;
        }
        const float* wr = s_w1 + o * 40 + ci * 5;
#pragma unroll
        for (int k = 0; k < 5; ++k) {
            float w = wr[k];
#pragma unroll
            for (int t = 0; t < 24; ++t) acc[t] = fmaf(win[t + k], w, acc[t]);
        }
    }
#pragma unroll
    for (int t = 0; t < 24; ++t) v[t] = fmaxf(acc[t], 0.f);
}

__device__ __forceinline__ void load_edges_w1(float* s_edges, float* s_w1,
                                              const float* __restrict__ inputs,
                                              const float* __restrict__ conv1_w,
                                              int b, int sn, int rn) {
    for (int i = threadIdx.x; i < 800; i += 256) {
        int ci = i / 100, t = i - ci * 100;
        int n = (ci < 4) ? sn : rn;
        int d = ci & 3;
        s_edges[ci * 100 + t] = inputs[((b * NN + n) * TT + t) * DD + d];
    }
    for (int i = threadIdx.x; i < 5120; i += 256) s_w1[i] = conv1_w[i];
}

// ---------------- K1: conv1 + relu, accumulate BN1 stats into replicas ----------------
__global__ __launch_bounds__(256) void k_conv1_stats(const float* __restrict__ inputs,
                                                     const float* __restrict__ conv1_w,
                                                     const float* __restrict__ conv1_b,
                                                     const int* __restrict__ sidx,
                                                     const int* __restrict__ ridx,
                                                     float* rep1) {
    __shared__ float s_edges[8 * 100];
    __shared__ float s_w1[128 * 40];
    int be = blockIdx.x;
    int b = be / EE, e = be - b * EE;
    float* rep = rep1 + (be & (NREP - 1)) * 256;
    load_edges_w1(s_edges, s_w1, inputs, conv1_w, b, sidx[e], ridx[e]);
    __syncthreads();
#pragma unroll
    for (int u = 0; u < 2; ++u) {
        int unit = threadIdx.x + u * 256;
        int o = unit >> 2, lc = unit & 3;
        float v[24];
        conv1_unit(s_edges, s_w1, o, lc, conv1_b[o], v);
        float s = 0.f, q = 0.f;
#pragma unroll
        for (int t = 0; t < 24; ++t) { s += v[t]; q += v[t] * v[t]; }
        s += __shfl_xor(s, 1); s += __shfl_xor(s, 2);
        q += __shfl_xor(q, 1); q += __shfl_xor(q, 2);
        if ((threadIdx.x & 3) == 0) {
            atomicAdd(&rep[o], s);
            atomicAdd(&rep[128 + o], q);
        }
    }
}

// ---------------- finalize BN from 64 replicas -> scale/shift ----------------
__global__ void k_finalize_rep(const float* __restrict__ rep, float* stats, int scIdx,
                               const float* __restrict__ g, const float* __restrict__ bb,
                               float inv_count) {
    int j = threadIdx.x;
    float s = 0.f, q = 0.f;
    for (int i = 0; i < NREP; ++i) {
        s += rep[i * 256 + j];
        q += rep[i * 256 + 128 + j];
    }
    float m = s * inv_count;
    float v = fmaxf(q * inv_count - m * m, 0.f);
    float sc = g[j] * rsqrtf(v + EPS);
    stats[scIdx + j] = sc;
    stats[scIdx + 128 + j] = bb[j] - m * sc;
}

// ---------------- finalize BN from stats sum/sumsq (small MLP BNs) ----------------
__global__ void k_finalize(float* stats, int sumIdx, const float* __restrict__ g,
                           const float* __restrict__ bb, float inv_count) {
    int j = threadIdx.x;
    float m = stats[sumIdx + j] * inv_count;
    float v = fmaxf(stats[sumIdx + 128 + j] * inv_count - m * m, 0.f);
    float sc = g[j] * rsqrtf(v + EPS);
    stats[sumIdx + 256 + j] = sc;
    stats[sumIdx + 384 + j] = bb[j] - m * sc;
}

// ---------------- K3: conv1(recompute)+BN1+pool -> LDS f16 (t-major), conv2 via f16 MFMA ----------------
__global__ __launch_bounds__(256) void k_conv2(const float* __restrict__ inputs,
                                               const float* __restrict__ conv1_w,
                                               const float* __restrict__ conv1_b,
                                               const _Float16* __restrict__ apack,
                                               const float* __restrict__ conv2_b,
                                               const int* __restrict__ sidx,
                                               const int* __restrict__ ridx,
                                               const float* __restrict__ stats,
                                               float* rep2,
                                               __half* __restrict__ y3h) {
    __shared__ float s_edges[8 * 100];
    __shared__ float s_w1[128 * 40];
    __shared__ __align__(16) _Float16 s_y2t[52 * 136];

    int be = blockIdx.x;
    int b = be / EE, e = be - b * EE;
    float* rep = rep2 + (be & (NREP - 1)) * 256;
    load_edges_w1(s_edges, s_w1, inputs, conv1_w, b, sidx[e], ridx[e]);
    {
        int* z = (int*)&s_y2t[48 * 136];
        for (int i = threadIdx.x; i < 272; i += 256) z[i] = 0;
    }
    __syncthreads();
    // phase 2: conv1 + BN1 + maxpool -> s_y2t (f16, t-major)
#pragma unroll
    for (int u = 0; u < 2; ++u) {
        int unit = threadIdx.x + u * 256;
        int o = unit >> 2, lc = unit & 3;
        float v[24];
        conv1_unit(s_edges, s_w1, o, lc, conv1_b[o], v);
        float sc = stats[S_BN1_SC + o], sh = stats[S_BN1_SH + o];
#pragma unroll
        for (int l = 0; l < 12; ++l) {
            float a = fmaf(v[2 * l], sc, sh);
            float c = fmaf(v[2 * l + 1], sc, sh);
            s_y2t[(lc * 12 + l) * 136 + o] = (_Float16)fmaxf(a, c);
        }
    }
    __syncthreads();
    // phase 3: MFMA GEMM (5 shifted taps x 4 K-slices)
    int w = threadIdx.x >> 6;
    int lane = threadIdx.x & 63;
    int quad = lane >> 4, l15 = lane & 15;
    f32x4 acc[2][3];
#pragma unroll
    for (int m = 0; m < 2; ++m)
#pragma unroll
        for (int nt = 0; nt < 3; ++nt) acc[m][nt] = (f32x4){0.f, 0.f, 0.f, 0.f};

    const f16x8* Ap = (const f16x8*)apack;
#pragma unroll
    for (int k = 0; k < 5; ++k) {
#pragma unroll
        for (int s = 0; s < 4; ++s) {
            f16x8 a0 = Ap[((k * 4 + s) * 8 + 2 * w) * 64 + lane];
            f16x8 a1 = Ap[((k * 4 + s) * 8 + 2 * w + 1) * 64 + lane];
#pragma unroll
            for (int nt = 0; nt < 3; ++nt) {
                const f16x8* bp = (const f16x8*)((const char*)s_y2t +
                                                 (nt * 16 + l15 + k) * 272 + 64 * s + quad * 16);
                f16x8 bfr = *bp;
                acc[0][nt] = __builtin_amdgcn_mfma_f32_16x16x32_f16(a0, bfr, acc[0][nt], 0, 0, 0);
                acc[1][nt] = __builtin_amdgcn_mfma_f32_16x16x32_f16(a1, bfr, acc[1][nt], 0, 0, 0);
            }
        }
    }
    // epilogue: bias + relu, store f16 y3, BN2 stats -> replicas
    _Float16* y3 = (_Float16*)y3h;
#pragma unroll
    for (int m = 0; m < 2; ++m) {
        int co0 = (2 * w + m) * 16 + quad * 4;
        float ssum[4] = {0.f, 0.f, 0.f, 0.f}, qsum[4] = {0.f, 0.f, 0.f, 0.f};
#pragma unroll
        for (int nt = 0; nt < 3; ++nt) {
            int t = nt * 16 + l15;
            bool valid = t < 44;
#pragma unroll
            for (int r = 0; r < 4; ++r) {
                float v = fmaxf(acc[m][nt][r] + conv2_b[co0 + r], 0.f);
                if (valid) {
                    y3[((long long)be * 128 + co0 + r) * 44 + t] = (_Float16)v;
                    ssum[r] += v; qsum[r] += v * v;
                }
            }
        }
#pragma unroll
        for (int r = 0; r < 4; ++r) {
            float s = ssum[r], q = qsum[r];
            s += __shfl_xor(s, 1); s += __shfl_xor(s, 2); s += __shfl_xor(s, 4); s += __shfl_xor(s, 8);
            q += __shfl_xor(q, 1); q += __shfl_xor(q, 2); q += __shfl_xor(q, 4); q += __shfl_xor(q, 8);
            if (l15 == 0) {
                atomicAdd(&rep[co0 + r], s);
                atomicAdd(&rep[128 + co0 + r], q);
            }
        }
    }
}

// ---------------- K5: BN2 apply + attention-pool (collapsed) -> x [BE][128] ----------------
__global__ __launch_bounds__(128) void k_predatt(const __half* __restrict__ y3,
                                                 const float* __restrict__ stats,
                                                 const float* __restrict__ att_w,
                                                 const float* __restrict__ att_b,
                                                 const float* __restrict__ pred_w,
                                                 const float* __restrict__ pred_b,
                                                 float* __restrict__ x) {
    __shared__ float h[128 * 45];
    __shared__ float att[44];
    __shared__ float hw[128];
    int be = blockIdx.x;
    int tid = threadIdx.x;
    for (int i = tid; i < 128 * 44; i += 128) {
        int c = i / 44, t = i - c * 44;
        float v = __half2float(y3[(long long)be * 5632 + i]);
        h[c * 45 + t] = fmaf(v, stats[S_BN2_SC + c], stats[S_BN2_SH + c]);
    }
    __syncthreads();
    if (tid < 44) {
        float a = att_b[0];
        for (int c = 0; c < 128; ++c) a = fmaf(h[c * 45 + tid], att_w[c], a);
        att[tid] = a;
    }
    __syncthreads();
    if (tid == 0) {
        float m = -1e30f;
        for (int t = 0; t < 44; ++t) m = fmaxf(m, att[t]);
        float s = 0.f;
        for (int t = 0; t < 44; ++t) { float ev = expf(att[t] - m); att[t] = ev; s += ev; }
        float inv = 1.f / s;
        for (int t = 0; t < 44; ++t) att[t] *= inv;
    }
    __syncthreads();
    {
        int c = tid;
        float a = 0.f;
        for (int t = 0; t < 44; ++t) a = fmaf(h[c * 45 + t], att[t], a);
        hw[c] = a;
    }
    __syncthreads();
    {
        int o = tid;
        float a = pred_b[o];
        for (int c = 0; c < 128; ++c) a = fmaf(pred_w[o * 128 + c], hw[c], a);
        x[(long long)be * 128 + o] = a * (1.0f / 44.0f);
    }
}

// ---------------- generic linear (IN -> 128) + ELU, 8 rows per block ----------------
template <int IN>
__global__ __launch_bounds__(128) void k_linear(const float* __restrict__ in,
                                                const float* __restrict__ W,
                                                const float* __restrict__ bias,
                                                float* __restrict__ out) {
    __shared__ float s_in[8 * IN];
    int r0 = blockIdx.x * 8;
    int j = threadIdx.x;
    for (int i = j; i < 8 * IN; i += 128) s_in[i] = in[(long long)r0 * IN + i];
    __syncthreads();
    float acc[8];
    float bj = bias[j];
#pragma unroll
    for (int e = 0; e < 8; ++e) acc[e] = bj;
    for (int i = 0; i < IN; ++i) {
        float w = W[j * IN + i];
#pragma unroll
        for (int e = 0; e < 8; ++e) acc[e] = fmaf(s_in[e * IN + i], w, acc[e]);
    }
#pragma unroll
    for (int e = 0; e < 8; ++e) out[(long long)(r0 + e) * 128 + j] = eluf(acc[e]);
}

// ---------------- mlp3 layer1: gather-concat [send|recv|skip] (384) -> 128, ELU ----------------
__global__ __launch_bounds__(128) void k_mlp3l1(const float* __restrict__ xn2,
                                                const float* __restrict__ x_skip,
                                                const int* __restrict__ sidx,
                                                const int* __restrict__ ridx,
                                                const float* __restrict__ W,
                                                const float* __restrict__ bias,
                                                float* __restrict__ out) {
    __shared__ float s_in[8 * 384];
    int r0 = blockIdx.x * 8;
    int j = threadIdx.x;
    for (int e = 0; e < 8; ++e) {
        int r = r0 + e;
        int b = r / EE, ed = r - b * EE;
        s_in[e * 384 + j] = xn2[(b * NN + sidx[ed]) * 128 + j];
        s_in[e * 384 + 128 + j] = xn2[(b * NN + ridx[ed]) * 128 + j];
        s_in[e * 384 + 256 + j] = x_skip[(long long)r * 128 + j];
    }
    __syncthreads();
    float acc[8];
    float bj = bias[j];
#pragma unroll
    for (int e = 0; e < 8; ++e) acc[e] = bj;
    for (int i = 0; i < 384; ++i) {
        float w = W[j * 384 + i];
#pragma unroll
        for (int e = 0; e < 8; ++e) acc[e] = fmaf(s_in[e * 384 + i], w, acc[e]);
    }
#pragma unroll
    for (int e = 0; e < 8; ++e) out[(long long)(r0 + e) * 128 + j] = eluf(acc[e]);
}

// ---------------- per-feature (column) stats over [R][128] ----------------
__global__ __launch_bounds__(128) void k_colstats(const float* __restrict__ in,
                                                  float* stats, int sumIdx, int R) {
    int r0 = blockIdx.x * 128;
    int j = threadIdx.x;
    float s = 0.f, q = 0.f;
    int rend = (r0 + 128 < R) ? r0 + 128 : R;
    for (int r = r0; r < rend; ++r) {
        float v = in[(long long)r * 128 + j];
        s += v; q += v * v;
    }
    atomicAdd(&stats[sumIdx + j], s);
    atomicAdd(&stats[sumIdx + 128 + j], q);
}

// ---------------- BN apply (elementwise, per-column scale/shift) ----------------
__global__ __launch_bounds__(256) void k_bnapply(const float* __restrict__ in,
                                                 float* __restrict__ out,
                                                 const float* __restrict__ stats,
                                                 int scIdx, int n) {
    int i = blockIdx.x * 256 + threadIdx.x;
    if (i < n) {
        int j = i & 127;
        out[i] = fmaf(in[i], stats[scIdx + j], stats[scIdx + 128 + j]);
    }
}

// ---------------- edge2node scatter-mean (via incoming-edge lists) ----------------
__global__ __launch_bounds__(128) void k_e2n(const float* __restrict__ x_skip,
                                             const int* __restrict__ inc,
                                             float* __restrict__ xn) {
    int bn = blockIdx.x;
    int b = bn / NN, n = bn - b * NN;
    int j = threadIdx.x;
    float s = 0.f;
    for (int k = 0; k < NN - 1; ++k) {
        int e = inc[n * (NN - 1) + k];
        s += x_skip[(long long)(b * EE + e) * 128 + j];
    }
    xn[bn * 128 + j] = s * (1.0f / (float)NN);
}

// ---------------- BN3 apply + fc_out (128 -> 16) ----------------
__global__ __launch_bounds__(256) void k_fcout(const float* __restrict__ h2,
                                               const float* __restrict__ stats,
                                               const float* __restrict__ fcw,
                                               const float* __restrict__ fcb,
                                               float* __restrict__ out) {
    __shared__ float s_x[16 * 129];
    __shared__ float s_w[16 * 129];
    int r0 = blockIdx.x * 16;
    int tid = threadIdx.x;
    for (int i = tid; i < 16 * 128; i += 256) {
        int rr = i >> 7, j = i & 127;
        s_x[rr * 129 + j] = fmaf(h2[(long long)(r0 + rr) * 128 + j],
                                 stats[S_M3_SC + j], stats[S_M3_SH + j]);
    }
    for (int i = tid; i < 16 * 128; i += 256) {
        int o = i >> 7, j = i & 127;
        s_w[o * 129 + j] = fcw[i];
    }
    __syncthreads();
    int rl = tid >> 4, o = tid & 15;
    float a = fcb[o];
    for (int j = 0; j < 128; ++j) a = fmaf(s_x[rl * 129 + j], s_w[o * 129 + j], a);
    out[(long long)(r0 + rl) * 16 + o] = a;
}

// ---------------- host launcher ----------------
extern "C" void kernel_launch(void* const* d_in, const int* in_sizes, int n_in,
                              void* d_out, int out_size, void* d_ws, size_t ws_size,
                              hipStream_t stream) {
    const float* inputs = (const float*)d_in[0];
    const float* rel_rec = (const float*)d_in[1];
    const float* rel_send = (const float*)d_in[2];
    const float* conv1_w = (const float*)d_in[3];
    const float* conv1_b = (const float*)d_in[4];
    const float* bn1_g = (const float*)d_in[5];
    const float* bn1_b = (const float*)d_in[6];
    const float* conv2_w = (const float*)d_in[7];
    const float* conv2_b = (const float*)d_in[8];
    const float* bn2_g = (const float*)d_in[9];
    const float* bn2_b = (const float*)d_in[10];
    const float* pred_w = (const float*)d_in[11];
    const float* pred_b = (const float*)d_in[12];
    const float* att_w = (const float*)d_in[13];
    const float* att_b = (const float*)d_in[14];
    const float* m1w1 = (const float*)d_in[15];
    const float* m1b1 = (const float*)d_in[16];
    const float* m1w2 = (const float*)d_in[17];
    const float* m1b2 = (const float*)d_in[18];
    const float* m1g = (const float*)d_in[19];
    const float* m1bb = (const float*)d_in[20];
    const float* m2w1 = (const float*)d_in[21];
    const float* m2b1 = (const float*)d_in[22];
    const float* m2w2 = (const float*)d_in[23];
    const float* m2b2 = (const float*)d_in[24];
    const float* m2g = (const float*)d_in[25];
    const float* m2bb = (const float*)d_in[26];
    const float* m3w1 = (const float*)d_in[27];
    const float* m3b1 = (const float*)d_in[28];
    const float* m3w2 = (const float*)d_in[29];
    const float* m3b2 = (const float*)d_in[30];
    const float* m3g = (const float*)d_in[31];
    const float* m3bb = (const float*)d_in[32];
    const float* fcw = (const float*)d_in[33];
    const float* fcb = (const float*)d_in[34];

    char* ws = (char*)d_ws;
    float* stats = (float*)(ws + OFF_STATS);
    int* sidx = (int*)(ws + OFF_SIDX);
    int* ridx = (int*)(ws + OFF_RIDX);
    int* inc = (int*)(ws + OFF_INC);
    __half* y3 = (__half*)(ws + OFF_Y3);
    float* x = (float*)(ws + OFF_X);
    float* bufA = (float*)(ws + OFF_BUFA);
    float* bufB = (float*)(ws + OFF_BUFB);
    float* x_skip = (float*)(ws + OFF_SKIP);
    float* xn = (float*)(ws + OFF_XN);
    float* t640 = (float*)(ws + OFF_T640);
    float* xn2 = (float*)(ws + OFF_XN2);
    _Float16* apack = (_Float16*)(ws + OFF_APACK);
    float* rep1 = (float*)(ws + OFF_REP1);
    float* rep2 = (float*)(ws + OFF_REP2);
    float* outp = (float*)d_out;

    hipLaunchKernelGGL(k_init, dim3(1), dim3(256), 0, stream,
                       rel_rec, rel_send, stats, rep1, rep2, sidx, ridx, inc);
    hipLaunchKernelGGL(k_pack, dim3(160), dim3(64), 0, stream, conv2_w, apack);
    hipLaunchKernelGGL(k_conv1_stats, dim3(BE), dim3(256), 0, stream,
                       inputs, conv1_w, conv1_b, sidx, ridx, rep1);
    hipLaunchKernelGGL(k_finalize_rep, dim3(1), dim3(128), 0, stream,
                       rep1, stats, S_BN1_SC, bn1_g, bn1_b, 1.0f / (float)(BE * L1));
    hipLaunchKernelGGL(k_conv2, dim3(BE), dim3(256), 0, stream,
                       inputs, conv1_w, conv1_b, apack, conv2_b, sidx, ridx, stats, rep2, y3);
    hipLaunchKernelGGL(k_finalize_rep, dim3(1), dim3(128), 0, stream,
                       rep2, stats, S_BN2_SC, bn2_g, bn2_b, 1.0f / (float)(BE * L2));
    hipLaunchKernelGGL(k_predatt, dim3(BE), dim3(128), 0, stream,
                       y3, stats, att_w, att_b, pred_w, pred_b, x);
    // mlp1
    hipLaunchKernelGGL(k_linear<128>, dim3(BE / 8), dim3(128), 0, stream, x, m1w1, m1b1, bufA);
    hipLaunchKernelGGL(k_linear<128>, dim3(BE / 8), dim3(128), 0, stream, bufA, m1w2, m1b2, bufB);
    hipLaunchKernelGGL(k_colstats, dim3(BE / 128), dim3(128), 0, stream, bufB, stats, S_M1_SUM, BE);
    hipLaunchKernelGGL(k_finalize, dim3(1), dim3(128), 0, stream,
                       stats, S_M1_SUM, m1g, m1bb, 1.0f / (float)BE);
    hipLaunchKernelGGL(k_bnapply, dim3(BE * 128 / 256), dim3(256), 0, stream,
                       bufB, x_skip, stats, S_M1_SC, BE * 128);
    // edge2node + mlp2
    hipLaunchKernelGGL(k_e2n, dim3(BB * NN), dim3(128), 0, stream, x_skip, inc, xn);
    hipLaunchKernelGGL(k_linear<128>, dim3(BB * NN / 8), dim3(128), 0, stream, xn, m2w1, m2b1, t640);
    hipLaunchKernelGGL(k_linear<128>, dim3(BB * NN / 8), dim3(128), 0, stream, t640, m2w2, m2b2, xn);
    hipLaunchKernelGGL(k_colstats, dim3(BB * NN / 128), dim3(128), 0, stream, xn, stats, S_M2_SUM, BB * NN);
    hipLaunchKernelGGL(k_finalize, dim3(1), dim3(128), 0, stream,
                       stats, S_M2_SUM, m2g, m2bb, 1.0f / (float)(BB * NN));
    hipLaunchKernelGGL(k_bnapply, dim3(BB * NN * 128 / 256), dim3(256), 0, stream,
                       xn, xn2, stats, S_M2_SC, BB * NN * 128);
    // node2edge + mlp3
    hipLaunchKernelGGL(k_mlp3l1, dim3(BE / 8), dim3(128), 0, stream,
                       xn2, x_skip, sidx, ridx, m3w1, m3b1, bufA);
    hipLaunchKernelGGL(k_linear<128>, dim3(BE / 8), dim3(128), 0, stream, bufA, m3w2, m3b2, bufB);
    hipLaunchKernelGGL(k_colstats, dim3(BE / 128), dim3(128), 0, stream, bufB, stats, S_M3_SUM, BE);
    hipLaunchKernelGGL(k_finalize, dim3(1), dim3(128), 0, stream,
                       stats, S_M3_SUM, m3g, m3bb, 1.0f / (float)BE);
    // fc_out
    hipLaunchKernelGGL(k_fcout, dim3(BE / 16), dim3(256), 0, stream, bufB, stats, fcw, fcb, outp);
    (void)in_sizes; (void)n_in; (void)out_size; (void)ws_size;
}

// Round 6
// 857.957 us; speedup vs baseline: 22.8205x; 1.1864x over previous
//
#include <hip/hip_runtime.h>
#include <hip/hip_bf16.h>
#include <hip/hip_fp16.h>

// ---------------- problem constants ----------------
#define BB 32
#define NN 20
#define TT 100
#define DD 4
#define HH 128
#define EE 380          // N*(N-1)
#define BE 12160        // B*E
#define L1 96           // conv1 out length
#define LP 48           // after maxpool
#define L2 44           // conv2 out length
#define NOUT 16
#define EPS 1e-5f
#define NREP 64         // stats replicas (atomic de-contention)

typedef _Float16 f16x8 __attribute__((ext_vector_type(8)));
typedef float f32x4 __attribute__((ext_vector_type(4)));

// stats slot indices (floats)
#define S_BN1_SUM 0
#define S_BN1_SQ 128
#define S_BN1_SC 256
#define S_BN1_SH 384
#define S_BN2_SUM 512
#define S_BN2_SQ 640
#define S_BN2_SC 768
#define S_BN2_SH 896
#define S_M1_SUM 1024
#define S_M1_SQ 1152
#define S_M1_SC 1280
#define S_M1_SH 1408
#define S_M2_SUM 1536
#define S_M2_SQ 1664
#define S_M2_SC 1792
#define S_M2_SH 1920
#define S_M3_SUM 2048
#define S_M3_SQ 2176
#define S_M3_SC 2304
#define S_M3_SH 2432
#define S_COUNT 2560

// workspace offsets (bytes)
#define OFF_STATS 0ULL
#define OFF_SIDX 16384ULL
#define OFF_RIDX 18432ULL
#define OFF_INC 20480ULL
#define OFF_Y3 24576ULL                      // fp16 [BE][128][44]
#define OFF_X 136994816ULL                   // f32 [BE][128]
#define OFF_BUFA 143220736ULL                // f32 [BE][128]; first 128KB doubles as BN1/BN2 replicas before mlp1
#define OFF_BUFB 149446656ULL                // f32 [BE][128]
#define OFF_SKIP 155672576ULL                // f32 [BE][128]
#define OFF_XN 161898496ULL                  // f32 [640][128]
#define OFF_T640 162226176ULL                // f32 [640][128]; holds Apack(160KB)+Apack1(16KB) during conv phase
#define OFF_XN2 162553856ULL                 // f32 [640][128]
#define OFF_APACK OFF_T640
#define OFF_APACK1 (OFF_T640 + 163840ULL)
#define OFF_REP1 OFF_BUFA                    // f32 [64][256] BN1 replica sums (dead until mlp1)
#define OFF_REP2 (OFF_BUFA + 65536ULL)       // f32 [64][256] BN2 replica sums

__device__ __forceinline__ float eluf(float v) { return v > 0.f ? v : expm1f(v); }

// ---------------- K0: zero stats+replicas, edge index tables ----------------
__global__ void k_init(const float* __restrict__ rel_rec, const float* __restrict__ rel_send,
                       float* stats, float* rep1, float* rep2,
                       int* sidx, int* ridx, int* inc) {
    int tid = threadIdx.x;
    for (int i = tid; i < S_COUNT; i += 256) stats[i] = 0.f;
    for (int i = tid; i < NREP * 256; i += 256) { rep1[i] = 0.f; rep2[i] = 0.f; }
    for (int e = tid; e < EE; e += 256) {
        int s = 0, r = 0;
        for (int n = 0; n < NN; ++n) {
            if (rel_send[e * NN + n] > 0.5f) s = n;
            if (rel_rec[e * NN + n] > 0.5f) r = n;
        }
        sidx[e] = s; ridx[e] = r;
    }
    __syncthreads();
    if (tid < NN) {
        int k = 0;
        for (int e = 0; e < EE; ++e)
            if (ridx[e] == tid) inc[tid * (NN - 1) + (k++)] = e;
    }
}

// ---------------- K pack: conv2_w -> f16 A-fragment-linear layout ----------------
// Frag f=(k*4+s)*8+m0: lane l holds A[m=m0*16+(l&15)][ci=32s+(l>>4)*8+j] of W_k
__global__ void k_pack(const float* __restrict__ w2, _Float16* __restrict__ apack) {
    int f = blockIdx.x;       // 0..159
    int l = threadIdx.x;      // 0..63
    int m0 = f & 7, ks = f >> 3, s = ks & 3, k = ks >> 2;
    int m = m0 * 16 + (l & 15);
    int cbase = 32 * s + (l >> 4) * 8;
#pragma unroll
    for (int j = 0; j < 8; ++j)
        apack[(f * 64 + l) * 8 + j] = (_Float16)w2[m * 640 + (cbase + j) * 5 + k];
}

// ---------------- K pack1: conv1_w -> f16 A-frag layout, K=40 padded to 64 ----------------
// Frag f = s*8 + m0 (s=kslice 0..1): lane l holds A[m=m0*16+(l&15)][kcol=32s+(l>>4)*8+j]
// kcol = ci*5+k indexes conv1_w[m*40 + kcol]; kcol>=40 -> 0
__global__ void k_pack1(const float* __restrict__ w1, _Float16* __restrict__ apack1) {
    int f = blockIdx.x;       // 0..15
    int l = threadIdx.x;      // 0..63
    int m0 = f & 7, s = f >> 3;
    int m = m0 * 16 + (l & 15);
    int cbase = 32 * s + (l >> 4) * 8;
#pragma unroll
    for (int j = 0; j < 8; ++j) {
        int c = cbase + j;
        apack1[(f * 64 + l) * 8 + j] = (c < 40) ? (_Float16)w1[m * 40 + c] : (_Float16)0.f;
    }
}

// ---------------- shared helpers ----------------
__device__ __forceinline__ void load_edges(float* s_edges,
                                           const float* __restrict__ inputs,
                                           int b, int sn, int rn) {
    for (int i = threadIdx.x; i < 800; i += 256) {
        int ci = i / 100, t = i - ci * 100;
        int n = (ci < 4) ? sn : rn;
        int d = ci & 3;
        s_edges[ci * 100 + t] = inputs[((b * NN + n) * TT + t) * DD + d];
    }
}

// im2col for conv1: s_x1[t][c] (row stride 72 f16), c=ci*5+k -> x[ci][t+k]; c in [40,64) -> 0
__device__ __forceinline__ void build_x1(_Float16* s_x1, const float* s_edges) {
    for (int i = threadIdx.x; i < 96 * 64; i += 256) {
        int t = i >> 6, c = i & 63;
        float v = 0.f;
        if (c < 40) {
            int ci = (c * 205) >> 10;   // c/5 for small c
            int k = c - 5 * ci;
            v = s_edges[ci * 100 + t + k];
        }
        s_x1[t * 72 + c] = (_Float16)v;
    }
}

// conv1 via MFMA: M=128, N=96 (6 ntiles), K=64 (2 kslices). Per wave: 2 mtiles.
// acc1[m][nt]: C[co=( (2w+m)*16 + quad*4 + r )][t = nt*16 + l15]
__device__ __forceinline__ void conv1_mfma(const _Float16* __restrict__ apack1,
                                           const _Float16* s_x1,
                                           int w, int lane, int quad, int l15,
                                           f32x4 acc1[2][6]) {
#pragma unroll
    for (int m = 0; m < 2; ++m)
#pragma unroll
        for (int nt = 0; nt < 6; ++nt) acc1[m][nt] = (f32x4){0.f, 0.f, 0.f, 0.f};
    const f16x8* Ap = (const f16x8*)apack1;
#pragma unroll
    for (int s = 0; s < 2; ++s) {
        f16x8 a0 = Ap[(s * 8 + 2 * w) * 64 + lane];
        f16x8 a1 = Ap[(s * 8 + 2 * w + 1) * 64 + lane];
#pragma unroll
        for (int nt = 0; nt < 6; ++nt) {
            f16x8 bfr = *(const f16x8*)((const char*)s_x1 +
                                        (nt * 16 + l15) * 144 + 64 * s + quad * 16);
            acc1[0][nt] = __builtin_amdgcn_mfma_f32_16x16x32_f16(a0, bfr, acc1[0][nt], 0, 0, 0);
            acc1[1][nt] = __builtin_amdgcn_mfma_f32_16x16x32_f16(a1, bfr, acc1[1][nt], 0, 0, 0);
        }
    }
}

// ---------------- K1: conv1 (MFMA) + relu, BN1 stats into replicas ----------------
__global__ __launch_bounds__(256) void k_conv1_stats(const float* __restrict__ inputs,
                                                     const _Float16* __restrict__ apack1,
                                                     const float* __restrict__ conv1_b,
                                                     const int* __restrict__ sidx,
                                                     const int* __restrict__ ridx,
                                                     float* rep1) {
    __shared__ float s_edges[800];
    __shared__ __align__(16) _Float16 s_x1[96 * 72];
    int be = blockIdx.x;
    int b = be / EE, e = be - b * EE;
    float* rep = rep1 + (be & (NREP - 1)) * 256;
    load_edges(s_edges, inputs, b, sidx[e], ridx[e]);
    __syncthreads();
    build_x1(s_x1, s_edges);
    __syncthreads();
    int w = threadIdx.x >> 6, lane = threadIdx.x & 63;
    int quad = lane >> 4, l15 = lane & 15;
    f32x4 acc1[2][6];
    conv1_mfma(apack1, s_x1, w, lane, quad, l15, acc1);
#pragma unroll
    for (int m = 0; m < 2; ++m) {
        int co0 = (2 * w + m) * 16 + quad * 4;
        float ss[4] = {0.f, 0.f, 0.f, 0.f}, qq[4] = {0.f, 0.f, 0.f, 0.f};
#pragma unroll
        for (int nt = 0; nt < 6; ++nt)
#pragma unroll
            for (int r = 0; r < 4; ++r) {
                float v = fmaxf(acc1[m][nt][r] + conv1_b[co0 + r], 0.f);
                ss[r] += v; qq[r] += v * v;
            }
#pragma unroll
        for (int r = 0; r < 4; ++r) {
            float s = ss[r], q = qq[r];
            s += __shfl_xor(s, 1); s += __shfl_xor(s, 2); s += __shfl_xor(s, 4); s += __shfl_xor(s, 8);
            q += __shfl_xor(q, 1); q += __shfl_xor(q, 2); q += __shfl_xor(q, 4); q += __shfl_xor(q, 8);
            if (l15 == 0) {
                atomicAdd(&rep[co0 + r], s);
                atomicAdd(&rep[128 + co0 + r], q);
            }
        }
    }
}

// ---------------- finalize BN from 64 replicas -> scale/shift ----------------
__global__ void k_finalize_rep(const float* __restrict__ rep, float* stats, int scIdx,
                               const float* __restrict__ g, const float* __restrict__ bb,
                               float inv_count) {
    int j = threadIdx.x;
    float s = 0.f, q = 0.f;
    for (int i = 0; i < NREP; ++i) {
        s += rep[i * 256 + j];
        q += rep[i * 256 + 128 + j];
    }
    float m = s * inv_count;
    float v = fmaxf(q * inv_count - m * m, 0.f);
    float sc = g[j] * rsqrtf(v + EPS);
    stats[scIdx + j] = sc;
    stats[scIdx + 128 + j] = bb[j] - m * sc;
}

// ---------------- finalize BN from stats sum/sumsq (small MLP BNs) ----------------
__global__ void k_finalize(float* stats, int sumIdx, const float* __restrict__ g,
                           const float* __restrict__ bb, float inv_count) {
    int j = threadIdx.x;
    float m = stats[sumIdx + j] * inv_count;
    float v = fmaxf(stats[sumIdx + 128 + j] * inv_count - m * m, 0.f);
    float sc = g[j] * rsqrtf(v + EPS);
    stats[sumIdx + 256 + j] = sc;
    stats[sumIdx + 384 + j] = bb[j] - m * sc;
}

// ---------------- K3: conv1(MFMA)+BN1+pool -> LDS f16 (t-major), conv2 via f16 MFMA ----------------
__global__ __launch_bounds__(256) void k_conv2(const float* __restrict__ inputs,
                                               const _Float16* __restrict__ apack1,
                                               const float* __restrict__ conv1_b,
                                               const _Float16* __restrict__ apack,
                                               const float* __restrict__ conv2_b,
                                               const int* __restrict__ sidx,
                                               const int* __restrict__ ridx,
                                               const float* __restrict__ stats,
                                               float* rep2,
                                               __half* __restrict__ y3h) {
    __shared__ float s_edges[800];
    __shared__ __align__(16) _Float16 s_x1[96 * 72];
    __shared__ __align__(16) _Float16 s_y2t[52 * 136];
    __shared__ float s_bnsc[128], s_bnsh[128];

    int be = blockIdx.x;
    int b = be / EE, e = be - b * EE;
    float* rep = rep2 + (be & (NREP - 1)) * 256;
    load_edges(s_edges, inputs, b, sidx[e], ridx[e]);
    if (threadIdx.x < 128) {
        s_bnsc[threadIdx.x] = stats[S_BN1_SC + threadIdx.x];
        s_bnsh[threadIdx.x] = stats[S_BN1_SH + threadIdx.x];
    }
    {
        int* z = (int*)&s_y2t[48 * 136];
        for (int i = threadIdx.x; i < 272; i += 256) z[i] = 0;
    }
    __syncthreads();
    build_x1(s_x1, s_edges);
    __syncthreads();

    int w = threadIdx.x >> 6, lane = threadIdx.x & 63;
    int quad = lane >> 4, l15 = lane & 15;
    // phase 2: conv1 MFMA -> BN1 -> maxpool(k=2) -> s_y2t[t'][co]
    {
        f32x4 acc1[2][6];
        conv1_mfma(apack1, s_x1, w, lane, quad, l15, acc1);
#pragma unroll
        for (int m = 0; m < 2; ++m) {
            int co0 = (2 * w + m) * 16 + quad * 4;
#pragma unroll
            for (int nt = 0; nt < 6; ++nt) {
                int t = nt * 16 + l15;
#pragma unroll
                for (int r = 0; r < 4; ++r) {
                    int co = co0 + r;
                    float v = fmaxf(acc1[m][nt][r] + conv1_b[co], 0.f);
                    float y = fmaf(v, s_bnsc[co], s_bnsh[co]);
                    float p = __shfl_xor(y, 1);           // pool partner (t ^ 1)
                    if ((l15 & 1) == 0)
                        s_y2t[(t >> 1) * 136 + co] = (_Float16)fmaxf(y, p);
                }
            }
        }
    }
    __syncthreads();
    // phase 3: conv2 MFMA (5 shifted taps x 4 K-slices)
    f32x4 acc[2][3];
#pragma unroll
    for (int m = 0; m < 2; ++m)
#pragma unroll
        for (int nt = 0; nt < 3; ++nt) acc[m][nt] = (f32x4){0.f, 0.f, 0.f, 0.f};

    const f16x8* Ap = (const f16x8*)apack;
#pragma unroll
    for (int k = 0; k < 5; ++k) {
#pragma unroll
        for (int s = 0; s < 4; ++s) {
            f16x8 a0 = Ap[((k * 4 + s) * 8 + 2 * w) * 64 + lane];
            f16x8 a1 = Ap[((k * 4 + s) * 8 + 2 * w + 1) * 64 + lane];
#pragma unroll
            for (int nt = 0; nt < 3; ++nt) {
                const f16x8* bp = (const f16x8*)((const char*)s_y2t +
                                                 (nt * 16 + l15 + k) * 272 + 64 * s + quad * 16);
                f16x8 bfr = *bp;
                acc[0][nt] = __builtin_amdgcn_mfma_f32_16x16x32_f16(a0, bfr, acc[0][nt], 0, 0, 0);
                acc[1][nt] = __builtin_amdgcn_mfma_f32_16x16x32_f16(a1, bfr, acc[1][nt], 0, 0, 0);
            }
        }
    }
    // epilogue: bias + relu, store f16 y3, BN2 stats -> replicas
    _Float16* y3 = (_Float16*)y3h;
#pragma unroll
    for (int m = 0; m < 2; ++m) {
        int co0 = (2 * w + m) * 16 + quad * 4;
        float ssum[4] = {0.f, 0.f, 0.f, 0.f}, qsum[4] = {0.f, 0.f, 0.f, 0.f};
#pragma unroll
        for (int nt = 0; nt < 3; ++nt) {
            int t = nt * 16 + l15;
            bool valid = t < 44;
#pragma unroll
            for (int r = 0; r < 4; ++r) {
                float v = fmaxf(acc[m][nt][r] + conv2_b[co0 + r], 0.f);
                if (valid) {
                    y3[((long long)be * 128 + co0 + r) * 44 + t] = (_Float16)v;
                    ssum[r] += v; qsum[r] += v * v;
                }
            }
        }
#pragma unroll
        for (int r = 0; r < 4; ++r) {
            float s = ssum[r], q = qsum[r];
            s += __shfl_xor(s, 1); s += __shfl_xor(s, 2); s += __shfl_xor(s, 4); s += __shfl_xor(s, 8);
            q += __shfl_xor(q, 1); q += __shfl_xor(q, 2); q += __shfl_xor(q, 4); q += __shfl_xor(q, 8);
            if (l15 == 0) {
                atomicAdd(&rep[co0 + r], s);
                atomicAdd(&rep[128 + co0 + r], q);
            }
        }
    }
}

// ---------------- K5: BN2 apply + attention-pool (collapsed) -> x [BE][128] ----------------
__global__ __launch_bounds__(128) void k_predatt(const __half* __restrict__ y3,
                                                 const float* __restrict__ stats,
                                                 const float* __restrict__ att_w,
                                                 const float* __restrict__ att_b,
                                                 const float* __restrict__ pred_w,
                                                 const float* __restrict__ pred_b,
                                                 float* __restrict__ x) {
    __shared__ float h[128 * 45];
    __shared__ float att[44];
    __shared__ float hw[128];
    int be = blockIdx.x;
    int tid = threadIdx.x;
    for (int i = tid; i < 128 * 44; i += 128) {
        int c = i / 44, t = i - c * 44;
        float v = __half2float(y3[(long long)be * 5632 + i]);
        h[c * 45 + t] = fmaf(v, stats[S_BN2_SC + c], stats[S_BN2_SH + c]);
    }
    __syncthreads();
    if (tid < 44) {
        float a = att_b[0];
        for (int c = 0; c < 128; ++c) a = fmaf(h[c * 45 + tid], att_w[c], a);
        att[tid] = a;
    }
    __syncthreads();
    if (tid == 0) {
        float m = -1e30f;
        for (int t = 0; t < 44; ++t) m = fmaxf(m, att[t]);
        float s = 0.f;
        for (int t = 0; t < 44; ++t) { float ev = expf(att[t] - m); att[t] = ev; s += ev; }
        float inv = 1.f / s;
        for (int t = 0; t < 44; ++t) att[t] *= inv;
    }
    __syncthreads();
    {
        int c = tid;
        float a = 0.f;
        for (int t = 0; t < 44; ++t) a = fmaf(h[c * 45 + t], att[t], a);
        hw[c] = a;
    }
    __syncthreads();
    {
        int o = tid;
        float a = pred_b[o];
        for (int c = 0; c < 128; ++c) a = fmaf(pred_w[o * 128 + c], hw[c], a);
        x[(long long)be * 128 + o] = a * (1.0f / 44.0f);
    }
}

// ---------------- generic linear (IN -> 128) + ELU, 8 rows per block ----------------
template <int IN>
__global__ __launch_bounds__(128) void k_linear(const float* __restrict__ in,
                                                const float* __restrict__ W,
                                                const float* __restrict__ bias,
                                                float* __restrict__ out) {
    __shared__ float s_in[8 * IN];
    int r0 = blockIdx.x * 8;
    int j = threadIdx.x;
    for (int i = j; i < 8 * IN; i += 128) s_in[i] = in[(long long)r0 * IN + i];
    __syncthreads();
    float acc[8];
    float bj = bias[j];
#pragma unroll
    for (int e = 0; e < 8; ++e) acc[e] = bj;
    for (int i = 0; i < IN; ++i) {
        float w = W[j * IN + i];
#pragma unroll
        for (int e = 0; e < 8; ++e) acc[e] = fmaf(s_in[e * IN + i], w, acc[e]);
    }
#pragma unroll
    for (int e = 0; e < 8; ++e) out[(long long)(r0 + e) * 128 + j] = eluf(acc[e]);
}

// ---------------- mlp3 layer1: gather-concat [send|recv|skip] (384) -> 128, ELU ----------------
__global__ __launch_bounds__(128) void k_mlp3l1(const float* __restrict__ xn2,
                                                const float* __restrict__ x_skip,
                                                const int* __restrict__ sidx,
                                                const int* __restrict__ ridx,
                                                const float* __restrict__ W,
                                                const float* __restrict__ bias,
                                                float* __restrict__ out) {
    __shared__ float s_in[8 * 384];
    int r0 = blockIdx.x * 8;
    int j = threadIdx.x;
    for (int e = 0; e < 8; ++e) {
        int r = r0 + e;
        int b = r / EE, ed = r - b * EE;
        s_in[e * 384 + j] = xn2[(b * NN + sidx[ed]) * 128 + j];
        s_in[e * 384 + 128 + j] = xn2[(b * NN + ridx[ed]) * 128 + j];
        s_in[e * 384 + 256 + j] = x_skip[(long long)r * 128 + j];
    }
    __syncthreads();
    float acc[8];
    float bj = bias[j];
#pragma unroll
    for (int e = 0; e < 8; ++e) acc[e] = bj;
    for (int i = 0; i < 384; ++i) {
        float w = W[j * 384 + i];
#pragma unroll
        for (int e = 0; e < 8; ++e) acc[e] = fmaf(s_in[e * 384 + i], w, acc[e]);
    }
#pragma unroll
    for (int e = 0; e < 8; ++e) out[(long long)(r0 + e) * 128 + j] = eluf(acc[e]);
}

// ---------------- per-feature (column) stats over [R][128] ----------------
__global__ __launch_bounds__(128) void k_colstats(const float* __restrict__ in,
                                                  float* stats, int sumIdx, int R) {
    int r0 = blockIdx.x * 128;
    int j = threadIdx.x;
    float s = 0.f, q = 0.f;
    int rend = (r0 + 128 < R) ? r0 + 128 : R;
    for (int r = r0; r < rend; ++r) {
        float v = in[(long long)r * 128 + j];
        s += v; q += v * v;
    }
    atomicAdd(&stats[sumIdx + j], s);
    atomicAdd(&stats[sumIdx + 128 + j], q);
}

// ---------------- BN apply (elementwise, per-column scale/shift) ----------------
__global__ __launch_bounds__(256) void k_bnapply(const float* __restrict__ in,
                                                 float* __restrict__ out,
                                                 const float* __restrict__ stats,
                                                 int scIdx, int n) {
    int i = blockIdx.x * 256 + threadIdx.x;
    if (i < n) {
        int j = i & 127;
        out[i] = fmaf(in[i], stats[scIdx + j], stats[scIdx + 128 + j]);
    }
}

// ---------------- edge2node scatter-mean (via incoming-edge lists) ----------------
__global__ __launch_bounds__(128) void k_e2n(const float* __restrict__ x_skip,
                                             const int* __restrict__ inc,
                                             float* __restrict__ xn) {
    int bn = blockIdx.x;
    int b = bn / NN, n = bn - b * NN;
    int j = threadIdx.x;
    float s = 0.f;
    for (int k = 0; k < NN - 1; ++k) {
        int e = inc[n * (NN - 1) + k];
        s += x_skip[(long long)(b * EE + e) * 128 + j];
    }
    xn[bn * 128 + j] = s * (1.0f / (float)NN);
}

// ---------------- BN3 apply + fc_out (128 -> 16) ----------------
__global__ __launch_bounds__(256) void k_fcout(const float* __restrict__ h2,
                                               const float* __restrict__ stats,
                                               const float* __restrict__ fcw,
                                               const float* __restrict__ fcb,
                                               float* __restrict__ out) {
    __shared__ float s_x[16 * 129];
    __shared__ float s_w[16 * 129];
    int r0 = blockIdx.x * 16;
    int tid = threadIdx.x;
    for (int i = tid; i < 16 * 128; i += 256) {
        int rr = i >> 7, j = i & 127;
        s_x[rr * 129 + j] = fmaf(h2[(long long)(r0 + rr) * 128 + j],
                                 stats[S_M3_SC + j], stats[S_M3_SH + j]);
    }
    for (int i = tid; i < 16 * 128; i += 256) {
        int o = i >> 7, j = i & 127;
        s_w[o * 129 + j] = fcw[i];
    }
    __syncthreads();
    int rl = tid >> 4, o = tid & 15;
    float a = fcb[o];
    for (int j = 0; j < 128; ++j) a = fmaf(s_x[rl * 129 + j], s_w[o * 129 + j], a);
    out[(long long)(r0 + rl) * 16 + o] = a;
}

// ---------------- host launcher ----------------
extern "C" void kernel_launch(void* const* d_in, const int* in_sizes, int n_in,
                              void* d_out, int out_size, void* d_ws, size_t ws_size,
                              hipStream_t stream) {
    const float* inputs = (const float*)d_in[0];
    const float* rel_rec = (const float*)d_in[1];
    const float* rel_send = (const float*)d_in[2];
    const float* conv1_w = (const float*)d_in[3];
    const float* conv1_b = (const float*)d_in[4];
    const float* bn1_g = (const float*)d_in[5];
    const float* bn1_b = (const float*)d_in[6];
    const float* conv2_w = (const float*)d_in[7];
    const float* conv2_b = (const float*)d_in[8];
    const float* bn2_g = (const float*)d_in[9];
    const float* bn2_b = (const float*)d_in[10];
    const float* pred_w = (const float*)d_in[11];
    const float* pred_b = (const float*)d_in[12];
    const float* att_w = (const float*)d_in[13];
    const float* att_b = (const float*)d_in[14];
    const float* m1w1 = (const float*)d_in[15];
    const float* m1b1 = (const float*)d_in[16];
    const float* m1w2 = (const float*)d_in[17];
    const float* m1b2 = (const float*)d_in[18];
    const float* m1g = (const float*)d_in[19];
    const float* m1bb = (const float*)d_in[20];
    const float* m2w1 = (const float*)d_in[21];
    const float* m2b1 = (const float*)d_in[22];
    const float* m2w2 = (const float*)d_in[23];
    const float* m2b2 = (const float*)d_in[24];
    const float* m2g = (const float*)d_in[25];
    const float* m2bb = (const float*)d_in[26];
    const float* m3w1 = (const float*)d_in[27];
    const float* m3b1 = (const float*)d_in[28];
    const float* m3w2 = (const float*)d_in[29];
    const float* m3b2 = (const float*)d_in[30];
    const float* m3g = (const float*)d_in[31];
    const float* m3bb = (const float*)d_in[32];
    const float* fcw = (const float*)d_in[33];
    const float* fcb = (const float*)d_in[34];

    char* ws = (char*)d_ws;
    float* stats = (float*)(ws + OFF_STATS);
    int* sidx = (int*)(ws + OFF_SIDX);
    int* ridx = (int*)(ws + OFF_RIDX);
    int* inc = (int*)(ws + OFF_INC);
    __half* y3 = (__half*)(ws + OFF_Y3);
    float* x = (float*)(ws + OFF_X);
    float* bufA = (float*)(ws + OFF_BUFA);
    float* bufB = (float*)(ws + OFF_BUFB);
    float* x_skip = (float*)(ws + OFF_SKIP);
    float* xn = (float*)(ws + OFF_XN);
    float* t640 = (float*)(ws + OFF_T640);
    float* xn2 = (float*)(ws + OFF_XN2);
    _Float16* apack = (_Float16*)(ws + OFF_APACK);
    _Float16* apack1 = (_Float16*)(ws + OFF_APACK1);
    float* rep1 = (float*)(ws + OFF_REP1);
    float* rep2 = (float*)(ws + OFF_REP2);
    float* outp = (float*)d_out;

    hipLaunchKernelGGL(k_init, dim3(1), dim3(256), 0, stream,
                       rel_rec, rel_send, stats, rep1, rep2, sidx, ridx, inc);
    hipLaunchKernelGGL(k_pack, dim3(160), dim3(64), 0, stream, conv2_w, apack);
    hipLaunchKernelGGL(k_pack1, dim3(16), dim3(64), 0, stream, conv1_w, apack1);
    hipLaunchKernelGGL(k_conv1_stats, dim3(BE), dim3(256), 0, stream,
                       inputs, apack1, conv1_b, sidx, ridx, rep1);
    hipLaunchKernelGGL(k_finalize_rep, dim3(1), dim3(128), 0, stream,
                       rep1, stats, S_BN1_SC, bn1_g, bn1_b, 1.0f / (float)(BE * L1));
    hipLaunchKernelGGL(k_conv2, dim3(BE), dim3(256), 0, stream,
                       inputs, apack1, conv1_b, apack, conv2_b, sidx, ridx, stats, rep2, y3);
    hipLaunchKernelGGL(k_finalize_rep, dim3(1), dim3(128), 0, stream,
                       rep2, stats, S_BN2_SC, bn2_g, bn2_b, 1.0f / (float)(BE * L2));
    hipLaunchKernelGGL(k_predatt, dim3(BE), dim3(128), 0, stream,
                       y3, stats, att_w, att_b, pred_w, pred_b, x);
    // mlp1
    hipLaunchKernelGGL(k_linear<128>, dim3(BE / 8), dim3(128), 0, stream, x, m1w1, m1b1, bufA);
    hipLaunchKernelGGL(k_linear<128>, dim3(BE / 8), dim3(128), 0, stream, bufA, m1w2, m1b2, bufB);
    hipLaunchKernelGGL(k_colstats, dim3(BE / 128), dim3(128), 0, stream, bufB, stats, S_M1_SUM, BE);
    hipLaunchKernelGGL(k_finalize, dim3(1), dim3(128), 0, stream,
                       stats, S_M1_SUM, m1g, m1bb, 1.0f / (float)BE);
    hipLaunchKernelGGL(k_bnapply, dim3(BE * 128 / 256), dim3(256), 0, stream,
                       bufB, x_skip, stats, S_M1_SC, BE * 128);
    // edge2node + mlp2
    hipLaunchKernelGGL(k_e2n, dim3(BB * NN), dim3(128), 0, stream, x_skip, inc, xn);
    hipLaunchKernelGGL(k_linear<128>, dim3(BB * NN / 8), dim3(128), 0, stream, xn, m2w1, m2b1, t640);
    hipLaunchKernelGGL(k_linear<128>, dim3(BB * NN / 8), dim3(128), 0, stream, t640, m2w2, m2b2, xn);
    hipLaunchKernelGGL(k_colstats, dim3(BB * NN / 128), dim3(128), 0, stream, xn, stats, S_M2_SUM, BB * NN);
    hipLaunchKernelGGL(k_finalize, dim3(1), dim3(128), 0, stream,
                       stats, S_M2_SUM, m2g, m2bb, 1.0f / (float)(BB * NN));
    hipLaunchKernelGGL(k_bnapply, dim3(BB * NN * 128 / 256), dim3(256), 0, stream,
                       xn, xn2, stats, S_M2_SC, BB * NN * 128);
    // node2edge + mlp3
    hipLaunchKernelGGL(k_mlp3l1, dim3(BE / 8), dim3(128), 0, stream,
                       xn2, x_skip, sidx, ridx, m3w1, m3b1, bufA);
    hipLaunchKernelGGL(k_linear<128>, dim3(BE / 8), dim3(128), 0, stream, bufA, m3w2, m3b2, bufB);
    hipLaunchKernelGGL(k_colstats, dim3(BE / 128), dim3(128), 0, stream, bufB, stats, S_M3_SUM, BE);
    hipLaunchKernelGGL(k_finalize, dim3(1), dim3(128), 0, stream,
                       stats, S_M3_SUM, m3g, m3bb, 1.0f / (float)BE);
    // fc_out
    hipLaunchKernelGGL(k_fcout, dim3(BE / 16), dim3(256), 0, stream, bufB, stats, fcw, fcb, outp);
    (void)in_sizes; (void)n_in; (void)out_size; (void)ws_size;
}

// Round 7
// 706.563 us; speedup vs baseline: 27.7102x; 1.2143x over previous
//
#include <hip/hip_runtime.h>
#include <hip/hip_bf16.h>
#include <hip/hip_fp16.h>

// ---------------- problem constants ----------------
#define BB 32
#define NN 20
#define TT 100
#define DD 4
#define HH 128
#define EE 380          // N*(N-1)
#define BE 12160        // B*E
#define L1 96           // conv1 out length
#define LP 48           // after maxpool
#define L2 44           // conv2 out length
#define NOUT 16
#define EPS 1e-5f
#define NREP 64         // stats replicas (atomic de-contention)

typedef _Float16 f16x8 __attribute__((ext_vector_type(8)));
typedef _Float16 f16x2 __attribute__((ext_vector_type(2)));
typedef float f32x4 __attribute__((ext_vector_type(4)));

// stats slot indices (floats): SC at base, SH at base+128
#define S_BN1_SC 256
#define S_BN2_SC 768
#define S_M1_SC 1280
#define S_M2_SC 1792
#define S_M3_SC 2304

// workspace offsets (bytes)
#define OFF_STATS 0ULL
#define OFF_SIDX 16384ULL
#define OFF_RIDX 18432ULL
#define OFF_INC 20480ULL
#define OFF_Y23 24576ULL                     // f16 [BE] slots of 6144: y2pre [48][128] then y3 [128][44] (same slot, overwritten after consumption)
#define OFF_X 149446656ULL                   // f32 [BE][128]
#define OFF_BUFA 155672576ULL                // f32 [BE][128]; rep1/rep2 live here before mlp1
#define OFF_BUFB 161898496ULL                // f32 [BE][128]
#define OFF_XN 168124416ULL                  // f32 [640][128]
#define OFF_T640 168452096ULL                // f32 [640][128]; conv-phase: apack(160K)+apack1(16K)+pwt(64K)
#define OFF_REPM 168779776ULL                // f32 [64][256] MLP stats replicas
#define OFF_APACK OFF_T640
#define OFF_APACK1 (OFF_T640 + 163840ULL)
#define OFF_PWT (OFF_T640 + 180224ULL)
#define OFF_REP1 OFF_BUFA
#define OFF_REP2 (OFF_BUFA + 65536ULL)

__device__ __forceinline__ float eluf(float v) { return v > 0.f ? v : expm1f(v); }

// ---------------- K prep: pack conv2_w/conv1_w A-frags, transpose pred_w, init tables ----------------
__global__ __launch_bounds__(256) void k_prep(const float* __restrict__ rel_rec,
                                              const float* __restrict__ rel_send,
                                              const float* __restrict__ w2,
                                              const float* __restrict__ w1,
                                              const float* __restrict__ pred_w,
                                              _Float16* __restrict__ apack,
                                              _Float16* __restrict__ apack1,
                                              float* __restrict__ pwt,
                                              float* rep1, float* rep2, float* repm,
                                              int* sidx, int* ridx, int* inc) {
    int b = blockIdx.x;
    int tid = threadIdx.x;
    int l = tid & 63;
    if (b < 40) {            // conv2_w frags: f=(k*4+s)*8+m0; lane holds A[m0*16+(l&15)][32s+(l>>4)*8+j] of tap k
        int f = b * 4 + (tid >> 6);
        int m0 = f & 7, ks = f >> 3, s = ks & 3, k = ks >> 2;
        int m = m0 * 16 + (l & 15);
        int cbase = 32 * s + (l >> 4) * 8;
#pragma unroll
        for (int j = 0; j < 8; ++j)
            apack[(f * 64 + l) * 8 + j] = (_Float16)w2[m * 640 + (cbase + j) * 5 + k];
    } else if (b < 44) {     // conv1_w frags: K=40 padded to 64
        int f = (b - 40) * 4 + (tid >> 6);
        int m0 = f & 7, s = f >> 3;
        int m = m0 * 16 + (l & 15);
        int cbase = 32 * s + (l >> 4) * 8;
#pragma unroll
        for (int j = 0; j < 8; ++j) {
            int c = cbase + j;
            apack1[(f * 64 + l) * 8 + j] = (c < 40) ? (_Float16)w1[m * 40 + c] : (_Float16)0.f;
        }
    } else if (b == 44) {    // init: zero replicas, build edge tables
        for (int i = tid; i < NREP * 256; i += 256) { rep1[i] = 0.f; rep2[i] = 0.f; repm[i] = 0.f; }
        for (int e = tid; e < EE; e += 256) {
            int s = 0, r = 0;
            for (int n = 0; n < NN; ++n) {
                if (rel_send[e * NN + n] > 0.5f) s = n;
                if (rel_rec[e * NN + n] > 0.5f) r = n;
            }
            sidx[e] = s; ridx[e] = r;
        }
        __syncthreads();
        if (tid < NN) {
            int k = 0;
            for (int e = 0; e < EE; ++e)
                if (ridx[e] == tid) inc[tid * (NN - 1) + (k++)] = e;
        }
    } else {                 // transpose pred_w -> pwt[c][o]
        int idx = (b - 45) * 2048 + tid;
        for (int rep = 0; rep < 8; ++rep, idx += 256) {
            int o = idx >> 7, c = idx & 127;
            pwt[c * 128 + o] = pred_w[idx];
        }
    }
}

// ---------------- shared helpers ----------------
__device__ __forceinline__ void load_edges(float* s_edges,
                                           const float* __restrict__ inputs,
                                           int b, int sn, int rn) {
    for (int i = threadIdx.x; i < 800; i += 256) {
        int ci = i / 100, t = i - ci * 100;
        int n = (ci < 4) ? sn : rn;
        int d = ci & 3;
        s_edges[ci * 100 + t] = inputs[((b * NN + n) * TT + t) * DD + d];
    }
}

// im2col for conv1: s_x1[t][c] (row stride 72 f16), c=ci*5+k -> x[ci][t+k]; c in [40,64) -> 0
__device__ __forceinline__ void build_x1(_Float16* s_x1, const float* s_edges) {
    for (int i = threadIdx.x; i < 96 * 64; i += 256) {
        int t = i >> 6, c = i & 63;
        float v = 0.f;
        if (c < 40) {
            int ci = (c * 205) >> 10;
            int k = c - 5 * ci;
            v = s_edges[ci * 100 + t + k];
        }
        s_x1[t * 72 + c] = (_Float16)v;
    }
}

__device__ __forceinline__ void conv1_mfma(const _Float16* __restrict__ apack1,
                                           const _Float16* s_x1,
                                           int w, int lane, int quad, int l15,
                                           f32x4 acc1[2][6]) {
#pragma unroll
    for (int m = 0; m < 2; ++m)
#pragma unroll
        for (int nt = 0; nt < 6; ++nt) acc1[m][nt] = (f32x4){0.f, 0.f, 0.f, 0.f};
    const f16x8* Ap = (const f16x8*)apack1;
#pragma unroll
    for (int s = 0; s < 2; ++s) {
        f16x8 a0 = Ap[(s * 8 + 2 * w) * 64 + lane];
        f16x8 a1 = Ap[(s * 8 + 2 * w + 1) * 64 + lane];
#pragma unroll
        for (int nt = 0; nt < 6; ++nt) {
            f16x8 bfr = *(const f16x8*)((const char*)s_x1 +
                                        (nt * 16 + l15) * 144 + 64 * s + quad * 16);
            acc1[0][nt] = __builtin_amdgcn_mfma_f32_16x16x32_f16(a0, bfr, acc1[0][nt], 0, 0, 0);
            acc1[1][nt] = __builtin_amdgcn_mfma_f32_16x16x32_f16(a1, bfr, acc1[1][nt], 0, 0, 0);
        }
    }
}

// ---------------- K1: conv1 (MFMA) + relu -> BN1 stats + PRE-BN maxpool -> y2pre (f16, t-major)
// NOTE: pool-before-BN is exact here because bn1_g=1 -> BN scale>0 -> max commutes with fma.
__global__ __launch_bounds__(256) void k_conv1_stats(const float* __restrict__ inputs,
                                                     const _Float16* __restrict__ apack1,
                                                     const float* __restrict__ conv1_b,
                                                     const int* __restrict__ sidx,
                                                     const int* __restrict__ ridx,
                                                     float* rep1,
                                                     _Float16* __restrict__ y2p) {
    __shared__ float s_edges[800];
    __shared__ __align__(16) _Float16 s_x1[96 * 72];
    __shared__ __align__(16) _Float16 s_y2t[48 * 136];
    int be = blockIdx.x;
    int b = be / EE, e = be - b * EE;
    float* rep = rep1 + (be & (NREP - 1)) * 256;
    load_edges(s_edges, inputs, b, sidx[e], ridx[e]);
    __syncthreads();
    build_x1(s_x1, s_edges);
    __syncthreads();
    int w = threadIdx.x >> 6, lane = threadIdx.x & 63;
    int quad = lane >> 4, l15 = lane & 15;
    f32x4 acc1[2][6];
    conv1_mfma(apack1, s_x1, w, lane, quad, l15, acc1);
#pragma unroll
    for (int m = 0; m < 2; ++m) {
        int co0 = (2 * w + m) * 16 + quad * 4;
        float ss[4] = {0.f, 0.f, 0.f, 0.f}, qq[4] = {0.f, 0.f, 0.f, 0.f};
#pragma unroll
        for (int nt = 0; nt < 6; ++nt) {
            int t = nt * 16 + l15;
#pragma unroll
            for (int r = 0; r < 4; ++r) {
                float v = fmaxf(acc1[m][nt][r] + conv1_b[co0 + r], 0.f);
                ss[r] += v; qq[r] += v * v;
                float p = __shfl_xor(v, 1);            // pool partner t^1
                if ((l15 & 1) == 0)
                    s_y2t[(t >> 1) * 136 + co0 + r] = (_Float16)fmaxf(v, p);
            }
        }
#pragma unroll
        for (int r = 0; r < 4; ++r) {
            float s = ss[r], q = qq[r];
            s += __shfl_xor(s, 1); s += __shfl_xor(s, 2); s += __shfl_xor(s, 4); s += __shfl_xor(s, 8);
            q += __shfl_xor(q, 1); q += __shfl_xor(q, 2); q += __shfl_xor(q, 4); q += __shfl_xor(q, 8);
            if (l15 == 0) {
                atomicAdd(&rep[co0 + r], s);
                atomicAdd(&rep[128 + co0 + r], q);
            }
        }
    }
    __syncthreads();
    // coalesced store: 48 rows of 128 f16
    _Float16* dst = y2p + (long long)be * 6144;
    for (int chunk = threadIdx.x; chunk < 768; chunk += 256) {
        int row = chunk >> 4, off = (chunk & 15) * 8;
        *(f16x8*)(dst + row * 128 + off) = *(const f16x8*)(&s_y2t[row * 136 + off]);
    }
}

// ---------------- finalize BN from 64 replicas -> scale/shift (and re-zero replicas) ----------------
__global__ void k_finalize_rep(float* __restrict__ rep, float* stats, int scIdx,
                               const float* __restrict__ g, const float* __restrict__ bb,
                               float inv_count) {
    int j = threadIdx.x;
    float s = 0.f, q = 0.f;
    for (int i = 0; i < NREP; ++i) {
        s += rep[i * 256 + j];
        q += rep[i * 256 + 128 + j];
    }
    for (int i = 0; i < NREP; ++i) {
        rep[i * 256 + j] = 0.f;
        rep[i * 256 + 128 + j] = 0.f;
    }
    float m = s * inv_count;
    float v = fmaxf(q * inv_count - m * m, 0.f);
    float sc = g[j] * rsqrtf(v + EPS);
    stats[scIdx + j] = sc;
    stats[scIdx + 128 + j] = bb[j] - m * sc;
}

// ---------------- K3: load y2pre + BN1 -> LDS, conv2 via f16 MFMA -> y3 (same slot) + BN2 stats ----------------
__global__ __launch_bounds__(256) void k_conv2(_Float16* __restrict__ y23,
                                               const _Float16* __restrict__ apack,
                                               const float* __restrict__ conv2_b,
                                               const float* __restrict__ stats,
                                               float* rep2) {
    __shared__ __align__(16) _Float16 s_y2t[52 * 136];
    int be = blockIdx.x;
    int tid = threadIdx.x;
    float* rep = rep2 + (be & (NREP - 1)) * 256;
    // zero pad rows 48..51
    if (tid < 272) ((int*)(&s_y2t[48 * 136]))[tid] = 0;
    // load y2pre, apply BN1 inline (sc/sh fixed per-thread c-range)
    {
        int c0 = (tid & 15) * 8;
        float4 sca = *(const float4*)(stats + S_BN1_SC + c0);
        float4 scb = *(const float4*)(stats + S_BN1_SC + c0 + 4);
        float4 sha = *(const float4*)(stats + S_BN1_SC + 128 + c0);
        float4 shb = *(const float4*)(stats + S_BN1_SC + 128 + c0 + 4);
        const _Float16* src = y23 + (long long)be * 6144;
#pragma unroll
        for (int kk = 0; kk < 3; ++kk) {
            int row = (tid >> 4) + kk * 16;
            f16x8 g = *(const f16x8*)(src + row * 128 + c0);
            f16x8 o;
            o[0] = (_Float16)fmaf((float)g[0], sca.x, sha.x);
            o[1] = (_Float16)fmaf((float)g[1], sca.y, sha.y);
            o[2] = (_Float16)fmaf((float)g[2], sca.z, sha.z);
            o[3] = (_Float16)fmaf((float)g[3], sca.w, sha.w);
            o[4] = (_Float16)fmaf((float)g[4], scb.x, shb.x);
            o[5] = (_Float16)fmaf((float)g[5], scb.y, shb.y);
            o[6] = (_Float16)fmaf((float)g[6], scb.z, shb.z);
            o[7] = (_Float16)fmaf((float)g[7], scb.w, shb.w);
            *(f16x8*)(&s_y2t[row * 136 + c0]) = o;
        }
    }
    __syncthreads();
    int w = tid >> 6, lane = tid & 63;
    int quad = lane >> 4, l15 = lane & 15;
    f32x4 acc[2][3];
#pragma unroll
    for (int m = 0; m < 2; ++m)
#pragma unroll
        for (int nt = 0; nt < 3; ++nt) acc[m][nt] = (f32x4){0.f, 0.f, 0.f, 0.f};
    const f16x8* Ap = (const f16x8*)apack;
#pragma unroll
    for (int k = 0; k < 5; ++k) {
#pragma unroll
        for (int s = 0; s < 4; ++s) {
            f16x8 a0 = Ap[((k * 4 + s) * 8 + 2 * w) * 64 + lane];
            f16x8 a1 = Ap[((k * 4 + s) * 8 + 2 * w + 1) * 64 + lane];
#pragma unroll
            for (int nt = 0; nt < 3; ++nt) {
                f16x8 bfr = *(const f16x8*)((const char*)s_y2t +
                                            (nt * 16 + l15 + k) * 272 + 64 * s + quad * 16);
                acc[0][nt] = __builtin_amdgcn_mfma_f32_16x16x32_f16(a0, bfr, acc[0][nt], 0, 0, 0);
                acc[1][nt] = __builtin_amdgcn_mfma_f32_16x16x32_f16(a1, bfr, acc[1][nt], 0, 0, 0);
            }
        }
    }
    // epilogue: bias + relu, store y3 into same slot ([128][44] c-major), BN2 stats -> replicas
    _Float16* y3 = y23 + (long long)be * 6144;
#pragma unroll
    for (int m = 0; m < 2; ++m) {
        int co0 = (2 * w + m) * 16 + quad * 4;
        float ssum[4] = {0.f, 0.f, 0.f, 0.f}, qsum[4] = {0.f, 0.f, 0.f, 0.f};
#pragma unroll
        for (int nt = 0; nt < 3; ++nt) {
            int t = nt * 16 + l15;
            bool valid = t < 44;
#pragma unroll
            for (int r = 0; r < 4; ++r) {
                float v = fmaxf(acc[m][nt][r] + conv2_b[co0 + r], 0.f);
                if (valid) {
                    y3[(co0 + r) * 44 + t] = (_Float16)v;
                    ssum[r] += v; qsum[r] += v * v;
                }
            }
        }
#pragma unroll
        for (int r = 0; r < 4; ++r) {
            float s = ssum[r], q = qsum[r];
            s += __shfl_xor(s, 1); s += __shfl_xor(s, 2); s += __shfl_xor(s, 4); s += __shfl_xor(s, 8);
            q += __shfl_xor(q, 1); q += __shfl_xor(q, 2); q += __shfl_xor(q, 4); q += __shfl_xor(q, 8);
            if (l15 == 0) {
                atomicAdd(&rep[co0 + r], s);
                atomicAdd(&rep[128 + co0 + r], q);
            }
        }
    }
}

// ---------------- K5: BN2 apply + attention-pool -> x [BE][128] (256 thr, parallel softmax) ----------------
__global__ __launch_bounds__(256) void k_predatt(const _Float16* __restrict__ y23,
                                                 const float* __restrict__ stats,
                                                 const float* __restrict__ att_w,
                                                 const float* __restrict__ att_b,
                                                 const float* __restrict__ pwt,
                                                 const float* __restrict__ pred_b,
                                                 float* __restrict__ x) {
    __shared__ float h[128 * 45];
    __shared__ float s_att[48];
    __shared__ float s_p1[256];
    __shared__ float s_p2[256];
    __shared__ float s_sc[128], s_sh[128];
    int be = blockIdx.x, tid = threadIdx.x;
    if (tid < 128) {
        s_sc[tid] = stats[S_BN2_SC + tid];
        s_sh[tid] = stats[S_BN2_SC + 128 + tid];
    }
    __syncthreads();
    const f16x2* yp = (const f16x2*)(y23 + (long long)be * 6144);
    for (int i = tid; i < 2816; i += 256) {
        int c = i / 22, t2 = i - c * 22;
        f16x2 v = yp[i];
        float sc = s_sc[c], sh = s_sh[c];
        h[c * 45 + 2 * t2] = fmaf((float)v[0], sc, sh);
        h[c * 45 + 2 * t2 + 1] = fmaf((float)v[1], sc, sh);
    }
    __syncthreads();
    int w = tid >> 6, lane = tid & 63;
    {
        float aw0 = att_w[lane], aw1 = att_w[64 + lane];
        for (int tt = 0; tt < 11; ++tt) {
            int t = w * 11 + tt;
            float p = h[lane * 45 + t] * aw0 + h[(64 + lane) * 45 + t] * aw1;
            p += __shfl_xor(p, 1); p += __shfl_xor(p, 2); p += __shfl_xor(p, 4);
            p += __shfl_xor(p, 8); p += __shfl_xor(p, 16); p += __shfl_xor(p, 32);
            if (lane == 0) s_att[t] = p + att_b[0];
        }
    }
    __syncthreads();
    if (w == 0) {
        float v = (lane < 44) ? s_att[lane] : -1e30f;
        float m = v;
        m = fmaxf(m, __shfl_xor(m, 1)); m = fmaxf(m, __shfl_xor(m, 2));
        m = fmaxf(m, __shfl_xor(m, 4)); m = fmaxf(m, __shfl_xor(m, 8));
        m = fmaxf(m, __shfl_xor(m, 16)); m = fmaxf(m, __shfl_xor(m, 32));
        float ev = (lane < 44) ? expf(v - m) : 0.f;
        float ss = ev;
        ss += __shfl_xor(ss, 1); ss += __shfl_xor(ss, 2); ss += __shfl_xor(ss, 4);
        ss += __shfl_xor(ss, 8); ss += __shfl_xor(ss, 16); ss += __shfl_xor(ss, 32);
        if (lane < 44) s_att[lane] = ev / ss;
    }
    __syncthreads();
    {   // hw partials: c = tid&127, half of t-range each
        int c = tid & 127, hh = tid >> 7;
        float a = 0.f;
        for (int t = hh * 22; t < hh * 22 + 22; ++t) a = fmaf(h[c * 45 + t], s_att[t], a);
        s_p1[tid] = a;
    }
    __syncthreads();
    {   // x partials: o = tid&127, half of c-range; pwt is c-major -> coalesced
        int o = tid & 127, hh = tid >> 7;
        float a = 0.f;
        for (int c = hh * 64; c < hh * 64 + 64; ++c) {
            float hw = s_p1[c] + s_p1[128 + c];
            a = fmaf(pwt[c * 128 + o], hw, a);
        }
        s_p2[tid] = a;
    }
    __syncthreads();
    if (tid < 128) {
        float a = s_p2[tid] + s_p2[128 + tid] + pred_b[tid];
        x[(long long)be * 128 + tid] = a * (1.0f / 44.0f);
    }
}

// ---------------- generic linear (IN -> 128) + ELU, 8 rows per block ----------------
template <int IN>
__global__ __launch_bounds__(128) void k_linear(const float* __restrict__ in,
                                                const float* __restrict__ W,
                                                const float* __restrict__ bias,
                                                float* __restrict__ out) {
    __shared__ float s_in[8 * IN];
    int r0 = blockIdx.x * 8;
    int j = threadIdx.x;
    for (int i = j; i < 8 * IN; i += 128) s_in[i] = in[(long long)r0 * IN + i];
    __syncthreads();
    float acc[8];
    float bj = bias[j];
#pragma unroll
    for (int e = 0; e < 8; ++e) acc[e] = bj;
    for (int i = 0; i < IN; ++i) {
        float w = W[j * IN + i];
#pragma unroll
        for (int e = 0; e < 8; ++e) acc[e] = fmaf(s_in[e * IN + i], w, acc[e]);
    }
#pragma unroll
    for (int e = 0; e < 8; ++e) out[(long long)(r0 + e) * 128 + j] = eluf(acc[e]);
}

// ---------------- linear + ELU + fused column stats into replicas ----------------
template <int IN>
__global__ __launch_bounds__(128) void k_linear_stats(const float* __restrict__ in,
                                                      const float* __restrict__ W,
                                                      const float* __restrict__ bias,
                                                      float* __restrict__ out,
                                                      float* __restrict__ repm) {
    __shared__ float s_in[8 * IN];
    int r0 = blockIdx.x * 8;
    int j = threadIdx.x;
    for (int i = j; i < 8 * IN; i += 128) s_in[i] = in[(long long)r0 * IN + i];
    __syncthreads();
    float acc[8];
    float bj = bias[j];
#pragma unroll
    for (int e = 0; e < 8; ++e) acc[e] = bj;
    for (int i = 0; i < IN; ++i) {
        float w = W[j * IN + i];
#pragma unroll
        for (int e = 0; e < 8; ++e) acc[e] = fmaf(s_in[e * IN + i], w, acc[e]);
    }
    float s = 0.f, q = 0.f;
#pragma unroll
    for (int e = 0; e < 8; ++e) {
        float o = eluf(acc[e]);
        out[(long long)(r0 + e) * 128 + j] = o;
        s += o; q += o * o;
    }
    float* rep = repm + (blockIdx.x & (NREP - 1)) * 256;
    atomicAdd(&rep[j], s);
    atomicAdd(&rep[128 + j], q);
}

// ---------------- edge2node scatter-mean with inline BN-M1 ----------------
__global__ __launch_bounds__(128) void k_e2n(const float* __restrict__ bufB,
                                             const int* __restrict__ inc,
                                             const float* __restrict__ stats,
                                             float* __restrict__ xn) {
    int bn = blockIdx.x;
    int b = bn / NN, n = bn - b * NN;
    int j = threadIdx.x;
    float sc = stats[S_M1_SC + j], sh = stats[S_M1_SC + 128 + j];
    float s = 0.f;
    for (int k = 0; k < NN - 1; ++k) {
        int e = inc[n * (NN - 1) + k];
        s += bufB[(long long)(b * EE + e) * 128 + j];
    }
    xn[bn * 128 + j] = (s * sc + (float)(NN - 1) * sh) * (1.0f / (float)NN);
}

// ---------------- mlp3 layer1: gather-concat [send|recv|skip] with inline BN-M2/BN-M1 ----------------
__global__ __launch_bounds__(128) void k_mlp3l1(const float* __restrict__ xn,
                                                const float* __restrict__ bufB,
                                                const int* __restrict__ sidx,
                                                const int* __restrict__ ridx,
                                                const float* __restrict__ stats,
                                                const float* __restrict__ W,
                                                const float* __restrict__ bias,
                                                float* __restrict__ out) {
    __shared__ float s_in[8 * 384];
    int r0 = blockIdx.x * 8;
    int j = threadIdx.x;
    float sc2 = stats[S_M2_SC + j], sh2 = stats[S_M2_SC + 128 + j];
    float sc1 = stats[S_M1_SC + j], sh1 = stats[S_M1_SC + 128 + j];
    for (int e = 0; e < 8; ++e) {
        int r = r0 + e;
        int b = r / EE, ed = r - b * EE;
        s_in[e * 384 + j] = fmaf(xn[(b * NN + sidx[ed]) * 128 + j], sc2, sh2);
        s_in[e * 384 + 128 + j] = fmaf(xn[(b * NN + ridx[ed]) * 128 + j], sc2, sh2);
        s_in[e * 384 + 256 + j] = fmaf(bufB[(long long)r * 128 + j], sc1, sh1);
    }
    __syncthreads();
    float acc[8];
    float bj = bias[j];
#pragma unroll
    for (int e = 0; e < 8; ++e) acc[e] = bj;
    for (int i = 0; i < 384; ++i) {
        float w = W[j * 384 + i];
#pragma unroll
        for (int e = 0; e < 8; ++e) acc[e] = fmaf(s_in[e * 384 + i], w, acc[e]);
    }
#pragma unroll
    for (int e = 0; e < 8; ++e) out[(long long)(r0 + e) * 128 + j] = eluf(acc[e]);
}

// ---------------- BN3 apply + fc_out (128 -> 16) ----------------
__global__ __launch_bounds__(256) void k_fcout(const float* __restrict__ h2,
                                               const float* __restrict__ stats,
                                               const float* __restrict__ fcw,
                                               const float* __restrict__ fcb,
                                               float* __restrict__ out) {
    __shared__ float s_x[16 * 129];
    __shared__ float s_w[16 * 129];
    int r0 = blockIdx.x * 16;
    int tid = threadIdx.x;
    for (int i = tid; i < 16 * 128; i += 256) {
        int rr = i >> 7, j = i & 127;
        s_x[rr * 129 + j] = fmaf(h2[(long long)(r0 + rr) * 128 + j],
                                 stats[S_M3_SC + j], stats[S_M3_SC + 128 + j]);
    }
    for (int i = tid; i < 16 * 128; i += 256) {
        int o = i >> 7, j = i & 127;
        s_w[o * 129 + j] = fcw[i];
    }
    __syncthreads();
    int rl = tid >> 4, o = tid & 15;
    float a = fcb[o];
    for (int j = 0; j < 128; ++j) a = fmaf(s_x[rl * 129 + j], s_w[o * 129 + j], a);
    out[(long long)(r0 + rl) * 16 + o] = a;
}

// ---------------- host launcher ----------------
extern "C" void kernel_launch(void* const* d_in, const int* in_sizes, int n_in,
                              void* d_out, int out_size, void* d_ws, size_t ws_size,
                              hipStream_t stream) {
    const float* inputs = (const float*)d_in[0];
    const float* rel_rec = (const float*)d_in[1];
    const float* rel_send = (const float*)d_in[2];
    const float* conv1_w = (const float*)d_in[3];
    const float* conv1_b = (const float*)d_in[4];
    const float* bn1_g = (const float*)d_in[5];
    const float* bn1_b = (const float*)d_in[6];
    const float* conv2_w = (const float*)d_in[7];
    const float* conv2_b = (const float*)d_in[8];
    const float* bn2_g = (const float*)d_in[9];
    const float* bn2_b = (const float*)d_in[10];
    const float* pred_w = (const float*)d_in[11];
    const float* pred_b = (const float*)d_in[12];
    const float* att_w = (const float*)d_in[13];
    const float* att_b = (const float*)d_in[14];
    const float* m1w1 = (const float*)d_in[15];
    const float* m1b1 = (const float*)d_in[16];
    const float* m1w2 = (const float*)d_in[17];
    const float* m1b2 = (const float*)d_in[18];
    const float* m1g = (const float*)d_in[19];
    const float* m1bb = (const float*)d_in[20];
    const float* m2w1 = (const float*)d_in[21];
    const float* m2b1 = (const float*)d_in[22];
    const float* m2w2 = (const float*)d_in[23];
    const float* m2b2 = (const float*)d_in[24];
    const float* m2g = (const float*)d_in[25];
    const float* m2bb = (const float*)d_in[26];
    const float* m3w1 = (const float*)d_in[27];
    const float* m3b1 = (const float*)d_in[28];
    const float* m3w2 = (const float*)d_in[29];
    const float* m3b2 = (const float*)d_in[30];
    const float* m3g = (const float*)d_in[31];
    const float* m3bb = (const float*)d_in[32];
    const float* fcw = (const float*)d_in[33];
    const float* fcb = (const float*)d_in[34];

    char* ws = (char*)d_ws;
    float* stats = (float*)(ws + OFF_STATS);
    int* sidx = (int*)(ws + OFF_SIDX);
    int* ridx = (int*)(ws + OFF_RIDX);
    int* inc = (int*)(ws + OFF_INC);
    _Float16* y23 = (_Float16*)(ws + OFF_Y23);
    float* x = (float*)(ws + OFF_X);
    float* bufA = (float*)(ws + OFF_BUFA);
    float* bufB = (float*)(ws + OFF_BUFB);
    float* xn = (float*)(ws + OFF_XN);
    float* t640 = (float*)(ws + OFF_T640);
    _Float16* apack = (_Float16*)(ws + OFF_APACK);
    _Float16* apack1 = (_Float16*)(ws + OFF_APACK1);
    float* pwt = (float*)(ws + OFF_PWT);
    float* rep1 = (float*)(ws + OFF_REP1);
    float* rep2 = (float*)(ws + OFF_REP2);
    float* repm = (float*)(ws + OFF_REPM);
    float* outp = (float*)d_out;

    hipLaunchKernelGGL(k_prep, dim3(53), dim3(256), 0, stream,
                       rel_rec, rel_send, conv2_w, conv1_w, pred_w,
                       apack, apack1, pwt, rep1, rep2, repm, sidx, ridx, inc);
    hipLaunchKernelGGL(k_conv1_stats, dim3(BE), dim3(256), 0, stream,
                       inputs, apack1, conv1_b, sidx, ridx, rep1, y23);
    hipLaunchKernelGGL(k_finalize_rep, dim3(1), dim3(128), 0, stream,
                       rep1, stats, S_BN1_SC, bn1_g, bn1_b, 1.0f / (float)(BE * L1));
    hipLaunchKernelGGL(k_conv2, dim3(BE), dim3(256), 0, stream,
                       y23, apack, conv2_b, stats, rep2);
    hipLaunchKernelGGL(k_finalize_rep, dim3(1), dim3(128), 0, stream,
                       rep2, stats, S_BN2_SC, bn2_g, bn2_b, 1.0f / (float)(BE * L2));
    hipLaunchKernelGGL(k_predatt, dim3(BE), dim3(256), 0, stream,
                       y23, stats, att_w, att_b, pwt, pred_b, x);
    // mlp1
    hipLaunchKernelGGL(k_linear<128>, dim3(BE / 8), dim3(128), 0, stream, x, m1w1, m1b1, bufA);
    hipLaunchKernelGGL(k_linear_stats<128>, dim3(BE / 8), dim3(128), 0, stream,
                       bufA, m1w2, m1b2, bufB, repm);
    hipLaunchKernelGGL(k_finalize_rep, dim3(1), dim3(128), 0, stream,
                       repm, stats, S_M1_SC, m1g, m1bb, 1.0f / (float)BE);
    // edge2node (BN-M1 inline) + mlp2
    hipLaunchKernelGGL(k_e2n, dim3(BB * NN), dim3(128), 0, stream, bufB, inc, stats, xn);
    hipLaunchKernelGGL(k_linear<128>, dim3(BB * NN / 8), dim3(128), 0, stream, xn, m2w1, m2b1, t640);
    hipLaunchKernelGGL(k_linear_stats<128>, dim3(BB * NN / 8), dim3(128), 0, stream,
                       t640, m2w2, m2b2, xn, repm);
    hipLaunchKernelGGL(k_finalize_rep, dim3(1), dim3(128), 0, stream,
                       repm, stats, S_M2_SC, m2g, m2bb, 1.0f / (float)(BB * NN));
    // node2edge + mlp3 (BN-M2/M1 inline)
    hipLaunchKernelGGL(k_mlp3l1, dim3(BE / 8), dim3(128), 0, stream,
                       xn, bufB, sidx, ridx, stats, m3w1, m3b1, bufA);
    hipLaunchKernelGGL(k_linear_stats<128>, dim3(BE / 8), dim3(128), 0, stream,
                       bufA, m3w2, m3b2, bufB, repm);
    hipLaunchKernelGGL(k_finalize_rep, dim3(1), dim3(128), 0, stream,
                       repm, stats, S_M3_SC, m3g, m3bb, 1.0f / (float)BE);
    // fc_out (BN-M3 inline)
    hipLaunchKernelGGL(k_fcout, dim3(BE / 16), dim3(256), 0, stream, bufB, stats, fcw, fcb, outp);
    (void)in_sizes; (void)n_in; (void)out_size; (void)ws_size;
}

// Round 8
// 660.270 us; speedup vs baseline: 29.6530x; 1.0701x over previous
//
#include <hip/hip_runtime.h>
#include <hip/hip_bf16.h>
#include <hip/hip_fp16.h>

// ---------------- problem constants ----------------
#define BB 32
#define NN 20
#define TT 100
#define DD 4
#define HH 128
#define EE 380          // N*(N-1)
#define BE 12160        // B*E
#define L1 96           // conv1 out length
#define LP 48           // after maxpool
#define L2 44           // conv2 out length
#define NOUT 16
#define EPS 1e-5f
#define NREP 64         // stats replicas (atomic de-contention)

typedef _Float16 f16x8 __attribute__((ext_vector_type(8)));
typedef _Float16 f16x4 __attribute__((ext_vector_type(4)));
typedef _Float16 f16x2 __attribute__((ext_vector_type(2)));
typedef float f32x4 __attribute__((ext_vector_type(4)));

// stats slot indices (floats): SC at base, SH at base+128
#define S_BN1_SC 256
#define S_BN2_SC 768
#define S_M1_SC 1280
#define S_M2_SC 1792
#define S_M3_SC 2304

// workspace offsets (bytes)
#define OFF_STATS 0ULL
#define OFF_SIDX 16384ULL
#define OFF_RIDX 18432ULL
#define OFF_INC 20480ULL
#define OFF_Y23 24576ULL                     // f16 [BE] slots of 6144: y2pre [48][128] then y3 [128][44]
#define OFF_X 149446656ULL                   // f32 [BE][128]
#define OFF_BUFA 155672576ULL                // f32 [BE][128]; rep1/rep2 live here during conv phase
#define OFF_BUFB 161898496ULL                // f32 [BE][128]
#define OFF_XN 168124416ULL                  // f32 [640][128]
#define OFF_T640 168452096ULL                // conv-phase: apack(160K)+apack1(16K)+pwt(64K)
#define OFF_REPM 168779776ULL                // f32 [64][256] MLP stats replicas
#define OFF_HF16 168845312ULL                // f16 [BE][128] MLP intermediates (3.1 MB)
#define OFF_MP 171958272ULL                  // f16 MLP weight packs (256 KB)
#define OFF_APACK OFF_T640
#define OFF_APACK1 (OFF_T640 + 163840ULL)
#define OFF_PWT (OFF_T640 + 180224ULL)
#define OFF_REP1 OFF_BUFA
#define OFF_REP2 (OFF_BUFA + 65536ULL)
// MP pack offsets in f16 units
#define MP_M1W1 0
#define MP_M1W2 16384
#define MP_M2W1 32768
#define MP_M2W2 49152
#define MP_M3W2 65536
#define MP_M3W1 81920

__device__ __forceinline__ float eluf(float v) { return v > 0.f ? v : expm1f(v); }

// ---------------- K prep: pack all MFMA weights, transpose pred_w, init tables ----------------
__global__ __launch_bounds__(256) void k_prep(const float* __restrict__ rel_rec,
                                              const float* __restrict__ rel_send,
                                              const float* __restrict__ w2,
                                              const float* __restrict__ w1,
                                              const float* __restrict__ pred_w,
                                              const float* __restrict__ m1w1,
                                              const float* __restrict__ m1w2,
                                              const float* __restrict__ m2w1,
                                              const float* __restrict__ m2w2,
                                              const float* __restrict__ m3w1,
                                              const float* __restrict__ m3w2,
                                              _Float16* __restrict__ apack,
                                              _Float16* __restrict__ apack1,
                                              float* __restrict__ pwt,
                                              _Float16* __restrict__ mp,
                                              float* rep1, float* rep2, float* repm,
                                              int* sidx, int* ridx, int* inc) {
    int b = blockIdx.x;
    int tid = threadIdx.x;
    int l = tid & 63;
    if (b < 40) {            // conv2_w frags
        int f = b * 4 + (tid >> 6);
        int m0 = f & 7, ks = f >> 3, s = ks & 3, k = ks >> 2;
        int m = m0 * 16 + (l & 15);
        int cbase = 32 * s + (l >> 4) * 8;
#pragma unroll
        for (int j = 0; j < 8; ++j)
            apack[(f * 64 + l) * 8 + j] = (_Float16)w2[m * 640 + (cbase + j) * 5 + k];
    } else if (b < 44) {     // conv1_w frags: K=40 padded to 64
        int f = (b - 40) * 4 + (tid >> 6);
        int m0 = f & 7, s = f >> 3;
        int m = m0 * 16 + (l & 15);
        int cbase = 32 * s + (l >> 4) * 8;
#pragma unroll
        for (int j = 0; j < 8; ++j) {
            int c = cbase + j;
            apack1[(f * 64 + l) * 8 + j] = (c < 40) ? (_Float16)w1[m * 40 + c] : (_Float16)0.f;
        }
    } else if (b == 44) {    // init: zero replicas, build edge tables
        for (int i = tid; i < NREP * 256; i += 256) { rep1[i] = 0.f; rep2[i] = 0.f; repm[i] = 0.f; }
        for (int e = tid; e < EE; e += 256) {
            int s = 0, r = 0;
            for (int n = 0; n < NN; ++n) {
                if (rel_send[e * NN + n] > 0.5f) s = n;
                if (rel_rec[e * NN + n] > 0.5f) r = n;
            }
            sidx[e] = s; ridx[e] = r;
        }
        __syncthreads();
        if (tid < NN) {
            int k = 0;
            for (int e = 0; e < EE; ++e)
                if (ridx[e] == tid) inc[tid * (NN - 1) + (k++)] = e;
        }
    } else if (b < 53) {     // transpose pred_w -> pwt[c][o]
        int idx = (b - 45) * 2048 + tid;
        for (int rep = 0; rep < 8; ++rep, idx += 256) {
            int o = idx >> 7, c = idx & 127;
            pwt[c * 128 + o] = pred_w[idx];
        }
    } else {                 // MLP weight packs: generic [128][K] -> A-frag-linear
        int idx = b - 53;    // 0..63
        const float* W; _Float16* dst; int K;
        if (idx < 8)       { W = m1w1; dst = mp + MP_M1W1; K = 128; }
        else if (idx < 16) { W = m1w2; dst = mp + MP_M1W2; K = 128; idx -= 8; }
        else if (idx < 24) { W = m2w1; dst = mp + MP_M2W1; K = 128; idx -= 16; }
        else if (idx < 32) { W = m2w2; dst = mp + MP_M2W2; K = 128; idx -= 24; }
        else if (idx < 40) { W = m3w2; dst = mp + MP_M3W2; K = 128; idx -= 32; }
        else               { W = m3w1; dst = mp + MP_M3W1; K = 384; idx -= 40; }
        int f = idx * 4 + (tid >> 6);
        int s = f >> 3, m0 = f & 7;
        int m = m0 * 16 + (l & 15);
        int cb = 32 * s + (l >> 4) * 8;
#pragma unroll
        for (int j = 0; j < 8; ++j)
            dst[(f * 64 + l) * 8 + j] = (_Float16)W[m * K + cb + j];
    }
}

// ---------------- shared helpers ----------------
__device__ __forceinline__ void load_edges(float* s_edges,
                                           const float* __restrict__ inputs,
                                           int b, int sn, int rn) {
    for (int i = threadIdx.x; i < 800; i += 256) {
        int ci = i / 100, t = i - ci * 100;
        int n = (ci < 4) ? sn : rn;
        int d = ci & 3;
        s_edges[ci * 100 + t] = inputs[((b * NN + n) * TT + t) * DD + d];
    }
}

__device__ __forceinline__ void build_x1(_Float16* s_x1, const float* s_edges) {
    for (int i = threadIdx.x; i < 96 * 64; i += 256) {
        int t = i >> 6, c = i & 63;
        float v = 0.f;
        if (c < 40) {
            int ci = (c * 205) >> 10;
            int k = c - 5 * ci;
            v = s_edges[ci * 100 + t + k];
        }
        s_x1[t * 72 + c] = (_Float16)v;
    }
}

__device__ __forceinline__ void conv1_mfma(const _Float16* __restrict__ apack1,
                                           const _Float16* s_x1,
                                           int w, int lane, int quad, int l15,
                                           f32x4 acc1[2][6]) {
#pragma unroll
    for (int m = 0; m < 2; ++m)
#pragma unroll
        for (int nt = 0; nt < 6; ++nt) acc1[m][nt] = (f32x4){0.f, 0.f, 0.f, 0.f};
    const f16x8* Ap = (const f16x8*)apack1;
#pragma unroll
    for (int s = 0; s < 2; ++s) {
        f16x8 a0 = Ap[(s * 8 + 2 * w) * 64 + lane];
        f16x8 a1 = Ap[(s * 8 + 2 * w + 1) * 64 + lane];
#pragma unroll
        for (int nt = 0; nt < 6; ++nt) {
            f16x8 bfr = *(const f16x8*)((const char*)s_x1 +
                                        (nt * 16 + l15) * 144 + 64 * s + quad * 16);
            acc1[0][nt] = __builtin_amdgcn_mfma_f32_16x16x32_f16(a0, bfr, acc1[0][nt], 0, 0, 0);
            acc1[1][nt] = __builtin_amdgcn_mfma_f32_16x16x32_f16(a1, bfr, acc1[1][nt], 0, 0, 0);
        }
    }
}

// ---------------- K1: conv1 (MFMA) + relu -> BN1 stats + PRE-BN maxpool -> y2pre ----------------
// pool-before-BN exact: bn1_g=1 -> BN scale>0 -> max commutes with fma.
__global__ __launch_bounds__(256) void k_conv1_stats(const float* __restrict__ inputs,
                                                     const _Float16* __restrict__ apack1,
                                                     const float* __restrict__ conv1_b,
                                                     const int* __restrict__ sidx,
                                                     const int* __restrict__ ridx,
                                                     float* rep1,
                                                     _Float16* __restrict__ y2p) {
    __shared__ float s_edges[800];
    __shared__ __align__(16) _Float16 s_x1[96 * 72];
    __shared__ __align__(16) _Float16 s_y2t[48 * 136];
    int be = blockIdx.x;
    int b = be / EE, e = be - b * EE;
    float* rep = rep1 + (be & (NREP - 1)) * 256;
    load_edges(s_edges, inputs, b, sidx[e], ridx[e]);
    __syncthreads();
    build_x1(s_x1, s_edges);
    __syncthreads();
    int w = threadIdx.x >> 6, lane = threadIdx.x & 63;
    int quad = lane >> 4, l15 = lane & 15;
    f32x4 acc1[2][6];
    conv1_mfma(apack1, s_x1, w, lane, quad, l15, acc1);
#pragma unroll
    for (int m = 0; m < 2; ++m) {
        int co0 = (2 * w + m) * 16 + quad * 4;
        float ss[4] = {0.f, 0.f, 0.f, 0.f}, qq[4] = {0.f, 0.f, 0.f, 0.f};
#pragma unroll
        for (int nt = 0; nt < 6; ++nt) {
            int t = nt * 16 + l15;
#pragma unroll
            for (int r = 0; r < 4; ++r) {
                float v = fmaxf(acc1[m][nt][r] + conv1_b[co0 + r], 0.f);
                ss[r] += v; qq[r] += v * v;
                float p = __shfl_xor(v, 1);
                if ((l15 & 1) == 0)
                    s_y2t[(t >> 1) * 136 + co0 + r] = (_Float16)fmaxf(v, p);
            }
        }
#pragma unroll
        for (int r = 0; r < 4; ++r) {
            float s = ss[r], q = qq[r];
            s += __shfl_xor(s, 1); s += __shfl_xor(s, 2); s += __shfl_xor(s, 4); s += __shfl_xor(s, 8);
            q += __shfl_xor(q, 1); q += __shfl_xor(q, 2); q += __shfl_xor(q, 4); q += __shfl_xor(q, 8);
            if (l15 == 0) {
                atomicAdd(&rep[co0 + r], s);
                atomicAdd(&rep[128 + co0 + r], q);
            }
        }
    }
    __syncthreads();
    _Float16* dst = y2p + (long long)be * 6144;
    for (int chunk = threadIdx.x; chunk < 768; chunk += 256) {
        int row = chunk >> 4, off = (chunk & 15) * 8;
        *(f16x8*)(dst + row * 128 + off) = *(const f16x8*)(&s_y2t[row * 136 + off]);
    }
}

// ---------------- finalize BN from 64 replicas -> scale/shift (re-zero replicas) ----------------
__global__ void k_finalize_rep(float* __restrict__ rep, float* stats, int scIdx,
                               const float* __restrict__ g, const float* __restrict__ bb,
                               float inv_count) {
    int j = threadIdx.x;
    float s = 0.f, q = 0.f;
    for (int i = 0; i < NREP; ++i) {
        s += rep[i * 256 + j];
        q += rep[i * 256 + 128 + j];
    }
    for (int i = 0; i < NREP; ++i) {
        rep[i * 256 + j] = 0.f;
        rep[i * 256 + 128 + j] = 0.f;
    }
    float m = s * inv_count;
    float v = fmaxf(q * inv_count - m * m, 0.f);
    float sc = g[j] * rsqrtf(v + EPS);
    stats[scIdx + j] = sc;
    stats[scIdx + 128 + j] = bb[j] - m * sc;
}

// ---------------- K3: 4 edges/block; y2pre+BN1 -> LDS, conv2 f16 MFMA -> y3 + BN2 stats ----------------
// Wave w: mtile group g=w&1 (mtiles 4g..4g+3), edge pair p=w>>1 (edges 2p,2p+1).
// Each B-frag read feeds 4 MFMAs; A-frags reused across 2 edges x 3 ntiles.
__global__ __launch_bounds__(256, 2) void k_conv2(_Float16* __restrict__ y23,
                                                  const _Float16* __restrict__ apack,
                                                  const float* __restrict__ conv2_b,
                                                  const float* __restrict__ stats,
                                                  float* rep2) {
    __shared__ __align__(16) _Float16 s_y2t[4][52 * 136];
    int tid = threadIdx.x;
    int be0 = blockIdx.x * 4;
    // zero pad rows 48..51 for all 4 edges
    for (int i = tid; i < 1088; i += 256) {
        int ed = i / 272, rem = i - ed * 272;
        ((int*)(&s_y2t[ed][48 * 136]))[rem] = 0;
    }
    // load y2pre + BN1 inline: c0 fixed per thread
    {
        int c0 = (tid & 15) * 8;
        float4 sca = *(const float4*)(stats + S_BN1_SC + c0);
        float4 scb = *(const float4*)(stats + S_BN1_SC + c0 + 4);
        float4 sha = *(const float4*)(stats + S_BN1_SC + 128 + c0);
        float4 shb = *(const float4*)(stats + S_BN1_SC + 128 + c0 + 4);
        for (int i = tid; i < 3072; i += 256) {
            int ed = i / 768, rem = i - ed * 768;
            int row = rem >> 4;
            f16x8 g = *(const f16x8*)(y23 + (long long)(be0 + ed) * 6144 + row * 128 + c0);
            f16x8 o;
            o[0] = (_Float16)fmaf((float)g[0], sca.x, sha.x);
            o[1] = (_Float16)fmaf((float)g[1], sca.y, sha.y);
            o[2] = (_Float16)fmaf((float)g[2], sca.z, sha.z);
            o[3] = (_Float16)fmaf((float)g[3], sca.w, sha.w);
            o[4] = (_Float16)fmaf((float)g[4], scb.x, shb.x);
            o[5] = (_Float16)fmaf((float)g[5], scb.y, shb.y);
            o[6] = (_Float16)fmaf((float)g[6], scb.z, shb.z);
            o[7] = (_Float16)fmaf((float)g[7], scb.w, shb.w);
            *(f16x8*)(&s_y2t[ed][row * 136 + c0]) = o;
        }
    }
    __syncthreads();
    int w = tid >> 6, lane = tid & 63;
    int quad = lane >> 4, l15 = lane & 15;
    int g = w & 1, p = w >> 1;
    f32x4 acc[4][3][2];
#pragma unroll
    for (int m = 0; m < 4; ++m)
#pragma unroll
        for (int nt = 0; nt < 3; ++nt)
#pragma unroll
            for (int e = 0; e < 2; ++e) acc[m][nt][e] = (f32x4){0.f, 0.f, 0.f, 0.f};
    const f16x8* Ap = (const f16x8*)apack;
#pragma unroll
    for (int k = 0; k < 5; ++k) {
#pragma unroll
        for (int s = 0; s < 4; ++s) {
            f16x8 am[4];
#pragma unroll
            for (int m = 0; m < 4; ++m)
                am[m] = Ap[((k * 4 + s) * 8 + g * 4 + m) * 64 + lane];
#pragma unroll
            for (int e = 0; e < 2; ++e) {
                const char* base = (const char*)&s_y2t[2 * p + e][0];
#pragma unroll
                for (int nt = 0; nt < 3; ++nt) {
                    f16x8 bfr = *(const f16x8*)(base + (nt * 16 + l15 + k) * 272 + 64 * s + quad * 16);
#pragma unroll
                    for (int m = 0; m < 4; ++m)
                        acc[m][nt][e] = __builtin_amdgcn_mfma_f32_16x16x32_f16(am[m], bfr, acc[m][nt][e], 0, 0, 0);
                }
            }
        }
    }
    // epilogue per edge: bias + relu, store y3 (same slot), BN2 stats
#pragma unroll
    for (int e = 0; e < 2; ++e) {
        int be = be0 + 2 * p + e;
        _Float16* y3 = y23 + (long long)be * 6144;
        float* rep = rep2 + (be & (NREP - 1)) * 256;
#pragma unroll
        for (int m = 0; m < 4; ++m) {
            int co0 = (g * 4 + m) * 16 + quad * 4;
            float ssum[4] = {0.f, 0.f, 0.f, 0.f}, qsum[4] = {0.f, 0.f, 0.f, 0.f};
#pragma unroll
            for (int nt = 0; nt < 3; ++nt) {
                int t = nt * 16 + l15;
                bool valid = t < 44;
#pragma unroll
                for (int r = 0; r < 4; ++r) {
                    float v = fmaxf(acc[m][nt][e][r] + conv2_b[co0 + r], 0.f);
                    if (valid) {
                        y3[(co0 + r) * 44 + t] = (_Float16)v;
                        ssum[r] += v; qsum[r] += v * v;
                    }
                }
            }
#pragma unroll
            for (int r = 0; r < 4; ++r) {
                float s = ssum[r], q = qsum[r];
                s += __shfl_xor(s, 1); s += __shfl_xor(s, 2); s += __shfl_xor(s, 4); s += __shfl_xor(s, 8);
                q += __shfl_xor(q, 1); q += __shfl_xor(q, 2); q += __shfl_xor(q, 4); q += __shfl_xor(q, 8);
                if (l15 == 0) {
                    atomicAdd(&rep[co0 + r], s);
                    atomicAdd(&rep[128 + co0 + r], q);
                }
            }
        }
    }
}

// ---------------- K5: BN2 apply + attention-pool -> x [BE][128] ----------------
__global__ __launch_bounds__(256) void k_predatt(const _Float16* __restrict__ y23,
                                                 const float* __restrict__ stats,
                                                 const float* __restrict__ att_w,
                                                 const float* __restrict__ att_b,
                                                 const float* __restrict__ pwt,
                                                 const float* __restrict__ pred_b,
                                                 float* __restrict__ x) {
    __shared__ float h[128 * 45];
    __shared__ float s_att[48];
    __shared__ float s_p1[256];
    __shared__ float s_p2[256];
    __shared__ float s_sc[128], s_sh[128];
    int be = blockIdx.x, tid = threadIdx.x;
    if (tid < 128) {
        s_sc[tid] = stats[S_BN2_SC + tid];
        s_sh[tid] = stats[S_BN2_SC + 128 + tid];
    }
    __syncthreads();
    const f16x2* yp = (const f16x2*)(y23 + (long long)be * 6144);
    for (int i = tid; i < 2816; i += 256) {
        int c = i / 22, t2 = i - c * 22;
        f16x2 v = yp[i];
        float sc = s_sc[c], sh = s_sh[c];
        h[c * 45 + 2 * t2] = fmaf((float)v[0], sc, sh);
        h[c * 45 + 2 * t2 + 1] = fmaf((float)v[1], sc, sh);
    }
    __syncthreads();
    int w = tid >> 6, lane = tid & 63;
    {
        float aw0 = att_w[lane], aw1 = att_w[64 + lane];
        for (int tt = 0; tt < 11; ++tt) {
            int t = w * 11 + tt;
            float p = h[lane * 45 + t] * aw0 + h[(64 + lane) * 45 + t] * aw1;
            p += __shfl_xor(p, 1); p += __shfl_xor(p, 2); p += __shfl_xor(p, 4);
            p += __shfl_xor(p, 8); p += __shfl_xor(p, 16); p += __shfl_xor(p, 32);
            if (lane == 0) s_att[t] = p + att_b[0];
        }
    }
    __syncthreads();
    if (w == 0) {
        float v = (lane < 44) ? s_att[lane] : -1e30f;
        float m = v;
        m = fmaxf(m, __shfl_xor(m, 1)); m = fmaxf(m, __shfl_xor(m, 2));
        m = fmaxf(m, __shfl_xor(m, 4)); m = fmaxf(m, __shfl_xor(m, 8));
        m = fmaxf(m, __shfl_xor(m, 16)); m = fmaxf(m, __shfl_xor(m, 32));
        float ev = (lane < 44) ? expf(v - m) : 0.f;
        float ss = ev;
        ss += __shfl_xor(ss, 1); ss += __shfl_xor(ss, 2); ss += __shfl_xor(ss, 4);
        ss += __shfl_xor(ss, 8); ss += __shfl_xor(ss, 16); ss += __shfl_xor(ss, 32);
        if (lane < 44) s_att[lane] = ev / ss;
    }
    __syncthreads();
    {
        int c = tid & 127, hh = tid >> 7;
        float a = 0.f;
        for (int t = hh * 22; t < hh * 22 + 22; ++t) a = fmaf(h[c * 45 + t], s_att[t], a);
        s_p1[tid] = a;
    }
    __syncthreads();
    {
        int o = tid & 127, hh = tid >> 7;
        float a = 0.f;
        for (int c = hh * 64; c < hh * 64 + 64; ++c) {
            float hw = s_p1[c] + s_p1[128 + c];
            a = fmaf(pwt[c * 128 + o], hw, a);
        }
        s_p2[tid] = a;
    }
    __syncthreads();
    if (tid < 128) {
        float a = s_p2[tid] + s_p2[128 + tid] + pred_b[tid];
        x[(long long)be * 128 + tid] = a * (1.0f / 44.0f);
    }
}

// ---------------- MFMA linear (128 -> 128), 64 rows/block ----------------
// IN16: input f16 [R][128] else f32. OUT16: output f16 else f32. STATS: fused col-stats.
template <bool IN16, bool OUT16, bool STATS>
__global__ __launch_bounds__(256) void k_linmm(const void* __restrict__ inV,
                                               const _Float16* __restrict__ wp,
                                               const float* __restrict__ bias,
                                               void* __restrict__ outV,
                                               float* __restrict__ repm) {
    __shared__ __align__(16) _Float16 s_b[64 * 136];
    int tid = threadIdx.x;
    long long r0 = (long long)blockIdx.x * 64;
    if (IN16) {
        const f16x8* src = (const f16x8*)((const _Float16*)inV + r0 * 128);
        for (int i = tid; i < 1024; i += 256) {
            int row = i >> 4, c0 = (i & 15) * 8;
            *(f16x8*)(&s_b[row * 136 + c0]) = src[i];
        }
    } else {
        const float4* src = (const float4*)((const float*)inV + r0 * 128);
        for (int i = tid; i < 2048; i += 256) {
            int row = i >> 5, c0 = (i & 31) * 4;
            float4 v = src[i];
            f16x4 o = {(_Float16)v.x, (_Float16)v.y, (_Float16)v.z, (_Float16)v.w};
            *(f16x4*)(&s_b[row * 136 + c0]) = o;
        }
    }
    __syncthreads();
    int w = tid >> 6, lane = tid & 63, quad = lane >> 4, l15 = lane & 15;
    f32x4 acc[2][4];
#pragma unroll
    for (int m = 0; m < 2; ++m)
#pragma unroll
        for (int nt = 0; nt < 4; ++nt) acc[m][nt] = (f32x4){0.f, 0.f, 0.f, 0.f};
    const f16x8* Ap = (const f16x8*)wp;
#pragma unroll
    for (int s = 0; s < 4; ++s) {
        f16x8 a0 = Ap[(s * 8 + 2 * w) * 64 + lane];
        f16x8 a1 = Ap[(s * 8 + 2 * w + 1) * 64 + lane];
#pragma unroll
        for (int nt = 0; nt < 4; ++nt) {
            f16x8 bfr = *(const f16x8*)((const char*)s_b + (nt * 16 + l15) * 272 + 64 * s + quad * 16);
            acc[0][nt] = __builtin_amdgcn_mfma_f32_16x16x32_f16(a0, bfr, acc[0][nt], 0, 0, 0);
            acc[1][nt] = __builtin_amdgcn_mfma_f32_16x16x32_f16(a1, bfr, acc[1][nt], 0, 0, 0);
        }
    }
#pragma unroll
    for (int m = 0; m < 2; ++m) {
        int j0 = (2 * w + m) * 16 + quad * 4;
        float4 bs = *(const float4*)(bias + j0);
        float ss[4] = {0.f, 0.f, 0.f, 0.f}, qq[4] = {0.f, 0.f, 0.f, 0.f};
#pragma unroll
        for (int nt = 0; nt < 4; ++nt) {
            int row = nt * 16 + l15;
            float v0 = eluf(acc[m][nt][0] + bs.x);
            float v1 = eluf(acc[m][nt][1] + bs.y);
            float v2 = eluf(acc[m][nt][2] + bs.z);
            float v3 = eluf(acc[m][nt][3] + bs.w);
            if (OUT16) {
                f16x4 o = {(_Float16)v0, (_Float16)v1, (_Float16)v2, (_Float16)v3};
                *(f16x4*)((_Float16*)outV + (r0 + row) * 128 + j0) = o;
            } else {
                float4 o = {v0, v1, v2, v3};
                *(float4*)((float*)outV + (r0 + row) * 128 + j0) = o;
            }
            if (STATS) {
                ss[0] += v0; qq[0] += v0 * v0;
                ss[1] += v1; qq[1] += v1 * v1;
                ss[2] += v2; qq[2] += v2 * v2;
                ss[3] += v3; qq[3] += v3 * v3;
            }
        }
        if (STATS) {
            float* rep = repm + (blockIdx.x & (NREP - 1)) * 256;
#pragma unroll
            for (int r = 0; r < 4; ++r) {
                float s = ss[r], q = qq[r];
                s += __shfl_xor(s, 1); s += __shfl_xor(s, 2); s += __shfl_xor(s, 4); s += __shfl_xor(s, 8);
                q += __shfl_xor(q, 1); q += __shfl_xor(q, 2); q += __shfl_xor(q, 4); q += __shfl_xor(q, 8);
                if (l15 == 0) {
                    atomicAdd(&rep[j0 + r], s);
                    atomicAdd(&rep[128 + j0 + r], q);
                }
            }
        }
    }
}

// ---------------- MFMA mlp3 l1: gather-concat [send|recv|skip] (K=384) -> 128 f16 ----------------
__global__ __launch_bounds__(256) void k_linmm3(const float* __restrict__ xn,
                                                const float* __restrict__ bufB,
                                                const int* __restrict__ sidx,
                                                const int* __restrict__ ridx,
                                                const float* __restrict__ stats,
                                                const _Float16* __restrict__ wp,
                                                const float* __restrict__ bias,
                                                _Float16* __restrict__ out) {
    __shared__ __align__(16) _Float16 s_b[64 * 392];
    __shared__ float s_st[4][128];
    __shared__ int s_s[64], s_r[64];
    int tid = threadIdx.x;
    long long r0 = (long long)blockIdx.x * 64;
    if (tid < 128) {
        s_st[0][tid] = stats[S_M2_SC + tid];
        s_st[1][tid] = stats[S_M2_SC + 128 + tid];
        s_st[2][tid] = stats[S_M1_SC + tid];
        s_st[3][tid] = stats[S_M1_SC + 128 + tid];
    }
    if (tid < 64) {
        int r = (int)r0 + tid, b = r / EE, ed = r - b * EE;
        s_s[tid] = (b * NN + sidx[ed]) * 128;
        s_r[tid] = (b * NN + ridx[ed]) * 128;
    }
    __syncthreads();
    for (int i = tid; i < 8192; i += 256) {
        int row = i >> 7, j = i & 127;
        float sc2 = s_st[0][j], sh2 = s_st[1][j];
        s_b[row * 392 + j] = (_Float16)fmaf(xn[s_s[row] + j], sc2, sh2);
        s_b[row * 392 + 128 + j] = (_Float16)fmaf(xn[s_r[row] + j], sc2, sh2);
        s_b[row * 392 + 256 + j] = (_Float16)fmaf(bufB[(r0 + row) * 128 + j], s_st[2][j], s_st[3][j]);
    }
    __syncthreads();
    int w = tid >> 6, lane = tid & 63, quad = lane >> 4, l15 = lane & 15;
    f32x4 acc[2][4];
#pragma unroll
    for (int m = 0; m < 2; ++m)
#pragma unroll
        for (int nt = 0; nt < 4; ++nt) acc[m][nt] = (f32x4){0.f, 0.f, 0.f, 0.f};
    const f16x8* Ap = (const f16x8*)wp;
#pragma unroll
    for (int s = 0; s < 12; ++s) {
        f16x8 a0 = Ap[(s * 8 + 2 * w) * 64 + lane];
        f16x8 a1 = Ap[(s * 8 + 2 * w + 1) * 64 + lane];
#pragma unroll
        for (int nt = 0; nt < 4; ++nt) {
            f16x8 bfr = *(const f16x8*)((const char*)s_b + (nt * 16 + l15) * 784 + 64 * s + quad * 16);
            acc[0][nt] = __builtin_amdgcn_mfma_f32_16x16x32_f16(a0, bfr, acc[0][nt], 0, 0, 0);
            acc[1][nt] = __builtin_amdgcn_mfma_f32_16x16x32_f16(a1, bfr, acc[1][nt], 0, 0, 0);
        }
    }
#pragma unroll
    for (int m = 0; m < 2; ++m) {
        int j0 = (2 * w + m) * 16 + quad * 4;
        float4 bs = *(const float4*)(bias + j0);
#pragma unroll
        for (int nt = 0; nt < 4; ++nt) {
            int row = nt * 16 + l15;
            f16x4 o = {(_Float16)eluf(acc[m][nt][0] + bs.x),
                       (_Float16)eluf(acc[m][nt][1] + bs.y),
                       (_Float16)eluf(acc[m][nt][2] + bs.z),
                       (_Float16)eluf(acc[m][nt][3] + bs.w)};
            *(f16x4*)(out + (r0 + row) * 128 + j0) = o;
        }
    }
}

// ---------------- edge2node scatter-mean with inline BN-M1 ----------------
__global__ __launch_bounds__(128) void k_e2n(const float* __restrict__ bufB,
                                             const int* __restrict__ inc,
                                             const float* __restrict__ stats,
                                             float* __restrict__ xn) {
    int bn = blockIdx.x;
    int b = bn / NN, n = bn - b * NN;
    int j = threadIdx.x;
    float sc = stats[S_M1_SC + j], sh = stats[S_M1_SC + 128 + j];
    float s = 0.f;
    for (int k = 0; k < NN - 1; ++k) {
        int e = inc[n * (NN - 1) + k];
        s += bufB[(long long)(b * EE + e) * 128 + j];
    }
    xn[bn * 128 + j] = (s * sc + (float)(NN - 1) * sh) * (1.0f / (float)NN);
}

// ---------------- BN3 apply + fc_out (128 -> 16) ----------------
__global__ __launch_bounds__(256) void k_fcout(const float* __restrict__ h2,
                                               const float* __restrict__ stats,
                                               const float* __restrict__ fcw,
                                               const float* __restrict__ fcb,
                                               float* __restrict__ out) {
    __shared__ float s_x[16 * 129];
    __shared__ float s_w[16 * 129];
    int r0 = blockIdx.x * 16;
    int tid = threadIdx.x;
    for (int i = tid; i < 16 * 128; i += 256) {
        int rr = i >> 7, j = i & 127;
        s_x[rr * 129 + j] = fmaf(h2[(long long)(r0 + rr) * 128 + j],
                                 stats[S_M3_SC + j], stats[S_M3_SC + 128 + j]);
    }
    for (int i = tid; i < 16 * 128; i += 256) {
        int o = i >> 7, j = i & 127;
        s_w[o * 129 + j] = fcw[i];
    }
    __syncthreads();
    int rl = tid >> 4, o = tid & 15;
    float a = fcb[o];
    for (int j = 0; j < 128; ++j) a = fmaf(s_x[rl * 129 + j], s_w[o * 129 + j], a);
    out[(long long)(r0 + rl) * 16 + o] = a;
}

// ---------------- host launcher ----------------
extern "C" void kernel_launch(void* const* d_in, const int* in_sizes, int n_in,
                              void* d_out, int out_size, void* d_ws, size_t ws_size,
                              hipStream_t stream) {
    const float* inputs = (const float*)d_in[0];
    const float* rel_rec = (const float*)d_in[1];
    const float* rel_send = (const float*)d_in[2];
    const float* conv1_w = (const float*)d_in[3];
    const float* conv1_b = (const float*)d_in[4];
    const float* bn1_g = (const float*)d_in[5];
    const float* bn1_b = (const float*)d_in[6];
    const float* conv2_w = (const float*)d_in[7];
    const float* conv2_b = (const float*)d_in[8];
    const float* bn2_g = (const float*)d_in[9];
    const float* bn2_b = (const float*)d_in[10];
    const float* pred_w = (const float*)d_in[11];
    const float* pred_b = (const float*)d_in[12];
    const float* att_w = (const float*)d_in[13];
    const float* att_b = (const float*)d_in[14];
    const float* m1w1 = (const float*)d_in[15];
    const float* m1b1 = (const float*)d_in[16];
    const float* m1w2 = (const float*)d_in[17];
    const float* m1b2 = (const float*)d_in[18];
    const float* m1g = (const float*)d_in[19];
    const float* m1bb = (const float*)d_in[20];
    const float* m2w1 = (const float*)d_in[21];
    const float* m2b1 = (const float*)d_in[22];
    const float* m2w2 = (const float*)d_in[23];
    const float* m2b2 = (const float*)d_in[24];
    const float* m2g = (const float*)d_in[25];
    const float* m2bb = (const float*)d_in[26];
    const float* m3w1 = (const float*)d_in[27];
    const float* m3b1 = (const float*)d_in[28];
    const float* m3w2 = (const float*)d_in[29];
    const float* m3b2 = (const float*)d_in[30];
    const float* m3g = (const float*)d_in[31];
    const float* m3bb = (const float*)d_in[32];
    const float* fcw = (const float*)d_in[33];
    const float* fcb = (const float*)d_in[34];

    char* ws = (char*)d_ws;
    float* stats = (float*)(ws + OFF_STATS);
    int* sidx = (int*)(ws + OFF_SIDX);
    int* ridx = (int*)(ws + OFF_RIDX);
    int* inc = (int*)(ws + OFF_INC);
    _Float16* y23 = (_Float16*)(ws + OFF_Y23);
    float* x = (float*)(ws + OFF_X);
    float* bufB = (float*)(ws + OFF_BUFB);
    float* xn = (float*)(ws + OFF_XN);
    _Float16* apack = (_Float16*)(ws + OFF_APACK);
    _Float16* apack1 = (_Float16*)(ws + OFF_APACK1);
    float* pwt = (float*)(ws + OFF_PWT);
    float* rep1 = (float*)(ws + OFF_REP1);
    float* rep2 = (float*)(ws + OFF_REP2);
    float* repm = (float*)(ws + OFF_REPM);
    _Float16* hf16 = (_Float16*)(ws + OFF_HF16);
    _Float16* mp = (_Float16*)(ws + OFF_MP);
    float* outp = (float*)d_out;

    hipLaunchKernelGGL(k_prep, dim3(117), dim3(256), 0, stream,
                       rel_rec, rel_send, conv2_w, conv1_w, pred_w,
                       m1w1, m1w2, m2w1, m2w2, m3w1, m3w2,
                       apack, apack1, pwt, mp, rep1, rep2, repm, sidx, ridx, inc);
    hipLaunchKernelGGL(k_conv1_stats, dim3(BE), dim3(256), 0, stream,
                       inputs, apack1, conv1_b, sidx, ridx, rep1, y23);
    hipLaunchKernelGGL(k_finalize_rep, dim3(1), dim3(128), 0, stream,
                       rep1, stats, S_BN1_SC, bn1_g, bn1_b, 1.0f / (float)(BE * L1));
    hipLaunchKernelGGL(k_conv2, dim3(BE / 4), dim3(256), 0, stream,
                       y23, apack, conv2_b, stats, rep2);
    hipLaunchKernelGGL(k_finalize_rep, dim3(1), dim3(128), 0, stream,
                       rep2, stats, S_BN2_SC, bn2_g, bn2_b, 1.0f / (float)(BE * L2));
    hipLaunchKernelGGL(k_predatt, dim3(BE), dim3(256), 0, stream,
                       y23, stats, att_w, att_b, pwt, pred_b, x);
    // mlp1 (MFMA)
    hipLaunchKernelGGL((k_linmm<false, true, false>), dim3(BE / 64), dim3(256), 0, stream,
                       (const void*)x, mp + MP_M1W1, m1b1, (void*)hf16, repm);
    hipLaunchKernelGGL((k_linmm<true, false, true>), dim3(BE / 64), dim3(256), 0, stream,
                       (const void*)hf16, mp + MP_M1W2, m1b2, (void*)bufB, repm);
    hipLaunchKernelGGL(k_finalize_rep, dim3(1), dim3(128), 0, stream,
                       repm, stats, S_M1_SC, m1g, m1bb, 1.0f / (float)BE);
    // edge2node (BN-M1 inline) + mlp2 (MFMA)
    hipLaunchKernelGGL(k_e2n, dim3(BB * NN), dim3(128), 0, stream, bufB, inc, stats, xn);
    hipLaunchKernelGGL((k_linmm<false, true, false>), dim3(BB * NN / 64), dim3(256), 0, stream,
                       (const void*)xn, mp + MP_M2W1, m2b1, (void*)hf16, repm);
    hipLaunchKernelGGL((k_linmm<true, false, true>), dim3(BB * NN / 64), dim3(256), 0, stream,
                       (const void*)hf16, mp + MP_M2W2, m2b2, (void*)xn, repm);
    hipLaunchKernelGGL(k_finalize_rep, dim3(1), dim3(128), 0, stream,
                       repm, stats, S_M2_SC, m2g, m2bb, 1.0f / (float)(BB * NN));
    // node2edge + mlp3 (MFMA, gather + BN inline)
    hipLaunchKernelGGL(k_linmm3, dim3(BE / 64), dim3(256), 0, stream,
                       xn, bufB, sidx, ridx, stats, mp + MP_M3W1, m3b1, hf16);
    hipLaunchKernelGGL((k_linmm<true, false, true>), dim3(BE / 64), dim3(256), 0, stream,
                       (const void*)hf16, mp + MP_M3W2, m3b2, (void*)bufB, repm);
    hipLaunchKernelGGL(k_finalize_rep, dim3(1), dim3(128), 0, stream,
                       repm, stats, S_M3_SC, m3g, m3bb, 1.0f / (float)BE);
    // fc_out (BN-M3 inline)
    hipLaunchKernelGGL(k_fcout, dim3(BE / 16), dim3(256), 0, stream, bufB, stats, fcw, fcb, outp);
    (void)in_sizes; (void)n_in; (void)out_size; (void)ws_size;
}

// Round 10
// 633.903 us; speedup vs baseline: 30.8863x; 1.0416x over previous
//
#include <hip/hip_runtime.h>
#include <hip/hip_bf16.h>
#include <hip/hip_fp16.h>

// ---------------- problem constants ----------------
#define BB 32
#define NN 20
#define TT 100
#define DD 4
#define HH 128
#define EE 380          // N*(N-1)
#define BE 12160        // B*E
#define L1 96           // conv1 out length
#define LP 48           // after maxpool
#define L2 44           // conv2 out length
#define NOUT 16
#define EPS 1e-5f
#define NREP 64         // stats replicas (atomic de-contention)

typedef _Float16 f16x8 __attribute__((ext_vector_type(8)));
typedef _Float16 f16x4 __attribute__((ext_vector_type(4)));
typedef _Float16 f16x2 __attribute__((ext_vector_type(2)));
typedef float f32x4 __attribute__((ext_vector_type(4)));

// stats slot indices (floats): SC at base, SH at base+128
#define S_BN1_SC 256
#define S_BN2_SC 768
#define S_M1_SC 1280
#define S_M2_SC 1792
#define S_M3_SC 2304

// workspace offsets (bytes)
#define OFF_STATS 0ULL
#define OFF_SIDX 16384ULL
#define OFF_RIDX 18432ULL
#define OFF_INC 20480ULL
#define OFF_Y23 24576ULL                     // f16 [BE] slots of 6144: y2pre [48][128] then y3 [128][44]
#define OFF_X 149446656ULL                   // f32 [BE][128]
#define OFF_BUFA 155672576ULL                // f32 [BE][128]; rep1/rep2 live here during conv phase
#define OFF_BUFB 161898496ULL                // f32 [BE][128]
#define OFF_XN 168124416ULL                  // f32 [640][128]
#define OFF_T640 168452096ULL                // conv-phase: apack(160K)+apack1(16K)+pwt(64K)
#define OFF_REPM 168779776ULL                // f32 [64][256] MLP stats replicas
#define OFF_HF16 168845312ULL                // f16 [BE][128] MLP intermediates (3.1 MB)
#define OFF_MP 171958272ULL                  // f16 MLP weight packs (256 KB)
#define OFF_APACK OFF_T640
#define OFF_APACK1 (OFF_T640 + 163840ULL)
#define OFF_PWT (OFF_T640 + 180224ULL)
#define OFF_REP1 OFF_BUFA
#define OFF_REP2 (OFF_BUFA + 65536ULL)
// MP pack offsets in f16 units
#define MP_M1W1 0
#define MP_M1W2 16384
#define MP_M2W1 32768
#define MP_M2W2 49152
#define MP_M3W2 65536
#define MP_M3W1 81920

__device__ __forceinline__ float eluf(float v) { return v > 0.f ? v : expm1f(v); }

// ---------------- K prep: pack all MFMA weights, transpose pred_w, init tables ----------------
__global__ __launch_bounds__(256) void k_prep(const float* __restrict__ rel_rec,
                                              const float* __restrict__ rel_send,
                                              const float* __restrict__ w2,
                                              const float* __restrict__ w1,
                                              const float* __restrict__ pred_w,
                                              const float* __restrict__ m1w1,
                                              const float* __restrict__ m1w2,
                                              const float* __restrict__ m2w1,
                                              const float* __restrict__ m2w2,
                                              const float* __restrict__ m3w1,
                                              const float* __restrict__ m3w2,
                                              _Float16* __restrict__ apack,
                                              _Float16* __restrict__ apack1,
                                              float* __restrict__ pwt,
                                              _Float16* __restrict__ mp,
                                              float* rep1, float* rep2, float* repm,
                                              int* sidx, int* ridx, int* inc) {
    int b = blockIdx.x;
    int tid = threadIdx.x;
    int l = tid & 63;
    if (b < 40) {            // conv2_w frags
        int f = b * 4 + (tid >> 6);
        int m0 = f & 7, ks = f >> 3, s = ks & 3, k = ks >> 2;
        int m = m0 * 16 + (l & 15);
        int cbase = 32 * s + (l >> 4) * 8;
#pragma unroll
        for (int j = 0; j < 8; ++j)
            apack[(f * 64 + l) * 8 + j] = (_Float16)w2[m * 640 + (cbase + j) * 5 + k];
    } else if (b < 44) {     // conv1_w frags: K=40 padded to 64
        int f = (b - 40) * 4 + (tid >> 6);
        int m0 = f & 7, s = f >> 3;
        int m = m0 * 16 + (l & 15);
        int cbase = 32 * s + (l >> 4) * 8;
#pragma unroll
        for (int j = 0; j < 8; ++j) {
            int c = cbase + j;
            apack1[(f * 64 + l) * 8 + j] = (c < 40) ? (_Float16)w1[m * 40 + c] : (_Float16)0.f;
        }
    } else if (b == 44) {    // init: zero replicas, build edge tables
        for (int i = tid; i < NREP * 256; i += 256) { rep1[i] = 0.f; rep2[i] = 0.f; repm[i] = 0.f; }
        for (int e = tid; e < EE; e += 256) {
            int s = 0, r = 0;
            for (int n = 0; n < NN; ++n) {
                if (rel_send[e * NN + n] > 0.5f) s = n;
                if (rel_rec[e * NN + n] > 0.5f) r = n;
            }
            sidx[e] = s; ridx[e] = r;
        }
        __syncthreads();
        if (tid < NN) {
            int k = 0;
            for (int e = 0; e < EE; ++e)
                if (ridx[e] == tid) inc[tid * (NN - 1) + (k++)] = e;
        }
    } else if (b < 53) {     // transpose pred_w -> pwt[c][o]
        int idx = (b - 45) * 2048 + tid;
        for (int rep = 0; rep < 8; ++rep, idx += 256) {
            int o = idx >> 7, c = idx & 127;
            pwt[c * 128 + o] = pred_w[idx];
        }
    } else {                 // MLP weight packs: generic [128][K] -> A-frag-linear
        int idx = b - 53;    // 0..63
        const float* W; _Float16* dst; int K;
        if (idx < 8)       { W = m1w1; dst = mp + MP_M1W1; K = 128; }
        else if (idx < 16) { W = m1w2; dst = mp + MP_M1W2; K = 128; idx -= 8; }
        else if (idx < 24) { W = m2w1; dst = mp + MP_M2W1; K = 128; idx -= 16; }
        else if (idx < 32) { W = m2w2; dst = mp + MP_M2W2; K = 128; idx -= 24; }
        else if (idx < 40) { W = m3w2; dst = mp + MP_M3W2; K = 128; idx -= 32; }
        else               { W = m3w1; dst = mp + MP_M3W1; K = 384; idx -= 40; }
        int f = idx * 4 + (tid >> 6);
        int s = f >> 3, m0 = f & 7;
        int m = m0 * 16 + (l & 15);
        int cb = 32 * s + (l >> 4) * 8;
#pragma unroll
        for (int j = 0; j < 8; ++j)
            dst[(f * 64 + l) * 8 + j] = (_Float16)W[m * K + cb + j];
    }
}

// ---------------- shared helpers ----------------
__device__ __forceinline__ void load_edges(float* s_edges,
                                           const float* __restrict__ inputs,
                                           int b, int sn, int rn) {
    for (int i = threadIdx.x; i < 800; i += 256) {
        int ci = i / 100, t = i - ci * 100;
        int n = (ci < 4) ? sn : rn;
        int d = ci & 3;
        s_edges[ci * 100 + t] = inputs[((b * NN + n) * TT + t) * DD + d];
    }
}

__device__ __forceinline__ void build_x1(_Float16* s_x1, const float* s_edges) {
    for (int i = threadIdx.x; i < 96 * 64; i += 256) {
        int t = i >> 6, c = i & 63;
        float v = 0.f;
        if (c < 40) {
            int ci = (c * 205) >> 10;
            int k = c - 5 * ci;
            v = s_edges[ci * 100 + t + k];
        }
        s_x1[t * 72 + c] = (_Float16)v;
    }
}

__device__ __forceinline__ void conv1_mfma(const _Float16* __restrict__ apack1,
                                           const _Float16* s_x1,
                                           int w, int lane, int quad, int l15,
                                           f32x4 acc1[2][6]) {
#pragma unroll
    for (int m = 0; m < 2; ++m)
#pragma unroll
        for (int nt = 0; nt < 6; ++nt) acc1[m][nt] = (f32x4){0.f, 0.f, 0.f, 0.f};
    const f16x8* Ap = (const f16x8*)apack1;
#pragma unroll
    for (int s = 0; s < 2; ++s) {
        f16x8 a0 = Ap[(s * 8 + 2 * w) * 64 + lane];
        f16x8 a1 = Ap[(s * 8 + 2 * w + 1) * 64 + lane];
#pragma unroll
        for (int nt = 0; nt < 6; ++nt) {
            f16x8 bfr = *(const f16x8*)((const char*)s_x1 +
                                        (nt * 16 + l15) * 144 + 64 * s + quad * 16);
            acc1[0][nt] = __builtin_amdgcn_mfma_f32_16x16x32_f16(a0, bfr, acc1[0][nt], 0, 0, 0);
            acc1[1][nt] = __builtin_amdgcn_mfma_f32_16x16x32_f16(a1, bfr, acc1[1][nt], 0, 0, 0);
        }
    }
}

// ---------------- K1: conv1 (MFMA) + relu -> BN1 stats + PRE-BN maxpool -> y2pre ----------------
// pool-before-BN exact: bn1_g=1 -> BN scale>0 -> max commutes with fma.
__global__ __launch_bounds__(256) void k_conv1_stats(const float* __restrict__ inputs,
                                                     const _Float16* __restrict__ apack1,
                                                     const float* __restrict__ conv1_b,
                                                     const int* __restrict__ sidx,
                                                     const int* __restrict__ ridx,
                                                     float* rep1,
                                                     _Float16* __restrict__ y2p) {
    __shared__ float s_edges[800];
    __shared__ __align__(16) _Float16 s_x1[96 * 72];
    __shared__ __align__(16) _Float16 s_y2t[48 * 136];
    int be = blockIdx.x;
    int b = be / EE, e = be - b * EE;
    float* rep = rep1 + (be & (NREP - 1)) * 256;
    load_edges(s_edges, inputs, b, sidx[e], ridx[e]);
    __syncthreads();
    build_x1(s_x1, s_edges);
    __syncthreads();
    int w = threadIdx.x >> 6, lane = threadIdx.x & 63;
    int quad = lane >> 4, l15 = lane & 15;
    f32x4 acc1[2][6];
    conv1_mfma(apack1, s_x1, w, lane, quad, l15, acc1);
#pragma unroll
    for (int m = 0; m < 2; ++m) {
        int co0 = (2 * w + m) * 16 + quad * 4;
        float ss[4] = {0.f, 0.f, 0.f, 0.f}, qq[4] = {0.f, 0.f, 0.f, 0.f};
#pragma unroll
        for (int nt = 0; nt < 6; ++nt) {
            int t = nt * 16 + l15;
#pragma unroll
            for (int r = 0; r < 4; ++r) {
                float v = fmaxf(acc1[m][nt][r] + conv1_b[co0 + r], 0.f);
                ss[r] += v; qq[r] += v * v;
                float p = __shfl_xor(v, 1);
                if ((l15 & 1) == 0)
                    s_y2t[(t >> 1) * 136 + co0 + r] = (_Float16)fmaxf(v, p);
            }
        }
#pragma unroll
        for (int r = 0; r < 4; ++r) {
            float s = ss[r], q = qq[r];
            s += __shfl_xor(s, 1); s += __shfl_xor(s, 2); s += __shfl_xor(s, 4); s += __shfl_xor(s, 8);
            q += __shfl_xor(q, 1); q += __shfl_xor(q, 2); q += __shfl_xor(q, 4); q += __shfl_xor(q, 8);
            if (l15 == 0) {
                atomicAdd(&rep[co0 + r], s);
                atomicAdd(&rep[128 + co0 + r], q);
            }
        }
    }
    __syncthreads();
    _Float16* dst = y2p + (long long)be * 6144;
    for (int chunk = threadIdx.x; chunk < 768; chunk += 256) {
        int row = chunk >> 4, off = (chunk & 15) * 8;
        *(f16x8*)(dst + row * 128 + off) = *(const f16x8*)(&s_y2t[row * 136 + off]);
    }
}

// ---------------- finalize BN from 64 replicas -> scale/shift (re-zero replicas) ----------------
__global__ void k_finalize_rep(float* __restrict__ rep, float* stats, int scIdx,
                               const float* __restrict__ g, const float* __restrict__ bb,
                               float inv_count) {
    int j = threadIdx.x;
    float s = 0.f, q = 0.f;
    for (int i = 0; i < NREP; ++i) {
        s += rep[i * 256 + j];
        q += rep[i * 256 + 128 + j];
    }
    for (int i = 0; i < NREP; ++i) {
        rep[i * 256 + j] = 0.f;
        rep[i * 256 + 128 + j] = 0.f;
    }
    float m = s * inv_count;
    float v = fmaxf(q * inv_count - m * m, 0.f);
    float sc = g[j] * rsqrtf(v + EPS);
    stats[scIdx + j] = sc;
    stats[scIdx + 128 + j] = bb[j] - m * sc;
}

// ---------------- K3: 2 edges/block; y2pre+BN1 -> LDS, conv2 f16 MFMA -> y3 + BN2 stats ----------------
// Wave w: mtile group g=w&1 (mtiles 4g..4g+3), edge e=w>>1. 28.3 KB LDS -> ~5 blocks/CU.
__global__ __launch_bounds__(256) void k_conv2(_Float16* __restrict__ y23,
                                               const _Float16* __restrict__ apack,
                                               const float* __restrict__ conv2_b,
                                               const float* __restrict__ stats,
                                               float* rep2) {
    __shared__ __align__(16) _Float16 s_y2t[2][52 * 136];
    int tid = threadIdx.x;
    int be0 = blockIdx.x * 2;
    for (int i = tid; i < 544; i += 256) {
        int ed = i / 272, rem = i - ed * 272;
        ((int*)(&s_y2t[ed][48 * 136]))[rem] = 0;
    }
    {
        int c0 = (tid & 15) * 8;
        float4 sca = *(const float4*)(stats + S_BN1_SC + c0);
        float4 scb = *(const float4*)(stats + S_BN1_SC + c0 + 4);
        float4 sha = *(const float4*)(stats + S_BN1_SC + 128 + c0);
        float4 shb = *(const float4*)(stats + S_BN1_SC + 128 + c0 + 4);
        for (int i = tid; i < 1536; i += 256) {
            int ed = i / 768, rem = i - ed * 768;
            int row = rem >> 4;
            f16x8 g = *(const f16x8*)(y23 + (long long)(be0 + ed) * 6144 + row * 128 + c0);
            f16x8 o;
            o[0] = (_Float16)fmaf((float)g[0], sca.x, sha.x);
            o[1] = (_Float16)fmaf((float)g[1], sca.y, sha.y);
            o[2] = (_Float16)fmaf((float)g[2], sca.z, sha.z);
            o[3] = (_Float16)fmaf((float)g[3], sca.w, sha.w);
            o[4] = (_Float16)fmaf((float)g[4], scb.x, shb.x);
            o[5] = (_Float16)fmaf((float)g[5], scb.y, shb.y);
            o[6] = (_Float16)fmaf((float)g[6], scb.z, shb.z);
            o[7] = (_Float16)fmaf((float)g[7], scb.w, shb.w);
            *(f16x8*)(&s_y2t[ed][row * 136 + c0]) = o;
        }
    }
    __syncthreads();
    int w = tid >> 6, lane = tid & 63;
    int quad = lane >> 4, l15 = lane & 15;
    int g = w & 1, e = w >> 1;
    f32x4 acc[4][3];
#pragma unroll
    for (int m = 0; m < 4; ++m)
#pragma unroll
        for (int nt = 0; nt < 3; ++nt) acc[m][nt] = (f32x4){0.f, 0.f, 0.f, 0.f};
    const f16x8* Ap = (const f16x8*)apack;
    const char* base = (const char*)&s_y2t[e][0];
#pragma unroll
    for (int k = 0; k < 5; ++k) {
#pragma unroll
        for (int s = 0; s < 4; ++s) {
            f16x8 am[4];
#pragma unroll
            for (int m = 0; m < 4; ++m)
                am[m] = Ap[((k * 4 + s) * 8 + g * 4 + m) * 64 + lane];
#pragma unroll
            for (int nt = 0; nt < 3; ++nt) {
                f16x8 bfr = *(const f16x8*)(base + (nt * 16 + l15 + k) * 272 + 64 * s + quad * 16);
#pragma unroll
                for (int m = 0; m < 4; ++m)
                    acc[m][nt] = __builtin_amdgcn_mfma_f32_16x16x32_f16(am[m], bfr, acc[m][nt], 0, 0, 0);
            }
        }
    }
    // epilogue: bias + relu, store y3 (same slot), BN2 stats
    int be = be0 + e;
    _Float16* y3 = y23 + (long long)be * 6144;
    float* rep = rep2 + (be & (NREP - 1)) * 256;
#pragma unroll
    for (int m = 0; m < 4; ++m) {
        int co0 = (g * 4 + m) * 16 + quad * 4;
        float ssum[4] = {0.f, 0.f, 0.f, 0.f}, qsum[4] = {0.f, 0.f, 0.f, 0.f};
#pragma unroll
        for (int nt = 0; nt < 3; ++nt) {
            int t = nt * 16 + l15;
            bool valid = t < 44;
#pragma unroll
            for (int r = 0; r < 4; ++r) {
                float v = fmaxf(acc[m][nt][r] + conv2_b[co0 + r], 0.f);
                if (valid) {
                    y3[(co0 + r) * 44 + t] = (_Float16)v;
                    ssum[r] += v; qsum[r] += v * v;
                }
            }
        }
#pragma unroll
        for (int r = 0; r < 4; ++r) {
            float s = ssum[r], q = qsum[r];
            s += __shfl_xor(s, 1); s += __shfl_xor(s, 2); s += __shfl_xor(s, 4); s += __shfl_xor(s, 8);
            q += __shfl_xor(q, 1); q += __shfl_xor(q, 2); q += __shfl_xor(q, 4); q += __shfl_xor(q, 8);
            if (l15 == 0) {
                atomicAdd(&rep[co0 + r], s);
                atomicAdd(&rep[128 + co0 + r], q);
            }
        }
    }
}

// ---------------- K5: BN2 apply + attention-pool -> x [BE][128] ----------------
__global__ __launch_bounds__(256) void k_predatt(const _Float16* __restrict__ y23,
                                                 const float* __restrict__ stats,
                                                 const float* __restrict__ att_w,
                                                 const float* __restrict__ att_b,
                                                 const float* __restrict__ pwt,
                                                 const float* __restrict__ pred_b,
                                                 float* __restrict__ x) {
    __shared__ float h[128 * 45];
    __shared__ float s_att[48];
    __shared__ float s_p1[256];
    __shared__ float s_p2[256];
    __shared__ float s_sc[128], s_sh[128];
    int be = blockIdx.x, tid = threadIdx.x;
    if (tid < 128) {
        s_sc[tid] = stats[S_BN2_SC + tid];
        s_sh[tid] = stats[S_BN2_SC + 128 + tid];
    }
    __syncthreads();
    const f16x2* yp = (const f16x2*)(y23 + (long long)be * 6144);
    for (int i = tid; i < 2816; i += 256) {
        int c = i / 22, t2 = i - c * 22;
        f16x2 v = yp[i];
        float sc = s_sc[c], sh = s_sh[c];
        h[c * 45 + 2 * t2] = fmaf((float)v[0], sc, sh);
        h[c * 45 + 2 * t2 + 1] = fmaf((float)v[1], sc, sh);
    }
    __syncthreads();
    int w = tid >> 6, lane = tid & 63;
    {
        float aw0 = att_w[lane], aw1 = att_w[64 + lane];
        for (int tt = 0; tt < 11; ++tt) {
            int t = w * 11 + tt;
            float p = h[lane * 45 + t] * aw0 + h[(64 + lane) * 45 + t] * aw1;
            p += __shfl_xor(p, 1); p += __shfl_xor(p, 2); p += __shfl_xor(p, 4);
            p += __shfl_xor(p, 8); p += __shfl_xor(p, 16); p += __shfl_xor(p, 32);
            if (lane == 0) s_att[t] = p + att_b[0];
        }
    }
    __syncthreads();
    if (w == 0) {
        float v = (lane < 44) ? s_att[lane] : -1e30f;
        float m = v;
        m = fmaxf(m, __shfl_xor(m, 1)); m = fmaxf(m, __shfl_xor(m, 2));
        m = fmaxf(m, __shfl_xor(m, 4)); m = fmaxf(m, __shfl_xor(m, 8));
        m = fmaxf(m, __shfl_xor(m, 16)); m = fmaxf(m, __shfl_xor(m, 32));
        float ev = (lane < 44) ? expf(v - m) : 0.f;
        float ss = ev;
        ss += __shfl_xor(ss, 1); ss += __shfl_xor(ss, 2); ss += __shfl_xor(ss, 4);
        ss += __shfl_xor(ss, 8); ss += __shfl_xor(ss, 16); ss += __shfl_xor(ss, 32);
        if (lane < 44) s_att[lane] = ev / ss;
    }
    __syncthreads();
    {
        int c = tid & 127, hh = tid >> 7;
        float a = 0.f;
        for (int t = hh * 22; t < hh * 22 + 22; ++t) a = fmaf(h[c * 45 + t], s_att[t], a);
        s_p1[tid] = a;
    }
    __syncthreads();
    {
        int o = tid & 127, hh = tid >> 7;
        float a = 0.f;
        for (int c = hh * 64; c < hh * 64 + 64; ++c) {
            float hw = s_p1[c] + s_p1[128 + c];
            a = fmaf(pwt[c * 128 + o], hw, a);
        }
        s_p2[tid] = a;
    }
    __syncthreads();
    if (tid < 128) {
        float a = s_p2[tid] + s_p2[128 + tid] + pred_b[tid];
        x[(long long)be * 128 + tid] = a * (1.0f / 44.0f);
    }
}

// ---------------- MFMA linear (128 -> 128), 64 rows/block ----------------
// IN16: input f16 [R][128] else f32. OUT16: output f16 else f32. STATS: fused col-stats.
template <bool IN16, bool OUT16, bool STATS>
__global__ __launch_bounds__(256) void k_linmm(const void* __restrict__ inV,
                                               const _Float16* __restrict__ wp,
                                               const float* __restrict__ bias,
                                               void* __restrict__ outV,
                                               float* __restrict__ repm) {
    __shared__ __align__(16) _Float16 s_b[64 * 136];
    int tid = threadIdx.x;
    long long r0 = (long long)blockIdx.x * 64;
    if (IN16) {
        const f16x8* src = (const f16x8*)((const _Float16*)inV + r0 * 128);
        for (int i = tid; i < 1024; i += 256) {
            int row = i >> 4, c0 = (i & 15) * 8;
            *(f16x8*)(&s_b[row * 136 + c0]) = src[i];
        }
    } else {
        const float4* src = (const float4*)((const float*)inV + r0 * 128);
        for (int i = tid; i < 2048; i += 256) {
            int row = i >> 5, c0 = (i & 31) * 4;
            float4 v = src[i];
            f16x4 o = {(_Float16)v.x, (_Float16)v.y, (_Float16)v.z, (_Float16)v.w};
            *(f16x4*)(&s_b[row * 136 + c0]) = o;
        }
    }
    __syncthreads();
    int w = tid >> 6, lane = tid & 63, quad = lane >> 4, l15 = lane & 15;
    f32x4 acc[2][4];
#pragma unroll
    for (int m = 0; m < 2; ++m)
#pragma unroll
        for (int nt = 0; nt < 4; ++nt) acc[m][nt] = (f32x4){0.f, 0.f, 0.f, 0.f};
    const f16x8* Ap = (const f16x8*)wp;
#pragma unroll
    for (int s = 0; s < 4; ++s) {
        f16x8 a0 = Ap[(s * 8 + 2 * w) * 64 + lane];
        f16x8 a1 = Ap[(s * 8 + 2 * w + 1) * 64 + lane];
#pragma unroll
        for (int nt = 0; nt < 4; ++nt) {
            f16x8 bfr = *(const f16x8*)((const char*)s_b + (nt * 16 + l15) * 272 + 64 * s + quad * 16);
            acc[0][nt] = __builtin_amdgcn_mfma_f32_16x16x32_f16(a0, bfr, acc[0][nt], 0, 0, 0);
            acc[1][nt] = __builtin_amdgcn_mfma_f32_16x16x32_f16(a1, bfr, acc[1][nt], 0, 0, 0);
        }
    }
#pragma unroll
    for (int m = 0; m < 2; ++m) {
        int j0 = (2 * w + m) * 16 + quad * 4;
        float4 bs = *(const float4*)(bias + j0);
        float ss[4] = {0.f, 0.f, 0.f, 0.f}, qq[4] = {0.f, 0.f, 0.f, 0.f};
#pragma unroll
        for (int nt = 0; nt < 4; ++nt) {
            int row = nt * 16 + l15;
            float v0 = eluf(acc[m][nt][0] + bs.x);
            float v1 = eluf(acc[m][nt][1] + bs.y);
            float v2 = eluf(acc[m][nt][2] + bs.z);
            float v3 = eluf(acc[m][nt][3] + bs.w);
            if (OUT16) {
                f16x4 o = {(_Float16)v0, (_Float16)v1, (_Float16)v2, (_Float16)v3};
                *(f16x4*)((_Float16*)outV + (r0 + row) * 128 + j0) = o;
            } else {
                float4 o = {v0, v1, v2, v3};
                *(float4*)((float*)outV + (r0 + row) * 128 + j0) = o;
            }
            if (STATS) {
                ss[0] += v0; qq[0] += v0 * v0;
                ss[1] += v1; qq[1] += v1 * v1;
                ss[2] += v2; qq[2] += v2 * v2;
                ss[3] += v3; qq[3] += v3 * v3;
            }
        }
        if (STATS) {
            float* rep = repm + (blockIdx.x & (NREP - 1)) * 256;
#pragma unroll
            for (int r = 0; r < 4; ++r) {
                float s = ss[r], q = qq[r];
                s += __shfl_xor(s, 1); s += __shfl_xor(s, 2); s += __shfl_xor(s, 4); s += __shfl_xor(s, 8);
                q += __shfl_xor(q, 1); q += __shfl_xor(q, 2); q += __shfl_xor(q, 4); q += __shfl_xor(q, 8);
                if (l15 == 0) {
                    atomicAdd(&rep[j0 + r], s);
                    atomicAdd(&rep[128 + j0 + r], q);
                }
            }
        }
    }
}

// ---------------- MFMA mlp3 l1: gather-concat [send|recv|skip] (K=384) -> 128 f16 ----------------
__global__ __launch_bounds__(256) void k_linmm3(const float* __restrict__ xn,
                                                const float* __restrict__ bufB,
                                                const int* __restrict__ sidx,
                                                const int* __restrict__ ridx,
                                                const float* __restrict__ stats,
                                                const _Float16* __restrict__ wp,
                                                const float* __restrict__ bias,
                                                _Float16* __restrict__ out) {
    __shared__ __align__(16) _Float16 s_b[64 * 392];
    __shared__ float s_st[4][128];
    __shared__ int s_s[64], s_r[64];
    int tid = threadIdx.x;
    long long r0 = (long long)blockIdx.x * 64;
    if (tid < 128) {
        s_st[0][tid] = stats[S_M2_SC + tid];
        s_st[1][tid] = stats[S_M2_SC + 128 + tid];
        s_st[2][tid] = stats[S_M1_SC + tid];
        s_st[3][tid] = stats[S_M1_SC + 128 + tid];
    }
    if (tid < 64) {
        int r = (int)r0 + tid, b = r / EE, ed = r - b * EE;
        s_s[tid] = (b * NN + sidx[ed]) * 128;
        s_r[tid] = (b * NN + ridx[ed]) * 128;
    }
    __syncthreads();
    for (int i = tid; i < 8192; i += 256) {
        int row = i >> 7, j = i & 127;
        float sc2 = s_st[0][j], sh2 = s_st[1][j];
        s_b[row * 392 + j] = (_Float16)fmaf(xn[s_s[row] + j], sc2, sh2);
        s_b[row * 392 + 128 + j] = (_Float16)fmaf(xn[s_r[row] + j], sc2, sh2);
        s_b[row * 392 + 256 + j] = (_Float16)fmaf(bufB[(r0 + row) * 128 + j], s_st[2][j], s_st[3][j]);
    }
    __syncthreads();
    int w = tid >> 6, lane = tid & 63, quad = lane >> 4, l15 = lane & 15;
    f32x4 acc[2][4];
#pragma unroll
    for (int m = 0; m < 2; ++m)
#pragma unroll
        for (int nt = 0; nt < 4; ++nt) acc[m][nt] = (f32x4){0.f, 0.f, 0.f, 0.f};
    const f16x8* Ap = (const f16x8*)wp;
#pragma unroll
    for (int s = 0; s < 12; ++s) {
        f16x8 a0 = Ap[(s * 8 + 2 * w) * 64 + lane];
        f16x8 a1 = Ap[(s * 8 + 2 * w + 1) * 64 + lane];
#pragma unroll
        for (int nt = 0; nt < 4; ++nt) {
            f16x8 bfr = *(const f16x8*)((const char*)s_b + (nt * 16 + l15) * 784 + 64 * s + quad * 16);
            acc[0][nt] = __builtin_amdgcn_mfma_f32_16x16x32_f16(a0, bfr, acc[0][nt], 0, 0, 0);
            acc[1][nt] = __builtin_amdgcn_mfma_f32_16x16x32_f16(a1, bfr, acc[1][nt], 0, 0, 0);
        }
    }
#pragma unroll
    for (int m = 0; m < 2; ++m) {
        int j0 = (2 * w + m) * 16 + quad * 4;
        float4 bs = *(const float4*)(bias + j0);
#pragma unroll
        for (int nt = 0; nt < 4; ++nt) {
            int row = nt * 16 + l15;
            f16x4 o = {(_Float16)eluf(acc[m][nt][0] + bs.x),
                       (_Float16)eluf(acc[m][nt][1] + bs.y),
                       (_Float16)eluf(acc[m][nt][2] + bs.z),
                       (_Float16)eluf(acc[m][nt][3] + bs.w)};
            *(f16x4*)(out + (r0 + row) * 128 + j0) = o;
        }
    }
}

// ---------------- edge2node scatter-mean with inline BN-M1 ----------------
__global__ __launch_bounds__(128) void k_e2n(const float* __restrict__ bufB,
                                             const int* __restrict__ inc,
                                             const float* __restrict__ stats,
                                             float* __restrict__ xn) {
    int bn = blockIdx.x;
    int b = bn / NN, n = bn - b * NN;
    int j = threadIdx.x;
    float sc = stats[S_M1_SC + j], sh = stats[S_M1_SC + 128 + j];
    float s = 0.f;
    for (int k = 0; k < NN - 1; ++k) {
        int e = inc[n * (NN - 1) + k];
        s += bufB[(long long)(b * EE + e) * 128 + j];
    }
    xn[bn * 128 + j] = (s * sc + (float)(NN - 1) * sh) * (1.0f / (float)NN);
}

// ---------------- BN3 apply + fc_out (128 -> 16) ----------------
__global__ __launch_bounds__(256) void k_fcout(const float* __restrict__ h2,
                                               const float* __restrict__ stats,
                                               const float* __restrict__ fcw,
                                               const float* __restrict__ fcb,
                                               float* __restrict__ out) {
    __shared__ float s_x[16 * 129];
    __shared__ float s_w[16 * 129];
    int r0 = blockIdx.x * 16;
    int tid = threadIdx.x;
    for (int i = tid; i < 16 * 128; i += 256) {
        int rr = i >> 7, j = i & 127;
        s_x[rr * 129 + j] = fmaf(h2[(long long)(r0 + rr) * 128 + j],
                                 stats[S_M3_SC + j], stats[S_M3_SC + 128 + j]);
    }
    for (int i = tid; i < 16 * 128; i += 256) {
        int o = i >> 7, j = i & 127;
        s_w[o * 129 + j] = fcw[i];
    }
    __syncthreads();
    int rl = tid >> 4, o = tid & 15;
    float a = fcb[o];
    for (int j = 0; j < 128; ++j) a = fmaf(s_x[rl * 129 + j], s_w[o * 129 + j], a);
    out[(long long)(r0 + rl) * 16 + o] = a;
}

// ---------------- host launcher ----------------
extern "C" void kernel_launch(void* const* d_in, const int* in_sizes, int n_in,
                              void* d_out, int out_size, void* d_ws, size_t ws_size,
                              hipStream_t stream) {
    const float* inputs = (const float*)d_in[0];
    const float* rel_rec = (const float*)d_in[1];
    const float* rel_send = (const float*)d_in[2];
    const float* conv1_w = (const float*)d_in[3];
    const float* conv1_b = (const float*)d_in[4];
    const float* bn1_g = (const float*)d_in[5];
    const float* bn1_b = (const float*)d_in[6];
    const float* conv2_w = (const float*)d_in[7];
    const float* conv2_b = (const float*)d_in[8];
    const float* bn2_g = (const float*)d_in[9];
    const float* bn2_b = (const float*)d_in[10];
    const float* pred_w = (const float*)d_in[11];
    const float* pred_b = (const float*)d_in[12];
    const float* att_w = (const float*)d_in[13];
    const float* att_b = (const float*)d_in[14];
    const float* m1w1 = (const float*)d_in[15];
    const float* m1b1 = (const float*)d_in[16];
    const float* m1w2 = (const float*)d_in[17];
    const float* m1b2 = (const float*)d_in[18];
    const float* m1g = (const float*)d_in[19];
    const float* m1bb = (const float*)d_in[20];
    const float* m2w1 = (const float*)d_in[21];
    const float* m2b1 = (const float*)d_in[22];
    const float* m2w2 = (const float*)d_in[23];
    const float* m2b2 = (const float*)d_in[24];
    const float* m2g = (const float*)d_in[25];
    const float* m2bb = (const float*)d_in[26];
    const float* m3w1 = (const float*)d_in[27];
    const float* m3b1 = (const float*)d_in[28];
    const float* m3w2 = (const float*)d_in[29];
    const float* m3b2 = (const float*)d_in[30];
    const float* m3g = (const float*)d_in[31];
    const float* m3bb = (const float*)d_in[32];
    const float* fcw = (const float*)d_in[33];
    const float* fcb = (const float*)d_in[34];

    char* ws = (char*)d_ws;
    float* stats = (float*)(ws + OFF_STATS);
    int* sidx = (int*)(ws + OFF_SIDX);
    int* ridx = (int*)(ws + OFF_RIDX);
    int* inc = (int*)(ws + OFF_INC);
    _Float16* y23 = (_Float16*)(ws + OFF_Y23);
    float* x = (float*)(ws + OFF_X);
    float* bufB = (float*)(ws + OFF_BUFB);
    float* xn = (float*)(ws + OFF_XN);
    _Float16* apack = (_Float16*)(ws + OFF_APACK);
    _Float16* apack1 = (_Float16*)(ws + OFF_APACK1);
    float* pwt = (float*)(ws + OFF_PWT);
    float* rep1 = (float*)(ws + OFF_REP1);
    float* rep2 = (float*)(ws + OFF_REP2);
    float* repm = (float*)(ws + OFF_REPM);
    _Float16* hf16 = (_Float16*)(ws + OFF_HF16);
    _Float16* mp = (_Float16*)(ws + OFF_MP);
    float* outp = (float*)d_out;

    hipLaunchKernelGGL(k_prep, dim3(117), dim3(256), 0, stream,
                       rel_rec, rel_send, conv2_w, conv1_w, pred_w,
                       m1w1, m1w2, m2w1, m2w2, m3w1, m3w2,
                       apack, apack1, pwt, mp, rep1, rep2, repm, sidx, ridx, inc);
    hipLaunchKernelGGL(k_conv1_stats, dim3(BE), dim3(256), 0, stream,
                       inputs, apack1, conv1_b, sidx, ridx, rep1, y23);
    hipLaunchKernelGGL(k_finalize_rep, dim3(1), dim3(128), 0, stream,
                       rep1, stats, S_BN1_SC, bn1_g, bn1_b, 1.0f / (float)(BE * L1));
    hipLaunchKernelGGL(k_conv2, dim3(BE / 2), dim3(256), 0, stream,
                       y23, apack, conv2_b, stats, rep2);
    hipLaunchKernelGGL(k_finalize_rep, dim3(1), dim3(128), 0, stream,
                       rep2, stats, S_BN2_SC, bn2_g, bn2_b, 1.0f / (float)(BE * L2));
    hipLaunchKernelGGL(k_predatt, dim3(BE), dim3(256), 0, stream,
                       y23, stats, att_w, att_b, pwt, pred_b, x);
    // mlp1 (MFMA)
    hipLaunchKernelGGL((k_linmm<false, true, false>), dim3(BE / 64), dim3(256), 0, stream,
                       (const void*)x, mp + MP_M1W1, m1b1, (void*)hf16, repm);
    hipLaunchKernelGGL((k_linmm<true, false, true>), dim3(BE / 64), dim3(256), 0, stream,
                       (const void*)hf16, mp + MP_M1W2, m1b2, (void*)bufB, repm);
    hipLaunchKernelGGL(k_finalize_rep, dim3(1), dim3(128), 0, stream,
                       repm, stats, S_M1_SC, m1g, m1bb, 1.0f / (float)BE);
    // edge2node (BN-M1 inline) + mlp2 (MFMA)
    hipLaunchKernelGGL(k_e2n, dim3(BB * NN), dim3(128), 0, stream, bufB, inc, stats, xn);
    hipLaunchKernelGGL((k_linmm<false, true, false>), dim3(BB * NN / 64), dim3(256), 0, stream,
                       (const void*)xn, mp + MP_M2W1, m2b1, (void*)hf16, repm);
    hipLaunchKernelGGL((k_linmm<true, false, true>), dim3(BB * NN / 64), dim3(256), 0, stream,
                       (const void*)hf16, mp + MP_M2W2, m2b2, (void*)xn, repm);
    hipLaunchKernelGGL(k_finalize_rep, dim3(1), dim3(128), 0, stream,
                       repm, stats, S_M2_SC, m2g, m2bb, 1.0f / (float)(BB * NN));
    // node2edge + mlp3 (MFMA, gather + BN inline)
    hipLaunchKernelGGL(k_linmm3, dim3(BE / 64), dim3(256), 0, stream,
                       xn, bufB, sidx, ridx, stats, mp + MP_M3W1, m3b1, hf16);
    hipLaunchKernelGGL((k_linmm<true, false, true>), dim3(BE / 64), dim3(256), 0, stream,
                       (const void*)hf16, mp + MP_M3W2, m3b2, (void*)bufB, repm);
    hipLaunchKernelGGL(k_finalize_rep, dim3(1), dim3(128), 0, stream,
                       repm, stats, S_M3_SC, m3g, m3bb, 1.0f / (float)BE);
    // fc_out (BN-M3 inline)
    hipLaunchKernelGGL(k_fcout, dim3(BE / 16), dim3(256), 0, stream, bufB, stats, fcw, fcb, outp);
    (void)in_sizes; (void)n_in; (void)out_size; (void)ws_size;
}

// Round 11
// 597.063 us; speedup vs baseline: 32.7921x; 1.0617x over previous
//
#include <hip/hip_runtime.h>
#include <hip/hip_bf16.h>
#include <hip/hip_fp16.h>

// ---------------- problem constants ----------------
#define BB 32
#define NN 20
#define TT 100
#define DD 4
#define HH 128
#define EE 380          // N*(N-1)
#define BE 12160        // B*E
#define L1 96           // conv1 out length
#define LP 48           // after maxpool
#define L2 44           // conv2 out length
#define NOUT 16
#define EPS 1e-5f
#define NREP 64         // stats replicas (atomic de-contention)

typedef _Float16 f16x8 __attribute__((ext_vector_type(8)));
typedef _Float16 f16x4 __attribute__((ext_vector_type(4)));
typedef _Float16 f16x2 __attribute__((ext_vector_type(2)));
typedef float f32x4 __attribute__((ext_vector_type(4)));

// stats slot indices (floats): SC at base, SH at base+128
#define S_BN1_SC 256
#define S_BN2_SC 768
#define S_M1_SC 1280
#define S_M2_SC 1792
#define S_M3_SC 2304

// workspace offsets (bytes)
#define OFF_STATS 0ULL
#define OFF_SIDX 16384ULL
#define OFF_RIDX 18432ULL
#define OFF_INC 20480ULL
#define OFF_Y23 24576ULL                     // f16 [BE] slots of 6144: y2pre [48][128] then y3 [128][44]
#define OFF_X 149446656ULL                   // f32 [BE][128]
#define OFF_BUFA 155672576ULL                // f32 [BE][128]; rep1/rep2 live here during conv phase
#define OFF_BUFB 161898496ULL                // f32 [BE][128]
#define OFF_XN 168124416ULL                  // f32 [640][128]
#define OFF_T640 168452096ULL                // conv-phase: apack(160K)+apack1(16K)+pwt(64K)
#define OFF_REPM 168779776ULL                // f32 [64][256] MLP stats replicas
#define OFF_HF16 168845312ULL                // f16 [BE][128] MLP intermediates (3.1 MB)
#define OFF_MP 171958272ULL                  // f16 MLP weight packs (256 KB)
#define OFF_APACK OFF_T640
#define OFF_APACK1 (OFF_T640 + 163840ULL)
#define OFF_PWT (OFF_T640 + 180224ULL)
#define OFF_REP1 OFF_BUFA
#define OFF_REP2 (OFF_BUFA + 65536ULL)
// MP pack offsets in f16 units
#define MP_M1W1 0
#define MP_M1W2 16384
#define MP_M2W1 32768
#define MP_M2W2 49152
#define MP_M3W2 65536
#define MP_M3W1 81920

__device__ __forceinline__ float eluf(float v) { return v > 0.f ? v : expm1f(v); }

// ---------------- K prep: pack all MFMA weights, transpose pred_w, init tables ----------------
// conv1 A-pack uses K-order c' = k*8 + ci (k=tap 0..7 padded, ci=channel 0..7) so that
// conv1 B-frags read DIRECTLY from a time-major f16 edge buffer (no im2col).
__global__ __launch_bounds__(256) void k_prep(const float* __restrict__ rel_rec,
                                              const float* __restrict__ rel_send,
                                              const float* __restrict__ w2,
                                              const float* __restrict__ w1,
                                              const float* __restrict__ pred_w,
                                              const float* __restrict__ m1w1,
                                              const float* __restrict__ m1w2,
                                              const float* __restrict__ m2w1,
                                              const float* __restrict__ m2w2,
                                              const float* __restrict__ m3w1,
                                              const float* __restrict__ m3w2,
                                              _Float16* __restrict__ apack,
                                              _Float16* __restrict__ apack1,
                                              float* __restrict__ pwt,
                                              _Float16* __restrict__ mp,
                                              float* rep1, float* rep2, float* repm,
                                              int* sidx, int* ridx, int* inc) {
    int b = blockIdx.x;
    int tid = threadIdx.x;
    int l = tid & 63;
    if (b < 40) {            // conv2_w frags
        int f = b * 4 + (tid >> 6);
        int m0 = f & 7, ks = f >> 3, s = ks & 3, k = ks >> 2;
        int m = m0 * 16 + (l & 15);
        int cbase = 32 * s + (l >> 4) * 8;
#pragma unroll
        for (int j = 0; j < 8; ++j)
            apack[(f * 64 + l) * 8 + j] = (_Float16)w2[m * 640 + (cbase + j) * 5 + k];
    } else if (b < 44) {     // conv1_w frags: c' = k*8+ci, taps k>=5 zero-padded
        int f = (b - 40) * 4 + (tid >> 6);
        int m0 = f & 7, s = f >> 3;
        int m = m0 * 16 + (l & 15);
        int cbase = 32 * s + (l >> 4) * 8;
#pragma unroll
        for (int j = 0; j < 8; ++j) {
            int c = cbase + j;
            int k = c >> 3, ci = c & 7;
            apack1[(f * 64 + l) * 8 + j] = (k < 5) ? (_Float16)w1[m * 40 + ci * 5 + k]
                                                   : (_Float16)0.f;
        }
    } else if (b == 44) {    // init: zero replicas, build edge tables
        for (int i = tid; i < NREP * 256; i += 256) { rep1[i] = 0.f; rep2[i] = 0.f; repm[i] = 0.f; }
        for (int e = tid; e < EE; e += 256) {
            int s = 0, r = 0;
            for (int n = 0; n < NN; ++n) {
                if (rel_send[e * NN + n] > 0.5f) s = n;
                if (rel_rec[e * NN + n] > 0.5f) r = n;
            }
            sidx[e] = s; ridx[e] = r;
        }
        __syncthreads();
        if (tid < NN) {
            int k = 0;
            for (int e = 0; e < EE; ++e)
                if (ridx[e] == tid) inc[tid * (NN - 1) + (k++)] = e;
        }
    } else if (b < 53) {     // transpose pred_w -> pwt[c][o]
        int idx = (b - 45) * 2048 + tid;
        for (int rep = 0; rep < 8; ++rep, idx += 256) {
            int o = idx >> 7, c = idx & 127;
            pwt[c * 128 + o] = pred_w[idx];
        }
    } else {                 // MLP weight packs: generic [128][K] -> A-frag-linear
        int idx = b - 53;    // 0..63
        const float* W; _Float16* dst; int K;
        if (idx < 8)       { W = m1w1; dst = mp + MP_M1W1; K = 128; }
        else if (idx < 16) { W = m1w2; dst = mp + MP_M1W2; K = 128; idx -= 8; }
        else if (idx < 24) { W = m2w1; dst = mp + MP_M2W1; K = 128; idx -= 16; }
        else if (idx < 32) { W = m2w2; dst = mp + MP_M2W2; K = 128; idx -= 24; }
        else if (idx < 40) { W = m3w2; dst = mp + MP_M3W2; K = 128; idx -= 32; }
        else               { W = m3w1; dst = mp + MP_M3W1; K = 384; idx -= 40; }
        int f = idx * 4 + (tid >> 6);
        int s = f >> 3, m0 = f & 7;
        int m = m0 * 16 + (l & 15);
        int cb = 32 * s + (l >> 4) * 8;
#pragma unroll
        for (int j = 0; j < 8; ++j)
            dst[(f * 64 + l) * 8 + j] = (_Float16)W[m * K + cb + j];
    }
}

// ---------------- K1: conv1 (MFMA, direct-from-LDS B) + relu -> BN1 stats + PRE-BN maxpool ----------------
// s_edgesT[t][ci] f16, rows 100..103 zeroed (read by padded taps; A=0 there).
// B-frag for (nt, kslice s): row (nt*16 + l15 + 4s + quad), 8 channels = one f16x8.
// pool-before-BN exact: bn1_g=1 -> BN scale>0 -> max commutes with fma.
__global__ __launch_bounds__(256) void k_conv1_stats(const float* __restrict__ inputs,
                                                     const _Float16* __restrict__ apack1,
                                                     const float* __restrict__ conv1_b,
                                                     const int* __restrict__ sidx,
                                                     const int* __restrict__ ridx,
                                                     float* rep1,
                                                     _Float16* __restrict__ y2p) {
    __shared__ __align__(16) _Float16 s_edgesT[104 * 8];
    __shared__ __align__(16) _Float16 s_y2t[48 * 136];
    int be = blockIdx.x;
    int b = be / EE, e = be - b * EE;
    int sn = sidx[e], rn = ridx[e];
    float* rep = rep1 + (be & (NREP - 1)) * 256;
    // stage: float4 per (node,t) -> f16x4 into time-major s_edgesT
    for (int i = threadIdx.x; i < 200; i += 256) {
        int side = (i >= 100) ? 1 : 0;
        int t = i - side * 100;
        int n = side ? rn : sn;
        float4 v = *(const float4*)(inputs + ((long long)(b * NN + n) * TT + t) * DD);
        f16x4 o = {(_Float16)v.x, (_Float16)v.y, (_Float16)v.z, (_Float16)v.w};
        *(f16x4*)(&s_edgesT[t * 8 + side * 4]) = o;
    }
    if (threadIdx.x < 32) s_edgesT[800 + threadIdx.x] = (_Float16)0.f;  // zero rows 100..103
    __syncthreads();
    int w = threadIdx.x >> 6, lane = threadIdx.x & 63;
    int quad = lane >> 4, l15 = lane & 15;
    f32x4 acc1[2][6];
#pragma unroll
    for (int m = 0; m < 2; ++m)
#pragma unroll
        for (int nt = 0; nt < 6; ++nt) acc1[m][nt] = (f32x4){0.f, 0.f, 0.f, 0.f};
    {
        const f16x8* Ap = (const f16x8*)apack1;
#pragma unroll
        for (int s = 0; s < 2; ++s) {
            f16x8 a0 = Ap[(s * 8 + 2 * w) * 64 + lane];
            f16x8 a1 = Ap[(s * 8 + 2 * w + 1) * 64 + lane];
#pragma unroll
            for (int nt = 0; nt < 6; ++nt) {
                f16x8 bfr = *(const f16x8*)(&s_edgesT[(nt * 16 + l15 + 4 * s + quad) * 8]);
                acc1[0][nt] = __builtin_amdgcn_mfma_f32_16x16x32_f16(a0, bfr, acc1[0][nt], 0, 0, 0);
                acc1[1][nt] = __builtin_amdgcn_mfma_f32_16x16x32_f16(a1, bfr, acc1[1][nt], 0, 0, 0);
            }
        }
    }
#pragma unroll
    for (int m = 0; m < 2; ++m) {
        int co0 = (2 * w + m) * 16 + quad * 4;
        float ss[4] = {0.f, 0.f, 0.f, 0.f}, qq[4] = {0.f, 0.f, 0.f, 0.f};
#pragma unroll
        for (int nt = 0; nt < 6; ++nt) {
            int t = nt * 16 + l15;
#pragma unroll
            for (int r = 0; r < 4; ++r) {
                float v = fmaxf(acc1[m][nt][r] + conv1_b[co0 + r], 0.f);
                ss[r] += v; qq[r] += v * v;
                float p = __shfl_xor(v, 1);
                if ((l15 & 1) == 0)
                    s_y2t[(t >> 1) * 136 + co0 + r] = (_Float16)fmaxf(v, p);
            }
        }
#pragma unroll
        for (int r = 0; r < 4; ++r) {
            float s = ss[r], q = qq[r];
            s += __shfl_xor(s, 1); s += __shfl_xor(s, 2); s += __shfl_xor(s, 4); s += __shfl_xor(s, 8);
            q += __shfl_xor(q, 1); q += __shfl_xor(q, 2); q += __shfl_xor(q, 4); q += __shfl_xor(q, 8);
            if (l15 == 0) {
                atomicAdd(&rep[co0 + r], s);
                atomicAdd(&rep[128 + co0 + r], q);
            }
        }
    }
    __syncthreads();
    _Float16* dst = y2p + (long long)be * 6144;
    for (int chunk = threadIdx.x; chunk < 768; chunk += 256) {
        int row = chunk >> 4, off = (chunk & 15) * 8;
        *(f16x8*)(dst + row * 128 + off) = *(const f16x8*)(&s_y2t[row * 136 + off]);
    }
}

// ---------------- finalize BN from 64 replicas -> scale/shift (re-zero replicas) ----------------
__global__ void k_finalize_rep(float* __restrict__ rep, float* stats, int scIdx,
                               const float* __restrict__ g, const float* __restrict__ bb,
                               float inv_count) {
    int j = threadIdx.x;
    float s = 0.f, q = 0.f;
    for (int i = 0; i < NREP; ++i) {
        s += rep[i * 256 + j];
        q += rep[i * 256 + 128 + j];
    }
    for (int i = 0; i < NREP; ++i) {
        rep[i * 256 + j] = 0.f;
        rep[i * 256 + 128 + j] = 0.f;
    }
    float m = s * inv_count;
    float v = fmaxf(q * inv_count - m * m, 0.f);
    float sc = g[j] * rsqrtf(v + EPS);
    stats[scIdx + j] = sc;
    stats[scIdx + 128 + j] = bb[j] - m * sc;
}

// ---------------- K3: 2 edges/block; y2pre+BN1 -> LDS, conv2 f16 MFMA -> y3 + BN2 stats ----------------
__global__ __launch_bounds__(256) void k_conv2(_Float16* __restrict__ y23,
                                               const _Float16* __restrict__ apack,
                                               const float* __restrict__ conv2_b,
                                               const float* __restrict__ stats,
                                               float* rep2) {
    __shared__ __align__(16) _Float16 s_y2t[2][52 * 136];
    int tid = threadIdx.x;
    int be0 = blockIdx.x * 2;
    for (int i = tid; i < 544; i += 256) {
        int ed = i / 272, rem = i - ed * 272;
        ((int*)(&s_y2t[ed][48 * 136]))[rem] = 0;
    }
    {
        int c0 = (tid & 15) * 8;
        float4 sca = *(const float4*)(stats + S_BN1_SC + c0);
        float4 scb = *(const float4*)(stats + S_BN1_SC + c0 + 4);
        float4 sha = *(const float4*)(stats + S_BN1_SC + 128 + c0);
        float4 shb = *(const float4*)(stats + S_BN1_SC + 128 + c0 + 4);
        for (int i = tid; i < 1536; i += 256) {
            int ed = i / 768, rem = i - ed * 768;
            int row = rem >> 4;
            f16x8 g = *(const f16x8*)(y23 + (long long)(be0 + ed) * 6144 + row * 128 + c0);
            f16x8 o;
            o[0] = (_Float16)fmaf((float)g[0], sca.x, sha.x);
            o[1] = (_Float16)fmaf((float)g[1], sca.y, sha.y);
            o[2] = (_Float16)fmaf((float)g[2], sca.z, sha.z);
            o[3] = (_Float16)fmaf((float)g[3], sca.w, sha.w);
            o[4] = (_Float16)fmaf((float)g[4], scb.x, shb.x);
            o[5] = (_Float16)fmaf((float)g[5], scb.y, shb.y);
            o[6] = (_Float16)fmaf((float)g[6], scb.z, shb.z);
            o[7] = (_Float16)fmaf((float)g[7], scb.w, shb.w);
            *(f16x8*)(&s_y2t[ed][row * 136 + c0]) = o;
        }
    }
    __syncthreads();
    int w = tid >> 6, lane = tid & 63;
    int quad = lane >> 4, l15 = lane & 15;
    int g = w & 1, e = w >> 1;
    f32x4 acc[4][3];
#pragma unroll
    for (int m = 0; m < 4; ++m)
#pragma unroll
        for (int nt = 0; nt < 3; ++nt) acc[m][nt] = (f32x4){0.f, 0.f, 0.f, 0.f};
    const f16x8* Ap = (const f16x8*)apack;
    const char* base = (const char*)&s_y2t[e][0];
#pragma unroll
    for (int k = 0; k < 5; ++k) {
#pragma unroll
        for (int s = 0; s < 4; ++s) {
            f16x8 am[4];
#pragma unroll
            for (int m = 0; m < 4; ++m)
                am[m] = Ap[((k * 4 + s) * 8 + g * 4 + m) * 64 + lane];
#pragma unroll
            for (int nt = 0; nt < 3; ++nt) {
                f16x8 bfr = *(const f16x8*)(base + (nt * 16 + l15 + k) * 272 + 64 * s + quad * 16);
#pragma unroll
                for (int m = 0; m < 4; ++m)
                    acc[m][nt] = __builtin_amdgcn_mfma_f32_16x16x32_f16(am[m], bfr, acc[m][nt], 0, 0, 0);
            }
        }
    }
    int be = be0 + e;
    _Float16* y3 = y23 + (long long)be * 6144;
    float* rep = rep2 + (be & (NREP - 1)) * 256;
#pragma unroll
    for (int m = 0; m < 4; ++m) {
        int co0 = (g * 4 + m) * 16 + quad * 4;
        float ssum[4] = {0.f, 0.f, 0.f, 0.f}, qsum[4] = {0.f, 0.f, 0.f, 0.f};
#pragma unroll
        for (int nt = 0; nt < 3; ++nt) {
            int t = nt * 16 + l15;
            bool valid = t < 44;
#pragma unroll
            for (int r = 0; r < 4; ++r) {
                float v = fmaxf(acc[m][nt][r] + conv2_b[co0 + r], 0.f);
                if (valid) {
                    y3[(co0 + r) * 44 + t] = (_Float16)v;
                    ssum[r] += v; qsum[r] += v * v;
                }
            }
        }
#pragma unroll
        for (int r = 0; r < 4; ++r) {
            float s = ssum[r], q = qsum[r];
            s += __shfl_xor(s, 1); s += __shfl_xor(s, 2); s += __shfl_xor(s, 4); s += __shfl_xor(s, 8);
            q += __shfl_xor(q, 1); q += __shfl_xor(q, 2); q += __shfl_xor(q, 4); q += __shfl_xor(q, 8);
            if (l15 == 0) {
                atomicAdd(&rep[co0 + r], s);
                atomicAdd(&rep[128 + co0 + r], q);
            }
        }
    }
}

// ---------------- K5: BN2 apply + attention-pool -> x [BE][128] ----------------
__global__ __launch_bounds__(256) void k_predatt(const _Float16* __restrict__ y23,
                                                 const float* __restrict__ stats,
                                                 const float* __restrict__ att_w,
                                                 const float* __restrict__ att_b,
                                                 const float* __restrict__ pwt,
                                                 const float* __restrict__ pred_b,
                                                 float* __restrict__ x) {
    __shared__ float h[128 * 45];
    __shared__ float s_att[48];
    __shared__ float s_p1[256];
    __shared__ float s_p2[256];
    __shared__ float s_sc[128], s_sh[128];
    int be = blockIdx.x, tid = threadIdx.x;
    if (tid < 128) {
        s_sc[tid] = stats[S_BN2_SC + tid];
        s_sh[tid] = stats[S_BN2_SC + 128 + tid];
    }
    __syncthreads();
    const f16x2* yp = (const f16x2*)(y23 + (long long)be * 6144);
    for (int i = tid; i < 2816; i += 256) {
        int c = i / 22, t2 = i - c * 22;
        f16x2 v = yp[i];
        float sc = s_sc[c], sh = s_sh[c];
        h[c * 45 + 2 * t2] = fmaf((float)v[0], sc, sh);
        h[c * 45 + 2 * t2 + 1] = fmaf((float)v[1], sc, sh);
    }
    __syncthreads();
    int w = tid >> 6, lane = tid & 63;
    {
        float aw0 = att_w[lane], aw1 = att_w[64 + lane];
        for (int tt = 0; tt < 11; ++tt) {
            int t = w * 11 + tt;
            float p = h[lane * 45 + t] * aw0 + h[(64 + lane) * 45 + t] * aw1;
            p += __shfl_xor(p, 1); p += __shfl_xor(p, 2); p += __shfl_xor(p, 4);
            p += __shfl_xor(p, 8); p += __shfl_xor(p, 16); p += __shfl_xor(p, 32);
            if (lane == 0) s_att[t] = p + att_b[0];
        }
    }
    __syncthreads();
    if (w == 0) {
        float v = (lane < 44) ? s_att[lane] : -1e30f;
        float m = v;
        m = fmaxf(m, __shfl_xor(m, 1)); m = fmaxf(m, __shfl_xor(m, 2));
        m = fmaxf(m, __shfl_xor(m, 4)); m = fmaxf(m, __shfl_xor(m, 8));
        m = fmaxf(m, __shfl_xor(m, 16)); m = fmaxf(m, __shfl_xor(m, 32));
        float ev = (lane < 44) ? expf(v - m) : 0.f;
        float ss = ev;
        ss += __shfl_xor(ss, 1); ss += __shfl_xor(ss, 2); ss += __shfl_xor(ss, 4);
        ss += __shfl_xor(ss, 8); ss += __shfl_xor(ss, 16); ss += __shfl_xor(ss, 32);
        if (lane < 44) s_att[lane] = ev / ss;
    }
    __syncthreads();
    {
        int c = tid & 127, hh = tid >> 7;
        float a = 0.f;
        for (int t = hh * 22; t < hh * 22 + 22; ++t) a = fmaf(h[c * 45 + t], s_att[t], a);
        s_p1[tid] = a;
    }
    __syncthreads();
    {
        int o = tid & 127, hh = tid >> 7;
        float a = 0.f;
        for (int c = hh * 64; c < hh * 64 + 64; ++c) {
            float hw = s_p1[c] + s_p1[128 + c];
            a = fmaf(pwt[c * 128 + o], hw, a);
        }
        s_p2[tid] = a;
    }
    __syncthreads();
    if (tid < 128) {
        float a = s_p2[tid] + s_p2[128 + tid] + pred_b[tid];
        x[(long long)be * 128 + tid] = a * (1.0f / 44.0f);
    }
}

// ---------------- MFMA linear (128 -> 128), 64 rows/block ----------------
template <bool IN16, bool OUT16, bool STATS>
__global__ __launch_bounds__(256) void k_linmm(const void* __restrict__ inV,
                                               const _Float16* __restrict__ wp,
                                               const float* __restrict__ bias,
                                               void* __restrict__ outV,
                                               float* __restrict__ repm) {
    __shared__ __align__(16) _Float16 s_b[64 * 136];
    int tid = threadIdx.x;
    long long r0 = (long long)blockIdx.x * 64;
    if (IN16) {
        const f16x8* src = (const f16x8*)((const _Float16*)inV + r0 * 128);
        for (int i = tid; i < 1024; i += 256) {
            int row = i >> 4, c0 = (i & 15) * 8;
            *(f16x8*)(&s_b[row * 136 + c0]) = src[i];
        }
    } else {
        const float4* src = (const float4*)((const float*)inV + r0 * 128);
        for (int i = tid; i < 2048; i += 256) {
            int row = i >> 5, c0 = (i & 31) * 4;
            float4 v = src[i];
            f16x4 o = {(_Float16)v.x, (_Float16)v.y, (_Float16)v.z, (_Float16)v.w};
            *(f16x4*)(&s_b[row * 136 + c0]) = o;
        }
    }
    __syncthreads();
    int w = tid >> 6, lane = tid & 63, quad = lane >> 4, l15 = lane & 15;
    f32x4 acc[2][4];
#pragma unroll
    for (int m = 0; m < 2; ++m)
#pragma unroll
        for (int nt = 0; nt < 4; ++nt) acc[m][nt] = (f32x4){0.f, 0.f, 0.f, 0.f};
    const f16x8* Ap = (const f16x8*)wp;
#pragma unroll
    for (int s = 0; s < 4; ++s) {
        f16x8 a0 = Ap[(s * 8 + 2 * w) * 64 + lane];
        f16x8 a1 = Ap[(s * 8 + 2 * w + 1) * 64 + lane];
#pragma unroll
        for (int nt = 0; nt < 4; ++nt) {
            f16x8 bfr = *(const f16x8*)((const char*)s_b + (nt * 16 + l15) * 272 + 64 * s + quad * 16);
            acc[0][nt] = __builtin_amdgcn_mfma_f32_16x16x32_f16(a0, bfr, acc[0][nt], 0, 0, 0);
            acc[1][nt] = __builtin_amdgcn_mfma_f32_16x16x32_f16(a1, bfr, acc[1][nt], 0, 0, 0);
        }
    }
#pragma unroll
    for (int m = 0; m < 2; ++m) {
        int j0 = (2 * w + m) * 16 + quad * 4;
        float4 bs = *(const float4*)(bias + j0);
        float ss[4] = {0.f, 0.f, 0.f, 0.f}, qq[4] = {0.f, 0.f, 0.f, 0.f};
#pragma unroll
        for (int nt = 0; nt < 4; ++nt) {
            int row = nt * 16 + l15;
            float v0 = eluf(acc[m][nt][0] + bs.x);
            float v1 = eluf(acc[m][nt][1] + bs.y);
            float v2 = eluf(acc[m][nt][2] + bs.z);
            float v3 = eluf(acc[m][nt][3] + bs.w);
            if (OUT16) {
                f16x4 o = {(_Float16)v0, (_Float16)v1, (_Float16)v2, (_Float16)v3};
                *(f16x4*)((_Float16*)outV + (r0 + row) * 128 + j0) = o;
            } else {
                float4 o = {v0, v1, v2, v3};
                *(float4*)((float*)outV + (r0 + row) * 128 + j0) = o;
            }
            if (STATS) {
                ss[0] += v0; qq[0] += v0 * v0;
                ss[1] += v1; qq[1] += v1 * v1;
                ss[2] += v2; qq[2] += v2 * v2;
                ss[3] += v3; qq[3] += v3 * v3;
            }
        }
        if (STATS) {
            float* rep = repm + (blockIdx.x & (NREP - 1)) * 256;
#pragma unroll
            for (int r = 0; r < 4; ++r) {
                float s = ss[r], q = qq[r];
                s += __shfl_xor(s, 1); s += __shfl_xor(s, 2); s += __shfl_xor(s, 4); s += __shfl_xor(s, 8);
                q += __shfl_xor(q, 1); q += __shfl_xor(q, 2); q += __shfl_xor(q, 4); q += __shfl_xor(q, 8);
                if (l15 == 0) {
                    atomicAdd(&rep[j0 + r], s);
                    atomicAdd(&rep[128 + j0 + r], q);
                }
            }
        }
    }
}

// ---------------- MFMA mlp3 l1: gather-concat [send|recv|skip] (K=384) -> 128 f16 ----------------
__global__ __launch_bounds__(256) void k_linmm3(const float* __restrict__ xn,
                                                const float* __restrict__ bufB,
                                                const int* __restrict__ sidx,
                                                const int* __restrict__ ridx,
                                                const float* __restrict__ stats,
                                                const _Float16* __restrict__ wp,
                                                const float* __restrict__ bias,
                                                _Float16* __restrict__ out) {
    __shared__ __align__(16) _Float16 s_b[64 * 392];
    __shared__ float s_st[4][128];
    __shared__ int s_s[64], s_r[64];
    int tid = threadIdx.x;
    long long r0 = (long long)blockIdx.x * 64;
    if (tid < 128) {
        s_st[0][tid] = stats[S_M2_SC + tid];
        s_st[1][tid] = stats[S_M2_SC + 128 + tid];
        s_st[2][tid] = stats[S_M1_SC + tid];
        s_st[3][tid] = stats[S_M1_SC + 128 + tid];
    }
    if (tid < 64) {
        int r = (int)r0 + tid, b = r / EE, ed = r - b * EE;
        s_s[tid] = (b * NN + sidx[ed]) * 128;
        s_r[tid] = (b * NN + ridx[ed]) * 128;
    }
    __syncthreads();
    for (int i = tid; i < 8192; i += 256) {
        int row = i >> 7, j = i & 127;
        float sc2 = s_st[0][j], sh2 = s_st[1][j];
        s_b[row * 392 + j] = (_Float16)fmaf(xn[s_s[row] + j], sc2, sh2);
        s_b[row * 392 + 128 + j] = (_Float16)fmaf(xn[s_r[row] + j], sc2, sh2);
        s_b[row * 392 + 256 + j] = (_Float16)fmaf(bufB[(r0 + row) * 128 + j], s_st[2][j], s_st[3][j]);
    }
    __syncthreads();
    int w = tid >> 6, lane = tid & 63, quad = lane >> 4, l15 = lane & 15;
    f32x4 acc[2][4];
#pragma unroll
    for (int m = 0; m < 2; ++m)
#pragma unroll
        for (int nt = 0; nt < 4; ++nt) acc[m][nt] = (f32x4){0.f, 0.f, 0.f, 0.f};
    const f16x8* Ap = (const f16x8*)wp;
#pragma unroll
    for (int s = 0; s < 12; ++s) {
        f16x8 a0 = Ap[(s * 8 + 2 * w) * 64 + lane];
        f16x8 a1 = Ap[(s * 8 + 2 * w + 1) * 64 + lane];
#pragma unroll
        for (int nt = 0; nt < 4; ++nt) {
            f16x8 bfr = *(const f16x8*)((const char*)s_b + (nt * 16 + l15) * 784 + 64 * s + quad * 16);
            acc[0][nt] = __builtin_amdgcn_mfma_f32_16x16x32_f16(a0, bfr, acc[0][nt], 0, 0, 0);
            acc[1][nt] = __builtin_amdgcn_mfma_f32_16x16x32_f16(a1, bfr, acc[1][nt], 0, 0, 0);
        }
    }
#pragma unroll
    for (int m = 0; m < 2; ++m) {
        int j0 = (2 * w + m) * 16 + quad * 4;
        float4 bs = *(const float4*)(bias + j0);
#pragma unroll
        for (int nt = 0; nt < 4; ++nt) {
            int row = nt * 16 + l15;
            f16x4 o = {(_Float16)eluf(acc[m][nt][0] + bs.x),
                       (_Float16)eluf(acc[m][nt][1] + bs.y),
                       (_Float16)eluf(acc[m][nt][2] + bs.z),
                       (_Float16)eluf(acc[m][nt][3] + bs.w)};
            *(f16x4*)(out + (r0 + row) * 128 + j0) = o;
        }
    }
}

// ---------------- edge2node scatter-mean with inline BN-M1 ----------------
__global__ __launch_bounds__(128) void k_e2n(const float* __restrict__ bufB,
                                             const int* __restrict__ inc,
                                             const float* __restrict__ stats,
                                             float* __restrict__ xn) {
    int bn = blockIdx.x;
    int b = bn / NN, n = bn - b * NN;
    int j = threadIdx.x;
    float sc = stats[S_M1_SC + j], sh = stats[S_M1_SC + 128 + j];
    float s = 0.f;
    for (int k = 0; k < NN - 1; ++k) {
        int e = inc[n * (NN - 1) + k];
        s += bufB[(long long)(b * EE + e) * 128 + j];
    }
    xn[bn * 128 + j] = (s * sc + (float)(NN - 1) * sh) * (1.0f / (float)NN);
}

// ---------------- BN3 apply + fc_out (128 -> 16) ----------------
__global__ __launch_bounds__(256) void k_fcout(const float* __restrict__ h2,
                                               const float* __restrict__ stats,
                                               const float* __restrict__ fcw,
                                               const float* __restrict__ fcb,
                                               float* __restrict__ out) {
    __shared__ float s_x[16 * 129];
    __shared__ float s_w[16 * 129];
    int r0 = blockIdx.x * 16;
    int tid = threadIdx.x;
    for (int i = tid; i < 16 * 128; i += 256) {
        int rr = i >> 7, j = i & 127;
        s_x[rr * 129 + j] = fmaf(h2[(long long)(r0 + rr) * 128 + j],
                                 stats[S_M3_SC + j], stats[S_M3_SC + 128 + j]);
    }
    for (int i = tid; i < 16 * 128; i += 256) {
        int o = i >> 7, j = i & 127;
        s_w[o * 129 + j] = fcw[i];
    }
    __syncthreads();
    int rl = tid >> 4, o = tid & 15;
    float a = fcb[o];
    for (int j = 0; j < 128; ++j) a = fmaf(s_x[rl * 129 + j], s_w[o * 129 + j], a);
    out[(long long)(r0 + rl) * 16 + o] = a;
}

// ---------------- host launcher ----------------
extern "C" void kernel_launch(void* const* d_in, const int* in_sizes, int n_in,
                              void* d_out, int out_size, void* d_ws, size_t ws_size,
                              hipStream_t stream) {
    const float* inputs = (const float*)d_in[0];
    const float* rel_rec = (const float*)d_in[1];
    const float* rel_send = (const float*)d_in[2];
    const float* conv1_w = (const float*)d_in[3];
    const float* conv1_b = (const float*)d_in[4];
    const float* bn1_g = (const float*)d_in[5];
    const float* bn1_b = (const float*)d_in[6];
    const float* conv2_w = (const float*)d_in[7];
    const float* conv2_b = (const float*)d_in[8];
    const float* bn2_g = (const float*)d_in[9];
    const float* bn2_b = (const float*)d_in[10];
    const float* pred_w = (const float*)d_in[11];
    const float* pred_b = (const float*)d_in[12];
    const float* att_w = (const float*)d_in[13];
    const float* att_b = (const float*)d_in[14];
    const float* m1w1 = (const float*)d_in[15];
    const float* m1b1 = (const float*)d_in[16];
    const float* m1w2 = (const float*)d_in[17];
    const float* m1b2 = (const float*)d_in[18];
    const float* m1g = (const float*)d_in[19];
    const float* m1bb = (const float*)d_in[20];
    const float* m2w1 = (const float*)d_in[21];
    const float* m2b1 = (const float*)d_in[22];
    const float* m2w2 = (const float*)d_in[23];
    const float* m2b2 = (const float*)d_in[24];
    const float* m2g = (const float*)d_in[25];
    const float* m2bb = (const float*)d_in[26];
    const float* m3w1 = (const float*)d_in[27];
    const float* m3b1 = (const float*)d_in[28];
    const float* m3w2 = (const float*)d_in[29];
    const float* m3b2 = (const float*)d_in[30];
    const float* m3g = (const float*)d_in[31];
    const float* m3bb = (const float*)d_in[32];
    const float* fcw = (const float*)d_in[33];
    const float* fcb = (const float*)d_in[34];

    char* ws = (char*)d_ws;
    float* stats = (float*)(ws + OFF_STATS);
    int* sidx = (int*)(ws + OFF_SIDX);
    int* ridx = (int*)(ws + OFF_RIDX);
    int* inc = (int*)(ws + OFF_INC);
    _Float16* y23 = (_Float16*)(ws + OFF_Y23);
    float* x = (float*)(ws + OFF_X);
    float* bufB = (float*)(ws + OFF_BUFB);
    float* xn = (float*)(ws + OFF_XN);
    _Float16* apack = (_Float16*)(ws + OFF_APACK);
    _Float16* apack1 = (_Float16*)(ws + OFF_APACK1);
    float* pwt = (float*)(ws + OFF_PWT);
    float* rep1 = (float*)(ws + OFF_REP1);
    float* rep2 = (float*)(ws + OFF_REP2);
    float* repm = (float*)(ws + OFF_REPM);
    _Float16* hf16 = (_Float16*)(ws + OFF_HF16);
    _Float16* mp = (_Float16*)(ws + OFF_MP);
    float* outp = (float*)d_out;

    hipLaunchKernelGGL(k_prep, dim3(117), dim3(256), 0, stream,
                       rel_rec, rel_send, conv2_w, conv1_w, pred_w,
                       m1w1, m1w2, m2w1, m2w2, m3w1, m3w2,
                       apack, apack1, pwt, mp, rep1, rep2, repm, sidx, ridx, inc);
    hipLaunchKernelGGL(k_conv1_stats, dim3(BE), dim3(256), 0, stream,
                       inputs, apack1, conv1_b, sidx, ridx, rep1, y23);
    hipLaunchKernelGGL(k_finalize_rep, dim3(1), dim3(128), 0, stream,
                       rep1, stats, S_BN1_SC, bn1_g, bn1_b, 1.0f / (float)(BE * L1));
    hipLaunchKernelGGL(k_conv2, dim3(BE / 2), dim3(256), 0, stream,
                       y23, apack, conv2_b, stats, rep2);
    hipLaunchKernelGGL(k_finalize_rep, dim3(1), dim3(128), 0, stream,
                       rep2, stats, S_BN2_SC, bn2_g, bn2_b, 1.0f / (float)(BE * L2));
    hipLaunchKernelGGL(k_predatt, dim3(BE), dim3(256), 0, stream,
                       y23, stats, att_w, att_b, pwt, pred_b, x);
    // mlp1 (MFMA)
    hipLaunchKernelGGL((k_linmm<false, true, false>), dim3(BE / 64), dim3(256), 0, stream,
                       (const void*)x, mp + MP_M1W1, m1b1, (void*)hf16, repm);
    hipLaunchKernelGGL((k_linmm<true, false, true>), dim3(BE / 64), dim3(256), 0, stream,
                       (const void*)hf16, mp + MP_M1W2, m1b2, (void*)bufB, repm);
    hipLaunchKernelGGL(k_finalize_rep, dim3(1), dim3(128), 0, stream,
                       repm, stats, S_M1_SC, m1g, m1bb, 1.0f / (float)BE);
    // edge2node (BN-M1 inline) + mlp2 (MFMA)
    hipLaunchKernelGGL(k_e2n, dim3(BB * NN), dim3(128), 0, stream, bufB, inc, stats, xn);
    hipLaunchKernelGGL((k_linmm<false, true, false>), dim3(BB * NN / 64), dim3(256), 0, stream,
                       (const void*)xn, mp + MP_M2W1, m2b1, (void*)hf16, repm);
    hipLaunchKernelGGL((k_linmm<true, false, true>), dim3(BB * NN / 64), dim3(256), 0, stream,
                       (const void*)hf16, mp + MP_M2W2, m2b2, (void*)xn, repm);
    hipLaunchKernelGGL(k_finalize_rep, dim3(1), dim3(128), 0, stream,
                       repm, stats, S_M2_SC, m2g, m2bb, 1.0f / (float)(BB * NN));
    // node2edge + mlp3 (MFMA, gather + BN inline)
    hipLaunchKernelGGL(k_linmm3, dim3(BE / 64), dim3(256), 0, stream,
                       xn, bufB, sidx, ridx, stats, mp + MP_M3W1, m3b1, hf16);
    hipLaunchKernelGGL((k_linmm<true, false, true>), dim3(BE / 64), dim3(256), 0, stream,
                       (const void*)hf16, mp + MP_M3W2, m3b2, (void*)bufB, repm);
    hipLaunchKernelGGL(k_finalize_rep, dim3(1), dim3(128), 0, stream,
                       repm, stats, S_M3_SC, m3g, m3bb, 1.0f / (float)BE);
    // fc_out (BN-M3 inline)
    hipLaunchKernelGGL(k_fcout, dim3(BE / 16), dim3(256), 0, stream, bufB, stats, fcw, fcb, outp);
    (void)in_sizes; (void)n_in; (void)out_size; (void)ws_size;
}